// Round 6
// baseline (365.417 us; speedup 1.0000x reference)
//
#include <hip/hip_runtime.h>
#include <hip/hip_bf16.h>

#define B_SZ    2
#define S_LEN   2048
#define D_MODEL 2048
#define N_HEADS 16
#define D_HEAD  128
#define L_RANK  64
#define M_ROWS  (B_SZ * S_LEN)   // 4096
#define KD      2048             // GEMM K
#define NTIL    (KD / 32)        // 64 K-tiles

typedef short          bf16x8 __attribute__((ext_vector_type(8)));
typedef float          f32x4  __attribute__((ext_vector_type(4)));
typedef float          f32x16 __attribute__((ext_vector_type(16)));
typedef unsigned short us4v   __attribute__((ext_vector_type(4)));
typedef unsigned short us8v   __attribute__((ext_vector_type(8)));
typedef unsigned int   u32x4  __attribute__((ext_vector_type(4)));

// log2(e) / sqrt(128), folded into the Q projection epilogue
#define SCALE_Q 0.127517432f

static __device__ __forceinline__ unsigned short f2bf(float f) {
    unsigned int u = __float_as_uint(f);
    u += 0x7FFFu + ((u >> 16) & 1u);      // RNE; inputs finite
    return (unsigned short)(u >> 16);
}

static __device__ __forceinline__ void gload16(const void* g, void* l) {
    __builtin_amdgcn_global_load_lds(
        (const __attribute__((address_space(1))) unsigned int*)g,
        (__attribute__((address_space(3))) unsigned int*)l, 16, 0, 0);
}

static __device__ __forceinline__ float exp2_hw(float x) {
    float r; asm("v_exp_f32 %0, %1" : "=v"(r) : "v"(x)); return r;
}
static __device__ __forceinline__ unsigned int cvtpk_bf16(float a, float b) {
    unsigned int r; asm("v_cvt_pk_bf16_f32 %0, %1, %2" : "=v"(r) : "v"(a), "v"(b)); return r;
}

// ---------------------------------------------------------------------------
// fp32 -> bf16 for all three activation tensors in ONE dispatch.
// ---------------------------------------------------------------------------
__global__ __launch_bounds__(256) void conv3_kernel(
    const float* __restrict__ q_in, const float* __restrict__ k_in,
    const float* __restrict__ v_in,
    unsigned short* __restrict__ q_o, unsigned short* __restrict__ k_o,
    unsigned short* __restrict__ v_o)
{
    const int bid = blockIdx.x;
    const int z = bid >> 12;               // 4096 blocks per tensor
    const float* in = z == 0 ? q_in : (z == 1 ? k_in : v_in);
    unsigned short* out = z == 0 ? q_o : (z == 1 ? k_o : v_o);
    size_t i = ((size_t)(bid & 4095) * 256 + threadIdx.x) * 8;
    float4 a = *(const float4*)&in[i];
    float4 b = *(const float4*)&in[i + 4];
    us8v o = { f2bf(a.x), f2bf(a.y), f2bf(a.z), f2bf(a.w),
               f2bf(b.x), f2bf(b.y), f2bf(b.z), f2bf(b.w) };
    *(us8v*)&out[i] = o;
}

// ---------------------------------------------------------------------------
// W [K][N] fp32 -> WT [N][K] bf16 (Wq and Wo), 64x64 LDS tile transpose
// ---------------------------------------------------------------------------
__global__ __launch_bounds__(256) void transpose_w_kernel(
    const float* __restrict__ Wq, const float* __restrict__ Wo,
    unsigned short* __restrict__ WqT, unsigned short* __restrict__ WoT)
{
    const float* W = blockIdx.z ? Wo : Wq;
    unsigned short* WT = blockIdx.z ? WoT : WqT;
    const int k0 = blockIdx.y * 64, n0 = blockIdx.x * 64;
    const int tid = threadIdx.x;
    __shared__ float t[64][69];
    #pragma unroll
    for (int c = 0; c < 4; ++c) {
        int idx = c * 256 + tid;
        int r = idx >> 4, c4 = (idx & 15) * 4;
        float4 v = *(const float4*)&W[(size_t)(k0 + r) * D_MODEL + n0 + c4];
        t[r][c4] = v.x; t[r][c4 + 1] = v.y; t[r][c4 + 2] = v.z; t[r][c4 + 3] = v.w;
    }
    __syncthreads();
    #pragma unroll
    for (int c = 0; c < 2; ++c) {
        int idx = c * 256 + tid;
        int nr = idx >> 3, s = idx & 7;
        us8v o;
        #pragma unroll
        for (int j = 0; j < 8; ++j) o[j] = f2bf(t[s * 8 + j][nr]);
        *(us8v*)&WT[(size_t)(n0 + nr) * D_MODEL + k0 + s * 8] = o;
    }
}

// ---------------------------------------------------------------------------
// WeT[h*128+d][din] = sum_l Wl[din][h*64+l] * Wr[l][d]  (bf16, transposed out)
// ---------------------------------------------------------------------------
__global__ __launch_bounds__(256) void weff_t_kernel(
    const float* __restrict__ Wlk, const float* __restrict__ Wlv,
    const float* __restrict__ Wkr, const float* __restrict__ Wvr,
    const float* __restrict__ blk, const float* __restrict__ blv,
    const float* __restrict__ bkr, const float* __restrict__ bvr,
    unsigned short* __restrict__ WeTk, unsigned short* __restrict__ WeTv,
    float* __restrict__ beffk, float* __restrict__ beffv)
{
    const int z = blockIdx.z;
    const float* Wl = z ? Wlv : Wlk;
    const float* Wr = z ? Wvr : Wkr;
    const float* bl = z ? blv : blk;
    const float* br = z ? bvr : bkr;
    unsigned short* We = z ? WeTv : WeTk;
    float* be = z ? beffv : beffk;

    const int h = blockIdx.y;
    const int din0 = blockIdx.x * 64;
    const int tid = threadIdx.x;
    const int lane = tid & 63, w = tid >> 6;

    __shared__ float WrS[64][128];   // [l][d]
    __shared__ float WlT[64][65];    // [l][r]

    #pragma unroll
    for (int c = 0; c < 8; ++c) {
        int e = c * 1024 + tid * 4;
        int l = e >> 7, d = e & 127;
        *(float4*)&WrS[l][d] = *(const float4*)&Wr[l * D_HEAD + d];
    }
    #pragma unroll
    for (int c = 0; c < 4; ++c) {
        int idx = c * 256 + tid;
        int r = idx >> 4, l4 = (idx & 15) * 4;
        float4 v = *(const float4*)&Wl[(size_t)(din0 + r) * (L_RANK * N_HEADS) + h * L_RANK + l4];
        WlT[l4 + 0][r] = v.x; WlT[l4 + 1][r] = v.y; WlT[l4 + 2][r] = v.z; WlT[l4 + 3][r] = v.w;
    }
    __syncthreads();

    for (int i = 0; i < 32; ++i) {
        int d = i * 4 + w;
        float acc = 0.f;
        #pragma unroll
        for (int l = 0; l < L_RANK; ++l) acc += WlT[l][lane] * WrS[l][d];
        We[(size_t)(h * D_HEAD + d) * D_MODEL + din0 + lane] = f2bf(acc);
    }
    if (blockIdx.x == 0 && tid < D_HEAD) {
        float acc = br[tid];
        #pragma unroll
        for (int l = 0; l < L_RANK; ++l) acc += bl[h * L_RANK + l] * WrS[l][tid];
        be[h * D_HEAD + tid] = acc;
    }
}

// ---------------------------------------------------------------------------
// Pipelined GEMM core: BM=128, BN=256, BK=32, 512 thr / 8 waves (2x4),
// 3-deep LDS buffers, prefetch distance 2, ONE raw barrier per K-tile,
// counted s_waitcnt vmcnt(3) (never 0 mid-loop). Chunk-XOR swizzle on
// both stage-source and frag-read (involution; measured 0 conflicts).
// ---------------------------------------------------------------------------
static __device__ __forceinline__ void gemm_core(
    const unsigned short* __restrict__ A,    // [M][2048] bf16, row panel row0
    const unsigned short* __restrict__ Bt,   // [N][2048] bf16, col panel col0
    unsigned short* Al, unsigned short* Bl,  // LDS: Al[3*4096], Bl[3*8192]
    int row0, int col0, int tid, f32x4 acc[4][4])
{
    const int lane = tid & 63;
    const int lr = lane & 15, lg = lane >> 4;
    const int wid = tid >> 6;
    const int wm = wid >> 2, wn = wid & 3;

    // staging sources (inverse-swizzled 16B chunk within each 64B row-K-step)
    const int rA = tid >> 2, pC = tid & 3;
    const unsigned short* aSrc = A + (size_t)(row0 + rA) * KD + ((pC ^ ((rA >> 1) & 3)) * 8);
    const int rB1 = rA + 128;
    const unsigned short* bSrc0 = Bt + (size_t)(col0 + rA) * KD + ((pC ^ ((rA >> 1) & 3)) * 8);
    const unsigned short* bSrc1 = Bt + (size_t)(col0 + rB1) * KD + ((pC ^ ((rB1 >> 1) & 3)) * 8);

    const int sx = (lr >> 1) & 3;
    const int abase = (wm * 64 + lr) * 32 + ((lg ^ sx) * 8);
    const int bbase = (wn * 64 + lr) * 32 + ((lg ^ sx) * 8);

    // prologue: stage tiles 0 (buf0) and 1 (buf1); per-tile issue order {A,B0,B1}
    gload16(aSrc,       Al + tid * 8);
    gload16(bSrc0,      Bl + tid * 8);
    gload16(bSrc1,      Bl + (512 + tid) * 8);
    gload16(aSrc + 32,  Al + 4096 + tid * 8);
    gload16(bSrc0 + 32, Bl + 8192 + tid * 8);
    gload16(bSrc1 + 32, Bl + 8192 + (512 + tid) * 8);

    int bufC = 0, bufS = 2;
    #pragma unroll 1
    for (int t = 0; t < NTIL; ++t) {
        // own loads for tile t complete (3 newer = tile t+1's stay in flight)
        if (t < NTIL - 1) asm volatile("s_waitcnt vmcnt(3)" ::: "memory");
        else              asm volatile("s_waitcnt vmcnt(0)" ::: "memory");
        __builtin_amdgcn_s_barrier();
        asm volatile("" ::: "memory");

        const unsigned short* Ac = Al + bufC * 4096;
        const unsigned short* Bc = Bl + bufC * 8192;
        unsigned short* As = Al + bufS * 4096;
        unsigned short* Bs = Bl + bufS * 8192;
        const bool pf = (t + 2 < NTIL);

        // ---- phase 0: issue {A, B0} for t+2; read a0..3,b0,b1; 8 MFMA ----
        if (pf) {
            gload16(aSrc  + (size_t)(t + 2) * 32, As + tid * 8);
            gload16(bSrc0 + (size_t)(t + 2) * 32, Bs + tid * 8);
        }
        bf16x8 af[4], b0, b1;
        #pragma unroll
        for (int m = 0; m < 4; ++m) af[m] = *(const bf16x8*)&Ac[abase + m * 512];
        b0 = *(const bf16x8*)&Bc[bbase];
        b1 = *(const bf16x8*)&Bc[bbase + 512];
        __builtin_amdgcn_s_setprio(1);
        #pragma unroll
        for (int m = 0; m < 4; ++m)
            acc[m][0] = __builtin_amdgcn_mfma_f32_16x16x32_bf16(af[m], b0, acc[m][0], 0, 0, 0);
        #pragma unroll
        for (int m = 0; m < 4; ++m)
            acc[m][1] = __builtin_amdgcn_mfma_f32_16x16x32_bf16(af[m], b1, acc[m][1], 0, 0, 0);
        __builtin_amdgcn_s_setprio(0);

        // ---- phase 1: issue {B1} for t+2; read b2,b3; 8 MFMA ----
        if (pf) gload16(bSrc1 + (size_t)(t + 2) * 32, Bs + (512 + tid) * 8);
        bf16x8 b2 = *(const bf16x8*)&Bc[bbase + 1024];
        bf16x8 b3 = *(const bf16x8*)&Bc[bbase + 1536];
        __builtin_amdgcn_s_setprio(1);
        #pragma unroll
        for (int m = 0; m < 4; ++m)
            acc[m][2] = __builtin_amdgcn_mfma_f32_16x16x32_bf16(af[m], b2, acc[m][2], 0, 0, 0);
        #pragma unroll
        for (int m = 0; m < 4; ++m)
            acc[m][3] = __builtin_amdgcn_mfma_f32_16x16x32_bf16(af[m], b3, acc[m][3], 0, 0, 0);
        __builtin_amdgcn_s_setprio(0);

        bufC = bufC == 2 ? 0 : bufC + 1;
        bufS = bufS == 2 ? 0 : bufS + 1;
    }
}

// ---------------------------------------------------------------------------
// Batched projection GEMM (z in {0:Q,1:K,2:V}), grid 768 = 3 perfect rounds.
// ---------------------------------------------------------------------------
__global__ __launch_bounds__(512, 2) void proj_gemm8_kernel(
    const unsigned short* __restrict__ Aq, const unsigned short* __restrict__ Ak,
    const unsigned short* __restrict__ Av,
    const unsigned short* __restrict__ WqT, const unsigned short* __restrict__ WeTk,
    const unsigned short* __restrict__ WeTv,
    const float* __restrict__ bq, const float* __restrict__ beffk,
    const float* __restrict__ beffv,
    unsigned short* __restrict__ q_bf, unsigned short* __restrict__ k_bf,
    unsigned short* __restrict__ v_t)
{
    __shared__ unsigned short Al[3][128 * 32];
    __shared__ unsigned short Bl[3][256 * 32];

    const int bid = blockIdx.x;
    const int wgid = (bid & 7) * 96 + (bid >> 3);   // 768 = 8*96, bijective
    const int z = wgid >> 8;
    const int rem = wgid & 255;
    const int row0 = (rem >> 3) * 128, col0 = (rem & 7) * 256;

    const unsigned short* A    = z == 0 ? Aq  : (z == 1 ? Ak   : Av);
    const unsigned short* Bt   = z == 0 ? WqT : (z == 1 ? WeTk : WeTv);
    const float*          bias = z == 0 ? bq  : (z == 1 ? beffk : beffv);

    const int tid = threadIdx.x;
    const int lane = tid & 63, wid = tid >> 6;
    const int lr = lane & 15, lg = lane >> 4;
    const int wm = wid >> 2, wn = wid & 3;

    f32x4 acc[4][4];
    #pragma unroll
    for (int m = 0; m < 4; ++m)
        #pragma unroll
        for (int n = 0; n < 4; ++n) acc[m][n] = (f32x4){0.f, 0.f, 0.f, 0.f};

    gemm_core(A, Bt, &Al[0][0], &Bl[0][0], row0, col0, tid, acc);

    float bv[4];
    #pragma unroll
    for (int n = 0; n < 4; ++n) bv[n] = bias[col0 + wn * 64 + n * 16 + lr];
    const float omul = (z == 0) ? SCALE_Q : 1.0f;

    #pragma unroll
    for (int m = 0; m < 4; ++m) {
        #pragma unroll
        for (int n = 0; n < 4; ++n) {
            const int col = col0 + wn * 64 + n * 16 + lr;
            const int rowb = row0 + wm * 64 + m * 16 + lg * 4;
            if (z < 2) {
                unsigned short* C = z == 0 ? q_bf : k_bf;
                #pragma unroll
                for (int j = 0; j < 4; ++j)
                    C[(size_t)(rowb + j) * D_MODEL + col] = f2bf((acc[m][n][j] + bv[n]) * omul);
            } else {
                const int bidx = rowb >> 11, s = rowb & 2047;
                const int h = col >> 7, d = col & 127;
                us4v o = { f2bf(acc[m][n][0] + bv[n]), f2bf(acc[m][n][1] + bv[n]),
                           f2bf(acc[m][n][2] + bv[n]), f2bf(acc[m][n][3] + bv[n]) };
                *(us4v*)&v_t[((size_t)(bidx * 16 + h) * 128 + d) * 2048 + s] = o;
            }
        }
    }
}

// ---------------------------------------------------------------------------
// Output GEMM: out fp32 = ao @ WoT^T + bo.  Grid 256 = 1 perfect round.
// ---------------------------------------------------------------------------
__global__ __launch_bounds__(512, 2) void out_gemm8_kernel(
    const unsigned short* __restrict__ A,
    const unsigned short* __restrict__ Bt,
    const float* __restrict__ bias,
    float* __restrict__ C)
{
    __shared__ unsigned short Al[3][128 * 32];
    __shared__ unsigned short Bl[3][256 * 32];

    const int bid = blockIdx.x;
    const int wgid = (bid & 7) * 32 + (bid >> 3);   // 256 = 8*32, bijective
    const int row0 = (wgid >> 3) * 128, col0 = (wgid & 7) * 256;

    const int tid = threadIdx.x;
    const int lane = tid & 63, wid = tid >> 6;
    const int lr = lane & 15, lg = lane >> 4;
    const int wm = wid >> 2, wn = wid & 3;

    f32x4 acc[4][4];
    #pragma unroll
    for (int m = 0; m < 4; ++m)
        #pragma unroll
        for (int n = 0; n < 4; ++n) acc[m][n] = (f32x4){0.f, 0.f, 0.f, 0.f};

    gemm_core(A, Bt, &Al[0][0], &Bl[0][0], row0, col0, tid, acc);

    float bv[4];
    #pragma unroll
    for (int n = 0; n < 4; ++n) bv[n] = bias[col0 + wn * 64 + n * 16 + lr];
    #pragma unroll
    for (int m = 0; m < 4; ++m)
        #pragma unroll
        for (int n = 0; n < 4; ++n) {
            const int col = col0 + wn * 64 + n * 16 + lr;
            const int rowb = row0 + wm * 64 + m * 16 + lg * 4;
            #pragma unroll
            for (int j = 0; j < 4; ++j)
                C[(size_t)(rowb + j) * D_MODEL + col] = acc[m][n][j] + bv[n];
        }
}

// ---------------------------------------------------------------------------
// Causal flash attention, swapped-QK 32x32x16, QK dependent-chain split 4-way.
// (unchanged from R5)
// ---------------------------------------------------------------------------
static __device__ __forceinline__ void flash_stage(
    const unsigned short* __restrict__ kgh,
    const unsigned short* __restrict__ vtb,
    unsigned short* Kl, unsigned short* Vl, int kv0, int tid)
{
    #pragma unroll
    for (int c = 0; c < 4; ++c) {
        int idx = c * 256 + tid;
        int r = idx >> 4, ch = idx & 15;
        gload16(kgh + (size_t)(kv0 + r) * D_MODEL + ((ch ^ (r & 7)) * 8), Kl + idx * 8);
    }
    #pragma unroll
    for (int c = 0; c < 4; ++c) {
        int idx = c * 256 + tid;
        int d = idx >> 3, ch = idx & 7;
        gload16(vtb + (size_t)d * S_LEN + kv0 + ((ch ^ (d & 7)) * 8), Vl + idx * 8);
    }
}

__global__ __launch_bounds__(256, 2) void flash_kernel(
    const unsigned short* __restrict__ Q,
    const unsigned short* __restrict__ Kg,
    const unsigned short* __restrict__ Vt,
    unsigned short* __restrict__ Og)
{
    __shared__ unsigned short Klds[2][64 * 128];
    __shared__ unsigned short Vlds[2][128 * 64];

    const int tid = threadIdx.x;
    const int lane = tid & 63, wid = tid >> 6;
    const int lc = lane & 31, hi = lane >> 5;

    const int blk = blockIdx.x;
    const int jj = blk >> 5;
    const int qt = (jj < 8) ? jj : 23 - jj;
    const int bh = blk & 31;
    const int b = bh >> 4, h = bh & 15;
    const size_t base = (size_t)b * S_LEN * D_MODEL;
    const unsigned short* kgh = Kg + base + h * D_HEAD;
    const unsigned short* vtb = Vt + (size_t)bh * D_HEAD * S_LEN;

    const int q0w = qt * 128 + wid * 32;
    const int qcol = q0w + lc;

    bf16x8 qf[8];
    #pragma unroll
    for (int dc = 0; dc < 8; ++dc)
        qf[dc] = *(const bf16x8*)&Q[base + (size_t)qcol * D_MODEL + h * D_HEAD + dc * 16 + hi * 8];

    f32x16 o_acc[4];
    #pragma unroll
    for (int dt = 0; dt < 4; ++dt)
        #pragma unroll
        for (int r = 0; r < 16; ++r) o_acc[dt][r] = 0.f;
    float m_r = -3e38f, l_r = 0.f;

    const int kxor = lc & 7;
    const int nt = 2 * qt + 2;

    flash_stage(kgh, vtb, Klds[0], Vlds[0], 0, tid);

    #pragma unroll 1
    for (int t = 0; t < nt; ++t) {
        const int bb = t & 1;
        const int kv0 = t * 64;
        __syncthreads();
        if (t + 1 < nt)
            flash_stage(kgh, vtb, Klds[bb ^ 1], Vlds[bb ^ 1], (t + 1) * 64, tid);

        f32x16 s0a, s0b, s1a, s1b;
        #pragma unroll
        for (int r = 0; r < 16; ++r) { s0a[r] = 0.f; s0b[r] = 0.f; s1a[r] = 0.f; s1b[r] = 0.f; }
        __builtin_amdgcn_s_setprio(1);
        #pragma unroll
        for (int dc = 0; dc < 4; ++dc) {
            bf16x8 kf0 = *(const bf16x8*)&Klds[bb][lc * 128 + (((dc * 2 + hi) ^ kxor) * 8)];
            bf16x8 kf1 = *(const bf16x8*)&Klds[bb][(32 + lc) * 128 + (((dc * 2 + hi) ^ kxor) * 8)];
            s0a = __builtin_amdgcn_mfma_f32_32x32x16_bf16(kf0, qf[dc], s0a, 0, 0, 0);
            s1a = __builtin_amdgcn_mfma_f32_32x32x16_bf16(kf1, qf[dc], s1a, 0, 0, 0);
        }
        #pragma unroll
        for (int dc = 4; dc < 8; ++dc) {
            bf16x8 kf0 = *(const bf16x8*)&Klds[bb][lc * 128 + (((dc * 2 + hi) ^ kxor) * 8)];
            bf16x8 kf1 = *(const bf16x8*)&Klds[bb][(32 + lc) * 128 + (((dc * 2 + hi) ^ kxor) * 8)];
            s0b = __builtin_amdgcn_mfma_f32_32x32x16_bf16(kf0, qf[dc], s0b, 0, 0, 0);
            s1b = __builtin_amdgcn_mfma_f32_32x32x16_bf16(kf1, qf[dc], s1b, 0, 0, 0);
        }
        __builtin_amdgcn_s_setprio(0);
        f32x16 s0 = s0a + s0b;
        f32x16 s1 = s1a + s1b;

        if (t >= nt - 2) {
            #pragma unroll
            for (int r = 0; r < 16; ++r) {
                int krow = (r & 3) + 8 * (r >> 2) + 4 * hi;
                if (kv0 + krow > qcol)      s0[r] = -3e38f;
                if (kv0 + 32 + krow > qcol) s1[r] = -3e38f;
            }
        }

        float mt[8];
        #pragma unroll
        for (int i = 0; i < 8; ++i)
            mt[i] = fmaxf(fmaxf(s0[2 * i], s0[2 * i + 1]), fmaxf(s1[2 * i], s1[2 * i + 1]));
        float mA = fmaxf(fmaxf(mt[0], mt[1]), fmaxf(mt[2], mt[3]));
        float mB = fmaxf(fmaxf(mt[4], mt[5]), fmaxf(mt[6], mt[7]));
        float sm = fmaxf(mA, mB);
        sm = fmaxf(sm, __shfl_xor(sm, 32));

        if (__any(sm > m_r + 11.5f)) {
            float mnew = fmaxf(m_r, sm);
            float alpha = exp2_hw(m_r - mnew);
            l_r *= alpha;
            m_r = mnew;
            #pragma unroll
            for (int r = 0; r < 16; ++r) {
                float av = __shfl(alpha, (r & 3) + 8 * (r >> 2) + 4 * hi);
                #pragma unroll
                for (int dt = 0; dt < 4; ++dt) o_acc[dt][r] *= av;
            }
        }

        #pragma unroll
        for (int r = 0; r < 16; ++r) {
            s0[r] = exp2_hw(s0[r] - m_r);
            s1[r] = exp2_hw(s1[r] - m_r);
        }
        float st[8];
        #pragma unroll
        for (int i = 0; i < 8; ++i)
            st[i] = (s0[2 * i] + s0[2 * i + 1]) + (s1[2 * i] + s1[2 * i + 1]);
        l_r += ((st[0] + st[1]) + (st[2] + st[3])) + ((st[4] + st[5]) + (st[6] + st[7]));

        #pragma unroll
        for (int t32 = 0; t32 < 2; ++t32) {
            const f32x16& s = t32 ? s1 : s0;
            unsigned int c0[4], c1[4];
            #pragma unroll
            for (int g = 0; g < 4; ++g) {
                c0[g] = cvtpk_bf16(s[4 * g],     s[4 * g + 1]);
                c1[g] = cvtpk_bf16(s[4 * g + 2], s[4 * g + 3]);
            }
            #pragma unroll
            for (int kt = 0; kt < 2; ++kt) {
                unsigned int sel0 = hi ? c0[2 * kt] : c0[2 * kt + 1];
                unsigned int sel1 = hi ? c1[2 * kt] : c1[2 * kt + 1];
                unsigned int o0 = (unsigned int)__shfl_xor((int)sel0, 32);
                unsigned int o1 = (unsigned int)__shfl_xor((int)sel1, 32);
                u32x4 uu;
                uu.x = hi ? o0 : c0[2 * kt];
                uu.y = hi ? o1 : c1[2 * kt];
                uu.z = hi ? c0[2 * kt + 1] : o0;
                uu.w = hi ? c1[2 * kt + 1] : o1;
                bf16x8 pf = __builtin_bit_cast(bf16x8, uu);
                __builtin_amdgcn_s_setprio(1);
                #pragma unroll
                for (int dt = 0; dt < 4; ++dt) {
                    bf16x8 vf = *(const bf16x8*)
                        &Vlds[bb][(dt * 32 + lc) * 64 + (((t32 * 4 + kt * 2 + hi) ^ kxor) * 8)];
                    o_acc[dt] = __builtin_amdgcn_mfma_f32_32x32x16_bf16(pf, vf, o_acc[dt], 0, 0, 0);
                }
                __builtin_amdgcn_s_setprio(0);
            }
        }
    }

    float lt = l_r + __shfl_xor(l_r, 32);
    float inv = 1.0f / lt;
    #pragma unroll
    for (int r = 0; r < 16; ++r) {
        int qrow = (r & 3) + 8 * (r >> 2) + 4 * hi;
        float iv = __shfl(inv, qrow);
        #pragma unroll
        for (int dt = 0; dt < 4; ++dt)
            Og[base + (size_t)(q0w + qrow) * D_MODEL + h * D_HEAD + dt * 32 + lc] =
                f2bf(o_acc[dt][r] * iv);
    }
}

// ---------------------------------------------------------------------------
extern "C" void kernel_launch(void* const* d_in, const int* in_sizes, int n_in,
                              void* d_out, int out_size, void* d_ws, size_t ws_size,
                              hipStream_t stream)
{
    const float* queries = (const float*)d_in[0];
    const float* keys    = (const float*)d_in[1];
    const float* values  = (const float*)d_in[2];
    const float* Wq  = (const float*)d_in[3];
    const float* bq  = (const float*)d_in[4];
    const float* Wlk = (const float*)d_in[5];
    const float* blk = (const float*)d_in[6];
    const float* Wlv = (const float*)d_in[7];
    const float* blv = (const float*)d_in[8];
    const float* Wkr = (const float*)d_in[9];
    const float* bkr = (const float*)d_in[10];
    const float* Wvr = (const float*)d_in[11];
    const float* bvr = (const float*)d_in[12];
    const float* Wo  = (const float*)d_in[13];
    const float* bo  = (const float*)d_in[14];
    float* out = (float*)d_out;

    char* ws = (char*)d_ws;
    const size_t MB16 = (size_t)M_ROWS * D_MODEL * 2;       // 16 MB
    const size_t MB8  = (size_t)D_MODEL * D_MODEL * 2;      // 8 MB
    unsigned short* abf_q = (unsigned short*)(ws);
    unsigned short* abf_k = (unsigned short*)(ws + MB16);
    unsigned short* abf_v = (unsigned short*)(ws + 2 * MB16);
    unsigned short* q_bf  = (unsigned short*)(ws + 3 * MB16);
    unsigned short* k_bf  = (unsigned short*)(ws + 4 * MB16);
    unsigned short* v_t   = (unsigned short*)(ws + 5 * MB16);
    unsigned short* ao    = abf_q;                            // dead after proj
    unsigned short* WqT   = (unsigned short*)(ws + 6 * MB16);
    unsigned short* WeTk  = (unsigned short*)(ws + 6 * MB16 + MB8);
    unsigned short* WeTv  = (unsigned short*)(ws + 6 * MB16 + 2 * MB8);
    unsigned short* WoT   = (unsigned short*)(ws + 6 * MB16 + 3 * MB8);
    float* beffk = (float*)(ws + 6 * MB16 + 4 * MB8);
    float* beffv = beffk + D_MODEL;

    weff_t_kernel<<<dim3(32, 16, 2), 256, 0, stream>>>(
        Wlk, Wlv, Wkr, Wvr, blk, blv, bkr, bvr, WeTk, WeTv, beffk, beffv);
    transpose_w_kernel<<<dim3(32, 32, 2), 256, 0, stream>>>(Wq, Wo, WqT, WoT);

    conv3_kernel<<<12288, 256, 0, stream>>>(queries, keys, values, abf_q, abf_k, abf_v);

    proj_gemm8_kernel<<<768, 512, 0, stream>>>(
        abf_q, abf_k, abf_v, WqT, WeTk, WeTv, bq, beffk, beffv,
        q_bf, k_bf, v_t);

    flash_kernel<<<512, 256, 0, stream>>>(q_bf, k_bf, v_t, ao);

    out_gemm8_kernel<<<256, 512, 0, stream>>>(ao, WoT, bo, out);
}

// Round 7
// 270.696 us; speedup vs baseline: 1.3499x; 1.3499x over previous
//
#include <hip/hip_runtime.h>
#include <hip/hip_bf16.h>

#define B_SZ    2
#define S_LEN   2048
#define D_MODEL 2048
#define N_HEADS 16
#define D_HEAD  128
#define L_RANK  64
#define M_ROWS  (B_SZ * S_LEN)   // 4096
#define KD      2048             // GEMM K
#define NT      (KD / 32)        // 64 K-steps

typedef short          bf16x8 __attribute__((ext_vector_type(8)));
typedef float          f32x4  __attribute__((ext_vector_type(4)));
typedef float          f32x16 __attribute__((ext_vector_type(16)));
typedef unsigned short us4v   __attribute__((ext_vector_type(4)));
typedef unsigned short us8v   __attribute__((ext_vector_type(8)));
typedef unsigned int   u32x4  __attribute__((ext_vector_type(4)));

// log2(e) / sqrt(128), folded into the Q projection epilogue
#define SCALE_Q 0.127517432f

static __device__ __forceinline__ unsigned short f2bf(float f) {
    unsigned int u = __float_as_uint(f);
    u += 0x7FFFu + ((u >> 16) & 1u);      // RNE; inputs finite
    return (unsigned short)(u >> 16);
}

static __device__ __forceinline__ void gload16(const void* g, void* l) {
    __builtin_amdgcn_global_load_lds(
        (const __attribute__((address_space(1))) unsigned int*)g,
        (__attribute__((address_space(3))) unsigned int*)l, 16, 0, 0);
}

static __device__ __forceinline__ float exp2_hw(float x) {
    float r; asm("v_exp_f32 %0, %1" : "=v"(r) : "v"(x)); return r;
}
static __device__ __forceinline__ unsigned int cvtpk_bf16(float a, float b) {
    unsigned int r; asm("v_cvt_pk_bf16_f32 %0, %1, %2" : "=v"(r) : "v"(a), "v"(b)); return r;
}

// ---------------------------------------------------------------------------
// Fused prep: [0,12288) fp32->bf16 conv of q/k/v; [12288,15360) 64x64 tile
// transposes of Wq/Wlk/Wlv (fp32 [K][N] -> bf16 [N][K]); 15360 = Wkr/Wvr
// mini transpose (fp32 [64][128] -> bf16 [128][64]).
// ---------------------------------------------------------------------------
__global__ __launch_bounds__(256) void prep_kernel(
    const float* __restrict__ q_in, const float* __restrict__ k_in,
    const float* __restrict__ v_in,
    const float* __restrict__ Wq, const float* __restrict__ Wlk,
    const float* __restrict__ Wlv,
    const float* __restrict__ Wkr, const float* __restrict__ Wvr,
    unsigned short* __restrict__ q_o, unsigned short* __restrict__ k_o,
    unsigned short* __restrict__ v_o,
    unsigned short* __restrict__ WqT, unsigned short* __restrict__ WlkT,
    unsigned short* __restrict__ WlvT,
    unsigned short* __restrict__ WkrT, unsigned short* __restrict__ WvrT)
{
    __shared__ float tl[64][69];
    const int bid = blockIdx.x, tid = threadIdx.x;

    if (bid < 12288) {
        const int z = bid >> 12;
        const float* in = z == 0 ? q_in : (z == 1 ? k_in : v_in);
        unsigned short* out = z == 0 ? q_o : (z == 1 ? k_o : v_o);
        size_t i = ((size_t)(bid & 4095) * 256 + tid) * 8;
        float4 a = *(const float4*)&in[i];
        float4 b = *(const float4*)&in[i + 4];
        us8v o = { f2bf(a.x), f2bf(a.y), f2bf(a.z), f2bf(a.w),
                   f2bf(b.x), f2bf(b.y), f2bf(b.z), f2bf(b.w) };
        *(us8v*)&out[i] = o;
    } else if (bid < 15360) {
        const int t = bid - 12288;
        const int z = t >> 10;
        const int y = (t & 1023) >> 5, x = t & 31;
        const int Nz = (z == 0) ? 2048 : 1024;
        if (x * 64 >= Nz) return;
        const float* W = z == 0 ? Wq : (z == 1 ? Wlk : Wlv);
        unsigned short* WT = z == 0 ? WqT : (z == 1 ? WlkT : WlvT);
        const int k0 = y * 64, n0 = x * 64;
        #pragma unroll
        for (int c = 0; c < 4; ++c) {
            int idx = c * 256 + tid;
            int r = idx >> 4, c4 = (idx & 15) * 4;
            float4 v = *(const float4*)&W[(size_t)(k0 + r) * Nz + n0 + c4];
            tl[r][c4] = v.x; tl[r][c4 + 1] = v.y; tl[r][c4 + 2] = v.z; tl[r][c4 + 3] = v.w;
        }
        __syncthreads();
        #pragma unroll
        for (int c = 0; c < 2; ++c) {
            int idx = c * 256 + tid;
            int nr = idx >> 3, s = idx & 7;
            us8v o;
            #pragma unroll
            for (int j = 0; j < 8; ++j) o[j] = f2bf(tl[s * 8 + j][nr]);
            *(us8v*)&WT[(size_t)(n0 + nr) * KD + k0 + s * 8] = o;
        }
    } else {
        #pragma unroll 1
        for (int t2 = 0; t2 < 2; ++t2) {
            const float* W = t2 ? Wvr : Wkr;
            unsigned short* WT = t2 ? WvrT : WkrT;
            for (int i = 0; i < 32; ++i) {
                int e = i * 256 + tid;
                int d = e >> 6, l = e & 63;
                WT[d * 64 + l] = f2bf(W[l * 128 + d]);
            }
        }
    }
}

// ---------------------------------------------------------------------------
// Generic single-tensor 64x64 transpose: W fp32 [2048][2048] -> WT bf16.
// ---------------------------------------------------------------------------
__global__ __launch_bounds__(256) void transpose_one_kernel(
    const float* __restrict__ W, unsigned short* __restrict__ WT)
{
    const int k0 = blockIdx.y * 64, n0 = blockIdx.x * 64;
    const int tid = threadIdx.x;
    __shared__ float tl[64][69];
    #pragma unroll
    for (int c = 0; c < 4; ++c) {
        int idx = c * 256 + tid;
        int r = idx >> 4, c4 = (idx & 15) * 4;
        float4 v = *(const float4*)&W[(size_t)(k0 + r) * D_MODEL + n0 + c4];
        tl[r][c4] = v.x; tl[r][c4 + 1] = v.y; tl[r][c4 + 2] = v.z; tl[r][c4 + 3] = v.w;
    }
    __syncthreads();
    #pragma unroll
    for (int c = 0; c < 2; ++c) {
        int idx = c * 256 + tid;
        int nr = idx >> 3, s = idx & 7;
        us8v o;
        #pragma unroll
        for (int j = 0; j < 8; ++j) o[j] = f2bf(tl[s * 8 + j][nr]);
        *(us8v*)&WT[(size_t)(n0 + nr) * D_MODEL + k0 + s * 8] = o;
    }
}

// ---------------------------------------------------------------------------
// Stage-1 batched GEMM (R5-proven core): z=0: q = Xq@WqT^T (+bq)*SCALE_Q,
// N=2048; z=1: lat_k = Xk@WlkT^T + blk, N=1024; z=2: lat_v, N=1024.
// 128x128 tile, BK=32, dbuf, one barrier per K-step, gload_lds both operands.
// grid 1024 (512+256+256), XCD-bijective swizzle.
// ---------------------------------------------------------------------------
__global__ __launch_bounds__(256) void stage1_kernel(
    const unsigned short* __restrict__ Aq, const unsigned short* __restrict__ Ak,
    const unsigned short* __restrict__ Av,
    const unsigned short* __restrict__ WqT, const unsigned short* __restrict__ WlkT,
    const unsigned short* __restrict__ WlvT,
    const float* __restrict__ bq, const float* __restrict__ blk,
    const float* __restrict__ blv,
    unsigned short* __restrict__ q_bf, unsigned short* __restrict__ lat_k,
    unsigned short* __restrict__ lat_v)
{
    __shared__ unsigned short Al[2][128 * 32];
    __shared__ unsigned short Bl[2][128 * 32];

    const int flat = blockIdx.x;
    const int swz = (flat & 7) * 128 + (flat >> 3);   // 1024 = 8*128
    int z, rem;
    if (swz < 512)      { z = 0; rem = swz; }
    else if (swz < 768) { z = 1; rem = swz - 512; }
    else                { z = 2; rem = swz - 768; }
    int row0, col0, Nz;
    if (z == 0) { row0 = (rem >> 4) * 128; col0 = (rem & 15) * 128; Nz = 2048; }
    else        { row0 = (rem >> 3) * 128; col0 = (rem & 7) * 128;  Nz = 1024; }

    const unsigned short* A    = z == 0 ? Aq  : (z == 1 ? Ak   : Av);
    const unsigned short* Bt   = z == 0 ? WqT : (z == 1 ? WlkT : WlvT);
    const float*          bias = z == 0 ? bq  : (z == 1 ? blk  : blv);
    unsigned short*       C    = z == 0 ? q_bf : (z == 1 ? lat_k : lat_v);

    const int tid = threadIdx.x;
    const int lane = tid & 63, wid = tid >> 6;
    const int lr = lane & 15, lg = lane >> 4;
    const int wr = wid >> 1, wc = wid & 1;

    const unsigned short* ag[2];
    const unsigned short* bg[2];
    unsigned short* alp[2][2];
    unsigned short* blp[2][2];
    #pragma unroll
    for (int c = 0; c < 2; ++c) {
        int idx = wid * 128 + c * 64 + lane;
        int row = idx >> 2, p = idx & 3;
        int sp = p ^ ((row >> 1) & 3);
        ag[c] = A  + (size_t)(row0 + row) * KD + sp * 8;
        bg[c] = Bt + (size_t)(col0 + row) * KD + sp * 8;
        alp[0][c] = Al[0] + idx * 8;  alp[1][c] = Al[1] + idx * 8;
        blp[0][c] = Bl[0] + idx * 8;  blp[1][c] = Bl[1] + idx * 8;
    }
    const int sx = (lr >> 1) & 3;
    const int abase = (wr * 64 + lr) * 32 + ((lg ^ sx) * 8);
    const int bbase = (wc * 64 + lr) * 32 + ((lg ^ sx) * 8);

    f32x4 acc[4][4];
    #pragma unroll
    for (int m = 0; m < 4; ++m)
        #pragma unroll
        for (int n = 0; n < 4; ++n) acc[m][n] = (f32x4){0.f, 0.f, 0.f, 0.f};

    #pragma unroll
    for (int c = 0; c < 2; ++c) { gload16(ag[c], alp[0][c]); gload16(bg[c], blp[0][c]); }
    __syncthreads();

    #pragma unroll 1
    for (int t = 0; t < NT; ++t) {
        const int cur = t & 1, nxt = cur ^ 1;
        if (t + 1 < NT) {
            #pragma unroll
            for (int c = 0; c < 2; ++c) {
                gload16(ag[c] + (size_t)(t + 1) * 32, alp[nxt][c]);
                gload16(bg[c] + (size_t)(t + 1) * 32, blp[nxt][c]);
            }
        }
        bf16x8 af[4], bfv[4];
        #pragma unroll
        for (int m = 0; m < 4; ++m) af[m]  = *(const bf16x8*)&Al[cur][abase + m * 512];
        #pragma unroll
        for (int n = 0; n < 4; ++n) bfv[n] = *(const bf16x8*)&Bl[cur][bbase + n * 512];
        __builtin_amdgcn_s_setprio(1);
        #pragma unroll
        for (int m = 0; m < 4; ++m)
            #pragma unroll
            for (int n = 0; n < 4; ++n)
                acc[m][n] = __builtin_amdgcn_mfma_f32_16x16x32_bf16(af[m], bfv[n], acc[m][n], 0, 0, 0);
        __builtin_amdgcn_s_setprio(0);
        __syncthreads();
    }

    float bv[4];
    #pragma unroll
    for (int n = 0; n < 4; ++n) bv[n] = bias[col0 + wc * 64 + n * 16 + lr];
    const float omul = (z == 0) ? SCALE_Q : 1.0f;

    #pragma unroll
    for (int m = 0; m < 4; ++m) {
        #pragma unroll
        for (int n = 0; n < 4; ++n) {
            const int col = col0 + wc * 64 + n * 16 + lr;
            const int rowb = row0 + wr * 64 + m * 16 + lg * 4;
            #pragma unroll
            for (int j = 0; j < 4; ++j)
                C[(size_t)(rowb + j) * Nz + col] = f2bf((acc[m][n][j] + bv[n]) * omul);
        }
    }
}

// ---------------------------------------------------------------------------
// Stage-2 recon (K=64, memory-bound): z=0: k = lat_k[:,h*64:+64]@WkrT^T + bkr
// -> k_bf[s][h*128+d]; z=1: v -> v_t[(b*16+h)*128+d][s].
// Block = 128 rows x 128 cols (one head). grid 1024.
// ---------------------------------------------------------------------------
__global__ __launch_bounds__(256) void recon_kernel(
    const unsigned short* __restrict__ lat_k, const unsigned short* __restrict__ lat_v,
    const unsigned short* __restrict__ WkrT, const unsigned short* __restrict__ WvrT,
    const float* __restrict__ bkr, const float* __restrict__ bvr,
    unsigned short* __restrict__ k_bf, unsigned short* __restrict__ v_t)
{
    __shared__ unsigned short Alds[128 * 64];
    __shared__ unsigned short Blds[128 * 64];

    const int flat = blockIdx.x;
    const int swz = (flat & 7) * 128 + (flat >> 3);   // 1024 = 8*128
    const int z = swz >> 9;
    const int rem = swz & 511;
    const int h = rem >> 5;
    const int r0 = (rem & 31) * 128;

    const unsigned short* lat = z ? lat_v : lat_k;
    const unsigned short* WT  = z ? WvrT : WkrT;
    const float* bias = z ? bvr : bkr;

    const int tid = threadIdx.x;
    const int lane = tid & 63, wid = tid >> 6;
    const int lr = lane & 15, lg = lane >> 4;
    const int wm = wid >> 1, wn = wid & 1;

    #pragma unroll
    for (int c = 0; c < 4; ++c) {
        int e = c * 256 + tid;
        int row = e >> 3, pc = e & 7;
        gload16(lat + (size_t)(r0 + row) * 1024 + h * 64 + ((pc ^ (row & 7)) * 8),
                Alds + e * 8);
    }
    #pragma unroll
    for (int c = 0; c < 4; ++c) {
        int e = c * 256 + tid;
        int d = e >> 3, pc = e & 7;
        gload16(WT + (size_t)d * 64 + ((pc ^ (d & 7)) * 8), Blds + e * 8);
    }
    __syncthreads();

    f32x4 acc[4][4];
    #pragma unroll
    for (int m = 0; m < 4; ++m)
        #pragma unroll
        for (int n = 0; n < 4; ++n) acc[m][n] = (f32x4){0.f, 0.f, 0.f, 0.f};

    #pragma unroll
    for (int ks = 0; ks < 2; ++ks) {
        bf16x8 af[4], bfv[4];
        #pragma unroll
        for (int m = 0; m < 4; ++m) {
            int row = wm * 64 + m * 16 + lr;
            af[m] = *(const bf16x8*)&Alds[row * 64 + (((ks * 4 + lg) ^ (row & 7)) * 8)];
        }
        #pragma unroll
        for (int n = 0; n < 4; ++n) {
            int row = wn * 64 + n * 16 + lr;
            bfv[n] = *(const bf16x8*)&Blds[row * 64 + (((ks * 4 + lg) ^ (row & 7)) * 8)];
        }
        #pragma unroll
        for (int m = 0; m < 4; ++m)
            #pragma unroll
            for (int n = 0; n < 4; ++n)
                acc[m][n] = __builtin_amdgcn_mfma_f32_16x16x32_bf16(af[m], bfv[n], acc[m][n], 0, 0, 0);
    }

    const int b = r0 >> 11;
    float bv[4];
    #pragma unroll
    for (int n = 0; n < 4; ++n) bv[n] = bias[wn * 64 + n * 16 + lr];

    #pragma unroll
    for (int m = 0; m < 4; ++m) {
        #pragma unroll
        for (int n = 0; n < 4; ++n) {
            const int d = wn * 64 + n * 16 + lr;
            const int rowb = r0 + wm * 64 + m * 16 + lg * 4;
            if (z == 0) {
                #pragma unroll
                for (int j = 0; j < 4; ++j)
                    k_bf[(size_t)(rowb + j) * D_MODEL + h * D_HEAD + d] =
                        f2bf(acc[m][n][j] + bv[n]);
            } else {
                us4v o = { f2bf(acc[m][n][0] + bv[n]), f2bf(acc[m][n][1] + bv[n]),
                           f2bf(acc[m][n][2] + bv[n]), f2bf(acc[m][n][3] + bv[n]) };
                *(us4v*)&v_t[((size_t)(b * 16 + h) * 128 + d) * 2048 + (rowb & 2047)] = o;
            }
        }
    }
}

// ---------------------------------------------------------------------------
// Output GEMM (R5-proven): out fp32 = ao @ WoT^T + bo.  Grid 512.
// ---------------------------------------------------------------------------
__global__ __launch_bounds__(256) void out_gemm_kernel(
    const unsigned short* __restrict__ A,
    const unsigned short* __restrict__ Bt,
    const float* __restrict__ bias,
    float* __restrict__ C)
{
    __shared__ unsigned short Al[2][128 * 32];
    __shared__ unsigned short Bl[2][128 * 32];

    const int flat = blockIdx.x;
    const int swz = (flat & 7) * 64 + (flat >> 3);   // 512 = 8 * 64
    const int row0 = (swz >> 4) * 128, col0 = (swz & 15) * 128;

    const int tid = threadIdx.x;
    const int lane = tid & 63, wid = tid >> 6;
    const int lr = lane & 15, lg = lane >> 4;
    const int wr = wid >> 1, wc = wid & 1;

    const unsigned short* ag[2];
    const unsigned short* bg[2];
    unsigned short* alp[2][2];
    unsigned short* blp[2][2];
    #pragma unroll
    for (int c = 0; c < 2; ++c) {
        int idx = wid * 128 + c * 64 + lane;
        int row = idx >> 2, p = idx & 3;
        int sp = p ^ ((row >> 1) & 3);
        ag[c] = A  + (size_t)(row0 + row) * KD + sp * 8;
        bg[c] = Bt + (size_t)(col0 + row) * KD + sp * 8;
        alp[0][c] = Al[0] + idx * 8;  alp[1][c] = Al[1] + idx * 8;
        blp[0][c] = Bl[0] + idx * 8;  blp[1][c] = Bl[1] + idx * 8;
    }
    const int sx = (lr >> 1) & 3;
    const int abase = (wr * 64 + lr) * 32 + ((lg ^ sx) * 8);
    const int bbase = (wc * 64 + lr) * 32 + ((lg ^ sx) * 8);

    f32x4 acc[4][4];
    #pragma unroll
    for (int m = 0; m < 4; ++m)
        #pragma unroll
        for (int n = 0; n < 4; ++n) acc[m][n] = (f32x4){0.f, 0.f, 0.f, 0.f};

    #pragma unroll
    for (int c = 0; c < 2; ++c) { gload16(ag[c], alp[0][c]); gload16(bg[c], blp[0][c]); }
    __syncthreads();

    #pragma unroll 1
    for (int t = 0; t < NT; ++t) {
        const int cur = t & 1, nxt = cur ^ 1;
        if (t + 1 < NT) {
            #pragma unroll
            for (int c = 0; c < 2; ++c) {
                gload16(ag[c] + (size_t)(t + 1) * 32, alp[nxt][c]);
                gload16(bg[c] + (size_t)(t + 1) * 32, blp[nxt][c]);
            }
        }
        bf16x8 af[4], bfv[4];
        #pragma unroll
        for (int m = 0; m < 4; ++m) af[m]  = *(const bf16x8*)&Al[cur][abase + m * 512];
        #pragma unroll
        for (int n = 0; n < 4; ++n) bfv[n] = *(const bf16x8*)&Bl[cur][bbase + n * 512];
        __builtin_amdgcn_s_setprio(1);
        #pragma unroll
        for (int m = 0; m < 4; ++m)
            #pragma unroll
            for (int n = 0; n < 4; ++n)
                acc[m][n] = __builtin_amdgcn_mfma_f32_16x16x32_bf16(af[m], bfv[n], acc[m][n], 0, 0, 0);
        __builtin_amdgcn_s_setprio(0);
        __syncthreads();
    }

    float bv[4];
    #pragma unroll
    for (int n = 0; n < 4; ++n) bv[n] = bias[col0 + wc * 64 + n * 16 + lr];
    #pragma unroll
    for (int m = 0; m < 4; ++m)
        #pragma unroll
        for (int n = 0; n < 4; ++n) {
            const int col = col0 + wc * 64 + n * 16 + lr;
            const int rowb = row0 + wr * 64 + m * 16 + lg * 4;
            #pragma unroll
            for (int j = 0; j < 4; ++j)
                C[(size_t)(rowb + j) * D_MODEL + col] = acc[m][n][j] + bv[n];
        }
}

// ---------------------------------------------------------------------------
// Causal flash attention, swapped-QK 32x32x16 (R5-proven, unchanged).
// ---------------------------------------------------------------------------
static __device__ __forceinline__ void flash_stage(
    const unsigned short* __restrict__ kgh,
    const unsigned short* __restrict__ vtb,
    unsigned short* Kl, unsigned short* Vl, int kv0, int tid)
{
    #pragma unroll
    for (int c = 0; c < 4; ++c) {
        int idx = c * 256 + tid;
        int r = idx >> 4, ch = idx & 15;
        gload16(kgh + (size_t)(kv0 + r) * D_MODEL + ((ch ^ (r & 7)) * 8), Kl + idx * 8);
    }
    #pragma unroll
    for (int c = 0; c < 4; ++c) {
        int idx = c * 256 + tid;
        int d = idx >> 3, ch = idx & 7;
        gload16(vtb + (size_t)d * S_LEN + kv0 + ((ch ^ (d & 7)) * 8), Vl + idx * 8);
    }
}

__global__ __launch_bounds__(256, 2) void flash_kernel(
    const unsigned short* __restrict__ Q,
    const unsigned short* __restrict__ Kg,
    const unsigned short* __restrict__ Vt,
    unsigned short* __restrict__ Og)
{
    __shared__ unsigned short Klds[2][64 * 128];
    __shared__ unsigned short Vlds[2][128 * 64];

    const int tid = threadIdx.x;
    const int lane = tid & 63, wid = tid >> 6;
    const int lc = lane & 31, hi = lane >> 5;

    const int blk = blockIdx.x;
    const int jj = blk >> 5;
    const int qt = (jj < 8) ? jj : 23 - jj;
    const int bh = blk & 31;
    const int b = bh >> 4, h = bh & 15;
    const size_t base = (size_t)b * S_LEN * D_MODEL;
    const unsigned short* kgh = Kg + base + h * D_HEAD;
    const unsigned short* vtb = Vt + (size_t)bh * D_HEAD * S_LEN;

    const int q0w = qt * 128 + wid * 32;
    const int qcol = q0w + lc;

    bf16x8 qf[8];
    #pragma unroll
    for (int dc = 0; dc < 8; ++dc)
        qf[dc] = *(const bf16x8*)&Q[base + (size_t)qcol * D_MODEL + h * D_HEAD + dc * 16 + hi * 8];

    f32x16 o_acc[4];
    #pragma unroll
    for (int dt = 0; dt < 4; ++dt)
        #pragma unroll
        for (int r = 0; r < 16; ++r) o_acc[dt][r] = 0.f;
    float m_r = -3e38f, l_r = 0.f;

    const int kxor = lc & 7;
    const int nt = 2 * qt + 2;

    flash_stage(kgh, vtb, Klds[0], Vlds[0], 0, tid);

    #pragma unroll 1
    for (int t = 0; t < nt; ++t) {
        const int bb = t & 1;
        const int kv0 = t * 64;
        __syncthreads();
        if (t + 1 < nt)
            flash_stage(kgh, vtb, Klds[bb ^ 1], Vlds[bb ^ 1], (t + 1) * 64, tid);

        f32x16 s0a, s0b, s1a, s1b;
        #pragma unroll
        for (int r = 0; r < 16; ++r) { s0a[r] = 0.f; s0b[r] = 0.f; s1a[r] = 0.f; s1b[r] = 0.f; }
        __builtin_amdgcn_s_setprio(1);
        #pragma unroll
        for (int dc = 0; dc < 4; ++dc) {
            bf16x8 kf0 = *(const bf16x8*)&Klds[bb][lc * 128 + (((dc * 2 + hi) ^ kxor) * 8)];
            bf16x8 kf1 = *(const bf16x8*)&Klds[bb][(32 + lc) * 128 + (((dc * 2 + hi) ^ kxor) * 8)];
            s0a = __builtin_amdgcn_mfma_f32_32x32x16_bf16(kf0, qf[dc], s0a, 0, 0, 0);
            s1a = __builtin_amdgcn_mfma_f32_32x32x16_bf16(kf1, qf[dc], s1a, 0, 0, 0);
        }
        #pragma unroll
        for (int dc = 4; dc < 8; ++dc) {
            bf16x8 kf0 = *(const bf16x8*)&Klds[bb][lc * 128 + (((dc * 2 + hi) ^ kxor) * 8)];
            bf16x8 kf1 = *(const bf16x8*)&Klds[bb][(32 + lc) * 128 + (((dc * 2 + hi) ^ kxor) * 8)];
            s0b = __builtin_amdgcn_mfma_f32_32x32x16_bf16(kf0, qf[dc], s0b, 0, 0, 0);
            s1b = __builtin_amdgcn_mfma_f32_32x32x16_bf16(kf1, qf[dc], s1b, 0, 0, 0);
        }
        __builtin_amdgcn_s_setprio(0);
        f32x16 s0 = s0a + s0b;
        f32x16 s1 = s1a + s1b;

        if (t >= nt - 2) {
            #pragma unroll
            for (int r = 0; r < 16; ++r) {
                int krow = (r & 3) + 8 * (r >> 2) + 4 * hi;
                if (kv0 + krow > qcol)      s0[r] = -3e38f;
                if (kv0 + 32 + krow > qcol) s1[r] = -3e38f;
            }
        }

        float mt[8];
        #pragma unroll
        for (int i = 0; i < 8; ++i)
            mt[i] = fmaxf(fmaxf(s0[2 * i], s0[2 * i + 1]), fmaxf(s1[2 * i], s1[2 * i + 1]));
        float mA = fmaxf(fmaxf(mt[0], mt[1]), fmaxf(mt[2], mt[3]));
        float mB = fmaxf(fmaxf(mt[4], mt[5]), fmaxf(mt[6], mt[7]));
        float sm = fmaxf(mA, mB);
        sm = fmaxf(sm, __shfl_xor(sm, 32));

        if (__any(sm > m_r + 11.5f)) {
            float mnew = fmaxf(m_r, sm);
            float alpha = exp2_hw(m_r - mnew);
            l_r *= alpha;
            m_r = mnew;
            #pragma unroll
            for (int r = 0; r < 16; ++r) {
                float av = __shfl(alpha, (r & 3) + 8 * (r >> 2) + 4 * hi);
                #pragma unroll
                for (int dt = 0; dt < 4; ++dt) o_acc[dt][r] *= av;
            }
        }

        #pragma unroll
        for (int r = 0; r < 16; ++r) {
            s0[r] = exp2_hw(s0[r] - m_r);
            s1[r] = exp2_hw(s1[r] - m_r);
        }
        float st[8];
        #pragma unroll
        for (int i = 0; i < 8; ++i)
            st[i] = (s0[2 * i] + s0[2 * i + 1]) + (s1[2 * i] + s1[2 * i + 1]);
        l_r += ((st[0] + st[1]) + (st[2] + st[3])) + ((st[4] + st[5]) + (st[6] + st[7]));

        #pragma unroll
        for (int t32 = 0; t32 < 2; ++t32) {
            const f32x16& s = t32 ? s1 : s0;
            unsigned int c0[4], c1[4];
            #pragma unroll
            for (int g = 0; g < 4; ++g) {
                c0[g] = cvtpk_bf16(s[4 * g],     s[4 * g + 1]);
                c1[g] = cvtpk_bf16(s[4 * g + 2], s[4 * g + 3]);
            }
            #pragma unroll
            for (int kt = 0; kt < 2; ++kt) {
                unsigned int sel0 = hi ? c0[2 * kt] : c0[2 * kt + 1];
                unsigned int sel1 = hi ? c1[2 * kt] : c1[2 * kt + 1];
                unsigned int o0 = (unsigned int)__shfl_xor((int)sel0, 32);
                unsigned int o1 = (unsigned int)__shfl_xor((int)sel1, 32);
                u32x4 uu;
                uu.x = hi ? o0 : c0[2 * kt];
                uu.y = hi ? o1 : c1[2 * kt];
                uu.z = hi ? c0[2 * kt + 1] : o0;
                uu.w = hi ? c1[2 * kt + 1] : o1;
                bf16x8 pf = __builtin_bit_cast(bf16x8, uu);
                __builtin_amdgcn_s_setprio(1);
                #pragma unroll
                for (int dt = 0; dt < 4; ++dt) {
                    bf16x8 vf = *(const bf16x8*)
                        &Vlds[bb][(dt * 32 + lc) * 64 + (((t32 * 4 + kt * 2 + hi) ^ kxor) * 8)];
                    o_acc[dt] = __builtin_amdgcn_mfma_f32_32x32x16_bf16(pf, vf, o_acc[dt], 0, 0, 0);
                }
                __builtin_amdgcn_s_setprio(0);
            }
        }
    }

    float lt = l_r + __shfl_xor(l_r, 32);
    float inv = 1.0f / lt;
    #pragma unroll
    for (int r = 0; r < 16; ++r) {
        int qrow = (r & 3) + 8 * (r >> 2) + 4 * hi;
        float iv = __shfl(inv, qrow);
        #pragma unroll
        for (int dt = 0; dt < 4; ++dt)
            Og[base + (size_t)(q0w + qrow) * D_MODEL + h * D_HEAD + dt * 32 + lc] =
                f2bf(o_acc[dt][r] * iv);
    }
}

// ---------------------------------------------------------------------------
extern "C" void kernel_launch(void* const* d_in, const int* in_sizes, int n_in,
                              void* d_out, int out_size, void* d_ws, size_t ws_size,
                              hipStream_t stream)
{
    const float* queries = (const float*)d_in[0];
    const float* keys    = (const float*)d_in[1];
    const float* values  = (const float*)d_in[2];
    const float* Wq  = (const float*)d_in[3];
    const float* bq  = (const float*)d_in[4];
    const float* Wlk = (const float*)d_in[5];
    const float* blk = (const float*)d_in[6];
    const float* Wlv = (const float*)d_in[7];
    const float* blv = (const float*)d_in[8];
    const float* Wkr = (const float*)d_in[9];
    const float* bkr = (const float*)d_in[10];
    const float* Wvr = (const float*)d_in[11];
    const float* bvr = (const float*)d_in[12];
    const float* Wo  = (const float*)d_in[13];
    const float* bo  = (const float*)d_in[14];
    float* out = (float*)d_out;

    char* ws = (char*)d_ws;
    const size_t MB = 1024 * 1024;
    unsigned short* abf_q = (unsigned short*)(ws);            // 16MB; ao aliases
    unsigned short* abf_k = (unsigned short*)(ws + 16 * MB);  // 16MB; WoT aliases
    unsigned short* abf_v = (unsigned short*)(ws + 32 * MB);
    unsigned short* q_bf  = (unsigned short*)(ws + 48 * MB);
    unsigned short* k_bf  = (unsigned short*)(ws + 64 * MB);
    unsigned short* v_t   = (unsigned short*)(ws + 80 * MB);
    unsigned short* lat_k = (unsigned short*)(ws + 96 * MB);   // 8MB
    unsigned short* lat_v = (unsigned short*)(ws + 104 * MB);  // 8MB
    unsigned short* WqT   = (unsigned short*)(ws + 112 * MB);  // 8MB
    unsigned short* WlkT  = (unsigned short*)(ws + 120 * MB);  // 4MB
    unsigned short* WlvT  = (unsigned short*)(ws + 124 * MB);  // 4MB
    unsigned short* WkrT  = (unsigned short*)(ws + 128 * MB);  // 16KB
    unsigned short* WvrT  = WkrT + 128 * 64;
    unsigned short* ao    = abf_q;   // dead after stage1
    unsigned short* WoT   = abf_k;   // dead after stage1 (8MB of its 16MB)

    prep_kernel<<<15361, 256, 0, stream>>>(
        queries, keys, values, Wq, Wlk, Wlv, Wkr, Wvr,
        abf_q, abf_k, abf_v, WqT, WlkT, WlvT, WkrT, WvrT);

    stage1_kernel<<<1024, 256, 0, stream>>>(
        abf_q, abf_k, abf_v, WqT, WlkT, WlvT, bq, blk, blv,
        q_bf, lat_k, lat_v);

    transpose_one_kernel<<<dim3(32, 32), 256, 0, stream>>>(Wo, WoT);

    recon_kernel<<<1024, 256, 0, stream>>>(
        lat_k, lat_v, WkrT, WvrT, bkr, bvr, k_bf, v_t);

    flash_kernel<<<512, 256, 0, stream>>>(q_bf, k_bf, v_t, ao);

    out_gemm_kernel<<<512, 256, 0, stream>>>(ao, WoT, bo, out);
}

// Round 8
// 269.411 us; speedup vs baseline: 1.3564x; 1.0048x over previous
//
#include <hip/hip_runtime.h>
#include <hip/hip_bf16.h>

#define B_SZ    2
#define S_LEN   2048
#define D_MODEL 2048
#define N_HEADS 16
#define D_HEAD  128
#define L_RANK  64
#define M_ROWS  (B_SZ * S_LEN)   // 4096
#define KD      2048             // GEMM K
#define NT      (KD / 32)        // 64 K-steps

typedef short          bf16x8 __attribute__((ext_vector_type(8)));
typedef float          f32x4  __attribute__((ext_vector_type(4)));
typedef float          f32x16 __attribute__((ext_vector_type(16)));
typedef unsigned short us4v   __attribute__((ext_vector_type(4)));
typedef unsigned short us8v   __attribute__((ext_vector_type(8)));
typedef unsigned int   u32x4  __attribute__((ext_vector_type(4)));

// log2(e) / sqrt(128), folded into the Q projection epilogue
#define SCALE_Q 0.127517432f

static __device__ __forceinline__ unsigned short f2bf(float f) {
    unsigned int u = __float_as_uint(f);
    u += 0x7FFFu + ((u >> 16) & 1u);      // RNE; inputs finite
    return (unsigned short)(u >> 16);
}

static __device__ __forceinline__ void gload16(const void* g, void* l) {
    __builtin_amdgcn_global_load_lds(
        (const __attribute__((address_space(1))) unsigned int*)g,
        (__attribute__((address_space(3))) unsigned int*)l, 16, 0, 0);
}

static __device__ __forceinline__ float exp2_hw(float x) {
    float r; asm("v_exp_f32 %0, %1" : "=v"(r) : "v"(x)); return r;
}
static __device__ __forceinline__ unsigned int cvtpk_bf16(float a, float b) {
    unsigned int r; asm("v_cvt_pk_bf16_f32 %0, %1, %2" : "=v"(r) : "v"(a), "v"(b)); return r;
}

// ---------------------------------------------------------------------------
// Fused prep:
//   [0,12288)      fp32->bf16 conv of q/k/v (4096 blocks each)
//   [12288,15360)  64x64 transposes of Wq (1024), Wlk (512+pad), Wlv
//   [15360,16384)  64x64 transposes of Wo (1024)
//   16384          Wkr/Wvr mini transpose (fp32 [64][128] -> bf16 [128][64])
// ---------------------------------------------------------------------------
__global__ __launch_bounds__(256) void prep_kernel(
    const float* __restrict__ q_in, const float* __restrict__ k_in,
    const float* __restrict__ v_in,
    const float* __restrict__ Wq, const float* __restrict__ Wlk,
    const float* __restrict__ Wlv, const float* __restrict__ Wo,
    const float* __restrict__ Wkr, const float* __restrict__ Wvr,
    unsigned short* __restrict__ q_o, unsigned short* __restrict__ k_o,
    unsigned short* __restrict__ v_o,
    unsigned short* __restrict__ WqT, unsigned short* __restrict__ WlkT,
    unsigned short* __restrict__ WlvT, unsigned short* __restrict__ WoT,
    unsigned short* __restrict__ WkrT, unsigned short* __restrict__ WvrT)
{
    __shared__ float tl[64][69];
    const int bid = blockIdx.x, tid = threadIdx.x;

    if (bid < 12288) {
        const int z = bid >> 12;
        const float* in = z == 0 ? q_in : (z == 1 ? k_in : v_in);
        unsigned short* out = z == 0 ? q_o : (z == 1 ? k_o : v_o);
        size_t i = ((size_t)(bid & 4095) * 256 + tid) * 8;
        float4 a = *(const float4*)&in[i];
        float4 b = *(const float4*)&in[i + 4];
        us8v o = { f2bf(a.x), f2bf(a.y), f2bf(a.z), f2bf(a.w),
                   f2bf(b.x), f2bf(b.y), f2bf(b.z), f2bf(b.w) };
        *(us8v*)&out[i] = o;
    } else if (bid < 16384) {
        const int t = bid - 12288;
        const int z = t >> 10;               // 0:Wq 1:Wlk 2:Wlv 3:Wo
        const int y = (t & 1023) >> 5, x = t & 31;
        const int Nz = (z == 1 || z == 2) ? 1024 : 2048;
        if (x * 64 >= Nz) return;
        const float* W = z == 0 ? Wq : (z == 1 ? Wlk : (z == 2 ? Wlv : Wo));
        unsigned short* WT = z == 0 ? WqT : (z == 1 ? WlkT : (z == 2 ? WlvT : WoT));
        const int k0 = y * 64, n0 = x * 64;
        #pragma unroll
        for (int c = 0; c < 4; ++c) {
            int idx = c * 256 + tid;
            int r = idx >> 4, c4 = (idx & 15) * 4;
            float4 v = *(const float4*)&W[(size_t)(k0 + r) * Nz + n0 + c4];
            tl[r][c4] = v.x; tl[r][c4 + 1] = v.y; tl[r][c4 + 2] = v.z; tl[r][c4 + 3] = v.w;
        }
        __syncthreads();
        #pragma unroll
        for (int c = 0; c < 2; ++c) {
            int idx = c * 256 + tid;
            int nr = idx >> 3, s = idx & 7;
            us8v o;
            #pragma unroll
            for (int j = 0; j < 8; ++j) o[j] = f2bf(tl[s * 8 + j][nr]);
            *(us8v*)&WT[(size_t)(n0 + nr) * KD + k0 + s * 8] = o;
        }
    } else {
        #pragma unroll 1
        for (int t2 = 0; t2 < 2; ++t2) {
            const float* W = t2 ? Wvr : Wkr;
            unsigned short* WT = t2 ? WvrT : WkrT;
            for (int i = 0; i < 32; ++i) {
                int e = i * 256 + tid;
                int d = e >> 6, l = e & 63;
                WT[d * 64 + l] = f2bf(W[l * 128 + d]);
            }
        }
    }
}

// ---------------------------------------------------------------------------
// Stage-1 batched GEMM (proven core): z=0: q = Xq@WqT^T (+bq)*SCALE_Q,
// N=2048; z=1: lat_k = Xk@WlkT^T + blk, N=1024; z=2: lat_v, N=1024.
// 128x128 tile, BK=32, dbuf, one barrier per K-step, gload_lds both operands.
// ---------------------------------------------------------------------------
__global__ __launch_bounds__(256) void stage1_kernel(
    const unsigned short* __restrict__ Aq, const unsigned short* __restrict__ Ak,
    const unsigned short* __restrict__ Av,
    const unsigned short* __restrict__ WqT, const unsigned short* __restrict__ WlkT,
    const unsigned short* __restrict__ WlvT,
    const float* __restrict__ bq, const float* __restrict__ blk,
    const float* __restrict__ blv,
    unsigned short* __restrict__ q_bf, unsigned short* __restrict__ lat_k,
    unsigned short* __restrict__ lat_v)
{
    __shared__ unsigned short Al[2][128 * 32];
    __shared__ unsigned short Bl[2][128 * 32];

    const int flat = blockIdx.x;
    const int swz = (flat & 7) * 128 + (flat >> 3);   // 1024 = 8*128
    int z, rem;
    if (swz < 512)      { z = 0; rem = swz; }
    else if (swz < 768) { z = 1; rem = swz - 512; }
    else                { z = 2; rem = swz - 768; }
    int row0, col0, Nz;
    if (z == 0) { row0 = (rem >> 4) * 128; col0 = (rem & 15) * 128; Nz = 2048; }
    else        { row0 = (rem >> 3) * 128; col0 = (rem & 7) * 128;  Nz = 1024; }

    const unsigned short* A    = z == 0 ? Aq  : (z == 1 ? Ak   : Av);
    const unsigned short* Bt   = z == 0 ? WqT : (z == 1 ? WlkT : WlvT);
    const float*          bias = z == 0 ? bq  : (z == 1 ? blk  : blv);
    unsigned short*       C    = z == 0 ? q_bf : (z == 1 ? lat_k : lat_v);

    const int tid = threadIdx.x;
    const int lane = tid & 63, wid = tid >> 6;
    const int lr = lane & 15, lg = lane >> 4;
    const int wr = wid >> 1, wc = wid & 1;

    const unsigned short* ag[2];
    const unsigned short* bg[2];
    unsigned short* alp[2][2];
    unsigned short* blp[2][2];
    #pragma unroll
    for (int c = 0; c < 2; ++c) {
        int idx = wid * 128 + c * 64 + lane;
        int row = idx >> 2, p = idx & 3;
        int sp = p ^ ((row >> 1) & 3);
        ag[c] = A  + (size_t)(row0 + row) * KD + sp * 8;
        bg[c] = Bt + (size_t)(col0 + row) * KD + sp * 8;
        alp[0][c] = Al[0] + idx * 8;  alp[1][c] = Al[1] + idx * 8;
        blp[0][c] = Bl[0] + idx * 8;  blp[1][c] = Bl[1] + idx * 8;
    }
    const int sx = (lr >> 1) & 3;
    const int abase = (wr * 64 + lr) * 32 + ((lg ^ sx) * 8);
    const int bbase = (wc * 64 + lr) * 32 + ((lg ^ sx) * 8);

    f32x4 acc[4][4];
    #pragma unroll
    for (int m = 0; m < 4; ++m)
        #pragma unroll
        for (int n = 0; n < 4; ++n) acc[m][n] = (f32x4){0.f, 0.f, 0.f, 0.f};

    #pragma unroll
    for (int c = 0; c < 2; ++c) { gload16(ag[c], alp[0][c]); gload16(bg[c], blp[0][c]); }
    __syncthreads();

    #pragma unroll 1
    for (int t = 0; t < NT; ++t) {
        const int cur = t & 1, nxt = cur ^ 1;
        if (t + 1 < NT) {
            #pragma unroll
            for (int c = 0; c < 2; ++c) {
                gload16(ag[c] + (size_t)(t + 1) * 32, alp[nxt][c]);
                gload16(bg[c] + (size_t)(t + 1) * 32, blp[nxt][c]);
            }
        }
        bf16x8 af[4], bfv[4];
        #pragma unroll
        for (int m = 0; m < 4; ++m) af[m]  = *(const bf16x8*)&Al[cur][abase + m * 512];
        #pragma unroll
        for (int n = 0; n < 4; ++n) bfv[n] = *(const bf16x8*)&Bl[cur][bbase + n * 512];
        __builtin_amdgcn_s_setprio(1);
        #pragma unroll
        for (int m = 0; m < 4; ++m)
            #pragma unroll
            for (int n = 0; n < 4; ++n)
                acc[m][n] = __builtin_amdgcn_mfma_f32_16x16x32_bf16(af[m], bfv[n], acc[m][n], 0, 0, 0);
        __builtin_amdgcn_s_setprio(0);
        __syncthreads();
    }

    float bv[4];
    #pragma unroll
    for (int n = 0; n < 4; ++n) bv[n] = bias[col0 + wc * 64 + n * 16 + lr];
    const float omul = (z == 0) ? SCALE_Q : 1.0f;

    #pragma unroll
    for (int m = 0; m < 4; ++m) {
        #pragma unroll
        for (int n = 0; n < 4; ++n) {
            const int col = col0 + wc * 64 + n * 16 + lr;
            const int rowb = row0 + wr * 64 + m * 16 + lg * 4;
            #pragma unroll
            for (int j = 0; j < 4; ++j)
                C[(size_t)(rowb + j) * Nz + col] = f2bf((acc[m][n][j] + bv[n]) * omul);
        }
    }
}

// ---------------------------------------------------------------------------
// Stage-2 recon (K=64): z=0: k -> k_bf[s][h*128+d]; z=1: v -> v_t.
// ---------------------------------------------------------------------------
__global__ __launch_bounds__(256) void recon_kernel(
    const unsigned short* __restrict__ lat_k, const unsigned short* __restrict__ lat_v,
    const unsigned short* __restrict__ WkrT, const unsigned short* __restrict__ WvrT,
    const float* __restrict__ bkr, const float* __restrict__ bvr,
    unsigned short* __restrict__ k_bf, unsigned short* __restrict__ v_t)
{
    __shared__ unsigned short Alds[128 * 64];
    __shared__ unsigned short Blds[128 * 64];

    const int flat = blockIdx.x;
    const int swz = (flat & 7) * 128 + (flat >> 3);   // 1024 = 8*128
    const int z = swz >> 9;
    const int rem = swz & 511;
    const int h = rem >> 5;
    const int r0 = (rem & 31) * 128;

    const unsigned short* lat = z ? lat_v : lat_k;
    const unsigned short* WT  = z ? WvrT : WkrT;
    const float* bias = z ? bvr : bkr;

    const int tid = threadIdx.x;
    const int lane = tid & 63, wid = tid >> 6;
    const int lr = lane & 15, lg = lane >> 4;
    const int wm = wid >> 1, wn = wid & 1;

    #pragma unroll
    for (int c = 0; c < 4; ++c) {
        int e = c * 256 + tid;
        int row = e >> 3, pc = e & 7;
        gload16(lat + (size_t)(r0 + row) * 1024 + h * 64 + ((pc ^ (row & 7)) * 8),
                Alds + e * 8);
    }
    #pragma unroll
    for (int c = 0; c < 4; ++c) {
        int e = c * 256 + tid;
        int d = e >> 3, pc = e & 7;
        gload16(WT + (size_t)d * 64 + ((pc ^ (d & 7)) * 8), Blds + e * 8);
    }
    __syncthreads();

    f32x4 acc[4][4];
    #pragma unroll
    for (int m = 0; m < 4; ++m)
        #pragma unroll
        for (int n = 0; n < 4; ++n) acc[m][n] = (f32x4){0.f, 0.f, 0.f, 0.f};

    #pragma unroll
    for (int ks = 0; ks < 2; ++ks) {
        bf16x8 af[4], bfv[4];
        #pragma unroll
        for (int m = 0; m < 4; ++m) {
            int row = wm * 64 + m * 16 + lr;
            af[m] = *(const bf16x8*)&Alds[row * 64 + (((ks * 4 + lg) ^ (row & 7)) * 8)];
        }
        #pragma unroll
        for (int n = 0; n < 4; ++n) {
            int row = wn * 64 + n * 16 + lr;
            bfv[n] = *(const bf16x8*)&Blds[row * 64 + (((ks * 4 + lg) ^ (row & 7)) * 8)];
        }
        #pragma unroll
        for (int m = 0; m < 4; ++m)
            #pragma unroll
            for (int n = 0; n < 4; ++n)
                acc[m][n] = __builtin_amdgcn_mfma_f32_16x16x32_bf16(af[m], bfv[n], acc[m][n], 0, 0, 0);
    }

    const int b = r0 >> 11;
    float bv[4];
    #pragma unroll
    for (int n = 0; n < 4; ++n) bv[n] = bias[wn * 64 + n * 16 + lr];

    #pragma unroll
    for (int m = 0; m < 4; ++m) {
        #pragma unroll
        for (int n = 0; n < 4; ++n) {
            const int d = wn * 64 + n * 16 + lr;
            const int rowb = r0 + wm * 64 + m * 16 + lg * 4;
            if (z == 0) {
                #pragma unroll
                for (int j = 0; j < 4; ++j)
                    k_bf[(size_t)(rowb + j) * D_MODEL + h * D_HEAD + d] =
                        f2bf(acc[m][n][j] + bv[n]);
            } else {
                us4v o = { f2bf(acc[m][n][0] + bv[n]), f2bf(acc[m][n][1] + bv[n]),
                           f2bf(acc[m][n][2] + bv[n]), f2bf(acc[m][n][3] + bv[n]) };
                *(us4v*)&v_t[((size_t)(b * 16 + h) * 128 + d) * 2048 + (rowb & 2047)] = o;
            }
        }
    }
}

// ---------------------------------------------------------------------------
// Output GEMM (proven): out fp32 = ao @ WoT^T + bo.  Grid 512.
// ---------------------------------------------------------------------------
__global__ __launch_bounds__(256) void out_gemm_kernel(
    const unsigned short* __restrict__ A,
    const unsigned short* __restrict__ Bt,
    const float* __restrict__ bias,
    float* __restrict__ C)
{
    __shared__ unsigned short Al[2][128 * 32];
    __shared__ unsigned short Bl[2][128 * 32];

    const int flat = blockIdx.x;
    const int swz = (flat & 7) * 64 + (flat >> 3);   // 512 = 8 * 64
    const int row0 = (swz >> 4) * 128, col0 = (swz & 15) * 128;

    const int tid = threadIdx.x;
    const int lane = tid & 63, wid = tid >> 6;
    const int lr = lane & 15, lg = lane >> 4;
    const int wr = wid >> 1, wc = wid & 1;

    const unsigned short* ag[2];
    const unsigned short* bg[2];
    unsigned short* alp[2][2];
    unsigned short* blp[2][2];
    #pragma unroll
    for (int c = 0; c < 2; ++c) {
        int idx = wid * 128 + c * 64 + lane;
        int row = idx >> 2, p = idx & 3;
        int sp = p ^ ((row >> 1) & 3);
        ag[c] = A  + (size_t)(row0 + row) * KD + sp * 8;
        bg[c] = Bt + (size_t)(col0 + row) * KD + sp * 8;
        alp[0][c] = Al[0] + idx * 8;  alp[1][c] = Al[1] + idx * 8;
        blp[0][c] = Bl[0] + idx * 8;  blp[1][c] = Bl[1] + idx * 8;
    }
    const int sx = (lr >> 1) & 3;
    const int abase = (wr * 64 + lr) * 32 + ((lg ^ sx) * 8);
    const int bbase = (wc * 64 + lr) * 32 + ((lg ^ sx) * 8);

    f32x4 acc[4][4];
    #pragma unroll
    for (int m = 0; m < 4; ++m)
        #pragma unroll
        for (int n = 0; n < 4; ++n) acc[m][n] = (f32x4){0.f, 0.f, 0.f, 0.f};

    #pragma unroll
    for (int c = 0; c < 2; ++c) { gload16(ag[c], alp[0][c]); gload16(bg[c], blp[0][c]); }
    __syncthreads();

    #pragma unroll 1
    for (int t = 0; t < NT; ++t) {
        const int cur = t & 1, nxt = cur ^ 1;
        if (t + 1 < NT) {
            #pragma unroll
            for (int c = 0; c < 2; ++c) {
                gload16(ag[c] + (size_t)(t + 1) * 32, alp[nxt][c]);
                gload16(bg[c] + (size_t)(t + 1) * 32, blp[nxt][c]);
            }
        }
        bf16x8 af[4], bfv[4];
        #pragma unroll
        for (int m = 0; m < 4; ++m) af[m]  = *(const bf16x8*)&Al[cur][abase + m * 512];
        #pragma unroll
        for (int n = 0; n < 4; ++n) bfv[n] = *(const bf16x8*)&Bl[cur][bbase + n * 512];
        __builtin_amdgcn_s_setprio(1);
        #pragma unroll
        for (int m = 0; m < 4; ++m)
            #pragma unroll
            for (int n = 0; n < 4; ++n)
                acc[m][n] = __builtin_amdgcn_mfma_f32_16x16x32_bf16(af[m], bfv[n], acc[m][n], 0, 0, 0);
        __builtin_amdgcn_s_setprio(0);
        __syncthreads();
    }

    float bv[4];
    #pragma unroll
    for (int n = 0; n < 4; ++n) bv[n] = bias[col0 + wc * 64 + n * 16 + lr];
    #pragma unroll
    for (int m = 0; m < 4; ++m)
        #pragma unroll
        for (int n = 0; n < 4; ++n) {
            const int col = col0 + wc * 64 + n * 16 + lr;
            const int rowb = row0 + wr * 64 + m * 16 + lg * 4;
            #pragma unroll
            for (int j = 0; j < 4; ++j)
                C[(size_t)(rowb + j) * D_MODEL + col] = acc[m][n][j] + bv[n];
        }
}

// ---------------------------------------------------------------------------
// Causal flash attention, swapped-QK 32x32x16.  HEAVY-FIRST block order:
// jj<8 -> qt=15-jj (heavy blocks dispatch first onto all CUs), jj>=8 ->
// qt=jj-8 (light partners backfill); per-CU pair totals 34 KV tiles.
// ---------------------------------------------------------------------------
static __device__ __forceinline__ void flash_stage(
    const unsigned short* __restrict__ kgh,
    const unsigned short* __restrict__ vtb,
    unsigned short* Kl, unsigned short* Vl, int kv0, int tid)
{
    #pragma unroll
    for (int c = 0; c < 4; ++c) {
        int idx = c * 256 + tid;
        int r = idx >> 4, ch = idx & 15;
        gload16(kgh + (size_t)(kv0 + r) * D_MODEL + ((ch ^ (r & 7)) * 8), Kl + idx * 8);
    }
    #pragma unroll
    for (int c = 0; c < 4; ++c) {
        int idx = c * 256 + tid;
        int d = idx >> 3, ch = idx & 7;
        gload16(vtb + (size_t)d * S_LEN + kv0 + ((ch ^ (d & 7)) * 8), Vl + idx * 8);
    }
}

__global__ __launch_bounds__(256, 2) void flash_kernel(
    const unsigned short* __restrict__ Q,
    const unsigned short* __restrict__ Kg,
    const unsigned short* __restrict__ Vt,
    unsigned short* __restrict__ Og)
{
    __shared__ unsigned short Klds[2][64 * 128];
    __shared__ unsigned short Vlds[2][128 * 64];

    const int tid = threadIdx.x;
    const int lane = tid & 63, wid = tid >> 6;
    const int lc = lane & 31, hi = lane >> 5;

    const int blk = blockIdx.x;
    const int jj = blk >> 5;
    const int qt = (jj < 8) ? (15 - jj) : (jj - 8);   // heavy first
    const int bh = blk & 31;
    const int b = bh >> 4, h = bh & 15;
    const size_t base = (size_t)b * S_LEN * D_MODEL;
    const unsigned short* kgh = Kg + base + h * D_HEAD;
    const unsigned short* vtb = Vt + (size_t)bh * D_HEAD * S_LEN;

    const int q0w = qt * 128 + wid * 32;
    const int qcol = q0w + lc;

    bf16x8 qf[8];
    #pragma unroll
    for (int dc = 0; dc < 8; ++dc)
        qf[dc] = *(const bf16x8*)&Q[base + (size_t)qcol * D_MODEL + h * D_HEAD + dc * 16 + hi * 8];

    f32x16 o_acc[4];
    #pragma unroll
    for (int dt = 0; dt < 4; ++dt)
        #pragma unroll
        for (int r = 0; r < 16; ++r) o_acc[dt][r] = 0.f;
    float m_r = -3e38f, l_r = 0.f;

    const int kxor = lc & 7;
    const int nt = 2 * qt + 2;

    flash_stage(kgh, vtb, Klds[0], Vlds[0], 0, tid);

    #pragma unroll 1
    for (int t = 0; t < nt; ++t) {
        const int bb = t & 1;
        const int kv0 = t * 64;
        __syncthreads();
        if (t + 1 < nt)
            flash_stage(kgh, vtb, Klds[bb ^ 1], Vlds[bb ^ 1], (t + 1) * 64, tid);

        f32x16 s0a, s0b, s1a, s1b;
        #pragma unroll
        for (int r = 0; r < 16; ++r) { s0a[r] = 0.f; s0b[r] = 0.f; s1a[r] = 0.f; s1b[r] = 0.f; }
        __builtin_amdgcn_s_setprio(1);
        #pragma unroll
        for (int dc = 0; dc < 4; ++dc) {
            bf16x8 kf0 = *(const bf16x8*)&Klds[bb][lc * 128 + (((dc * 2 + hi) ^ kxor) * 8)];
            bf16x8 kf1 = *(const bf16x8*)&Klds[bb][(32 + lc) * 128 + (((dc * 2 + hi) ^ kxor) * 8)];
            s0a = __builtin_amdgcn_mfma_f32_32x32x16_bf16(kf0, qf[dc], s0a, 0, 0, 0);
            s1a = __builtin_amdgcn_mfma_f32_32x32x16_bf16(kf1, qf[dc], s1a, 0, 0, 0);
        }
        #pragma unroll
        for (int dc = 4; dc < 8; ++dc) {
            bf16x8 kf0 = *(const bf16x8*)&Klds[bb][lc * 128 + (((dc * 2 + hi) ^ kxor) * 8)];
            bf16x8 kf1 = *(const bf16x8*)&Klds[bb][(32 + lc) * 128 + (((dc * 2 + hi) ^ kxor) * 8)];
            s0b = __builtin_amdgcn_mfma_f32_32x32x16_bf16(kf0, qf[dc], s0b, 0, 0, 0);
            s1b = __builtin_amdgcn_mfma_f32_32x32x16_bf16(kf1, qf[dc], s1b, 0, 0, 0);
        }
        __builtin_amdgcn_s_setprio(0);
        f32x16 s0 = s0a + s0b;
        f32x16 s1 = s1a + s1b;

        if (t >= nt - 2) {
            #pragma unroll
            for (int r = 0; r < 16; ++r) {
                int krow = (r & 3) + 8 * (r >> 2) + 4 * hi;
                if (kv0 + krow > qcol)      s0[r] = -3e38f;
                if (kv0 + 32 + krow > qcol) s1[r] = -3e38f;
            }
        }

        float mt[8];
        #pragma unroll
        for (int i = 0; i < 8; ++i)
            mt[i] = fmaxf(fmaxf(s0[2 * i], s0[2 * i + 1]), fmaxf(s1[2 * i], s1[2 * i + 1]));
        float mA = fmaxf(fmaxf(mt[0], mt[1]), fmaxf(mt[2], mt[3]));
        float mB = fmaxf(fmaxf(mt[4], mt[5]), fmaxf(mt[6], mt[7]));
        float sm = fmaxf(mA, mB);
        sm = fmaxf(sm, __shfl_xor(sm, 32));

        if (__any(sm > m_r + 11.5f)) {
            float mnew = fmaxf(m_r, sm);
            float alpha = exp2_hw(m_r - mnew);
            l_r *= alpha;
            m_r = mnew;
            #pragma unroll
            for (int r = 0; r < 16; ++r) {
                float av = __shfl(alpha, (r & 3) + 8 * (r >> 2) + 4 * hi);
                #pragma unroll
                for (int dt = 0; dt < 4; ++dt) o_acc[dt][r] *= av;
            }
        }

        #pragma unroll
        for (int r = 0; r < 16; ++r) {
            s0[r] = exp2_hw(s0[r] - m_r);
            s1[r] = exp2_hw(s1[r] - m_r);
        }
        float st[8];
        #pragma unroll
        for (int i = 0; i < 8; ++i)
            st[i] = (s0[2 * i] + s0[2 * i + 1]) + (s1[2 * i] + s1[2 * i + 1]);
        l_r += ((st[0] + st[1]) + (st[2] + st[3])) + ((st[4] + st[5]) + (st[6] + st[7]));

        #pragma unroll
        for (int t32 = 0; t32 < 2; ++t32) {
            const f32x16& s = t32 ? s1 : s0;
            unsigned int c0[4], c1[4];
            #pragma unroll
            for (int g = 0; g < 4; ++g) {
                c0[g] = cvtpk_bf16(s[4 * g],     s[4 * g + 1]);
                c1[g] = cvtpk_bf16(s[4 * g + 2], s[4 * g + 3]);
            }
            #pragma unroll
            for (int kt = 0; kt < 2; ++kt) {
                unsigned int sel0 = hi ? c0[2 * kt] : c0[2 * kt + 1];
                unsigned int sel1 = hi ? c1[2 * kt] : c1[2 * kt + 1];
                unsigned int o0 = (unsigned int)__shfl_xor((int)sel0, 32);
                unsigned int o1 = (unsigned int)__shfl_xor((int)sel1, 32);
                u32x4 uu;
                uu.x = hi ? o0 : c0[2 * kt];
                uu.y = hi ? o1 : c1[2 * kt];
                uu.z = hi ? c0[2 * kt + 1] : o0;
                uu.w = hi ? c1[2 * kt + 1] : o1;
                bf16x8 pf = __builtin_bit_cast(bf16x8, uu);
                __builtin_amdgcn_s_setprio(1);
                #pragma unroll
                for (int dt = 0; dt < 4; ++dt) {
                    bf16x8 vf = *(const bf16x8*)
                        &Vlds[bb][(dt * 32 + lc) * 64 + (((t32 * 4 + kt * 2 + hi) ^ kxor) * 8)];
                    o_acc[dt] = __builtin_amdgcn_mfma_f32_32x32x16_bf16(pf, vf, o_acc[dt], 0, 0, 0);
                }
                __builtin_amdgcn_s_setprio(0);
            }
        }
    }

    float lt = l_r + __shfl_xor(l_r, 32);
    float inv = 1.0f / lt;
    #pragma unroll
    for (int r = 0; r < 16; ++r) {
        int qrow = (r & 3) + 8 * (r >> 2) + 4 * hi;
        float iv = __shfl(inv, qrow);
        #pragma unroll
        for (int dt = 0; dt < 4; ++dt)
            Og[base + (size_t)(q0w + qrow) * D_MODEL + h * D_HEAD + dt * 32 + lc] =
                f2bf(o_acc[dt][r] * iv);
    }
}

// ---------------------------------------------------------------------------
extern "C" void kernel_launch(void* const* d_in, const int* in_sizes, int n_in,
                              void* d_out, int out_size, void* d_ws, size_t ws_size,
                              hipStream_t stream)
{
    const float* queries = (const float*)d_in[0];
    const float* keys    = (const float*)d_in[1];
    const float* values  = (const float*)d_in[2];
    const float* Wq  = (const float*)d_in[3];
    const float* bq  = (const float*)d_in[4];
    const float* Wlk = (const float*)d_in[5];
    const float* blk = (const float*)d_in[6];
    const float* Wlv = (const float*)d_in[7];
    const float* blv = (const float*)d_in[8];
    const float* Wkr = (const float*)d_in[9];
    const float* bkr = (const float*)d_in[10];
    const float* Wvr = (const float*)d_in[11];
    const float* bvr = (const float*)d_in[12];
    const float* Wo  = (const float*)d_in[13];
    const float* bo  = (const float*)d_in[14];
    float* out = (float*)d_out;

    char* ws = (char*)d_ws;
    const size_t MB = 1024 * 1024;
    unsigned short* abf_q = (unsigned short*)(ws);            // 16MB; ao aliases
    unsigned short* abf_k = (unsigned short*)(ws + 16 * MB);  // 16MB
    unsigned short* abf_v = (unsigned short*)(ws + 32 * MB);
    unsigned short* q_bf  = (unsigned short*)(ws + 48 * MB);
    unsigned short* k_bf  = (unsigned short*)(ws + 64 * MB);
    unsigned short* v_t   = (unsigned short*)(ws + 80 * MB);
    unsigned short* lat_k = (unsigned short*)(ws + 96 * MB);   // 8MB
    unsigned short* lat_v = (unsigned short*)(ws + 104 * MB);  // 8MB
    unsigned short* WqT   = (unsigned short*)(ws + 112 * MB);  // 8MB
    unsigned short* WlkT  = (unsigned short*)(ws + 120 * MB);  // 4MB
    unsigned short* WlvT  = (unsigned short*)(ws + 124 * MB);  // 4MB
    unsigned short* WkrT  = (unsigned short*)(ws + 128 * MB);  // 16KB
    unsigned short* WvrT  = WkrT + 128 * 64;
    unsigned short* WoT   = (unsigned short*)(ws + 129 * MB);  // 8MB
    unsigned short* ao    = abf_q;   // dead after stage1

    prep_kernel<<<16385, 256, 0, stream>>>(
        queries, keys, values, Wq, Wlk, Wlv, Wo, Wkr, Wvr,
        abf_q, abf_k, abf_v, WqT, WlkT, WlvT, WoT, WkrT, WvrT);

    stage1_kernel<<<1024, 256, 0, stream>>>(
        abf_q, abf_k, abf_v, WqT, WlkT, WlvT, bq, blk, blv,
        q_bf, lat_k, lat_v);

    recon_kernel<<<1024, 256, 0, stream>>>(
        lat_k, lat_v, WkrT, WvrT, bkr, bvr, k_bf, v_t);

    flash_kernel<<<512, 256, 0, stream>>>(q_bf, k_bf, v_t, ao);

    out_gemm_kernel<<<512, 256, 0, stream>>>(ao, WoT, bo, out);
}

// Round 9
// 242.218 us; speedup vs baseline: 1.5086x; 1.1123x over previous
//
#include <hip/hip_runtime.h>
#include <hip/hip_bf16.h>

#define B_SZ    2
#define S_LEN   2048
#define D_MODEL 2048
#define N_HEADS 16
#define D_HEAD  128
#define L_RANK  64
#define M_ROWS  (B_SZ * S_LEN)   // 4096
#define KD      2048             // GEMM K
#define NT      (KD / 32)        // 64 K-steps (128^2 kernels)
#define NTK     (KD / 64)        // 32 K-tiles (256^2 8-phase kernel)

typedef short          bf16x8 __attribute__((ext_vector_type(8)));
typedef float          f32x4  __attribute__((ext_vector_type(4)));
typedef float          f32x16 __attribute__((ext_vector_type(16)));
typedef unsigned short us4v   __attribute__((ext_vector_type(4)));
typedef unsigned short us8v   __attribute__((ext_vector_type(8)));
typedef unsigned int   u32x4  __attribute__((ext_vector_type(4)));

// log2(e) / sqrt(128), folded into the Q projection epilogue
#define SCALE_Q 0.127517432f

static __device__ __forceinline__ unsigned short f2bf(float f) {
    unsigned int u = __float_as_uint(f);
    u += 0x7FFFu + ((u >> 16) & 1u);      // RNE; inputs finite
    return (unsigned short)(u >> 16);
}

static __device__ __forceinline__ void gload16(const void* g, void* l) {
    __builtin_amdgcn_global_load_lds(
        (const __attribute__((address_space(1))) unsigned int*)g,
        (__attribute__((address_space(3))) unsigned int*)l, 16, 0, 0);
}

// compiler-invisible LDS read (defeats alias-driven auto vmcnt waits);
// MUST be followed by explicit lgkmcnt(0) + sched_barrier(0) before use.
static __device__ __forceinline__ bf16x8 ds_read128(const unsigned short* p) {
    bf16x8 r;
    unsigned int a = (unsigned int)(size_t)
        (const __attribute__((address_space(3))) unsigned short*)p;
    asm volatile("ds_read_b128 %0, %1" : "=&v"(r) : "v"(a));
    return r;
}

static __device__ __forceinline__ float exp2_hw(float x) {
    float r; asm("v_exp_f32 %0, %1" : "=v"(r) : "v"(x)); return r;
}
static __device__ __forceinline__ unsigned int cvtpk_bf16(float a, float b) {
    unsigned int r; asm("v_cvt_pk_bf16_f32 %0, %1, %2" : "=v"(r) : "v"(a), "v"(b)); return r;
}

// ---------------------------------------------------------------------------
// Fused prep (unchanged from R8)
// ---------------------------------------------------------------------------
__global__ __launch_bounds__(256) void prep_kernel(
    const float* __restrict__ q_in, const float* __restrict__ k_in,
    const float* __restrict__ v_in,
    const float* __restrict__ Wq, const float* __restrict__ Wlk,
    const float* __restrict__ Wlv, const float* __restrict__ Wo,
    const float* __restrict__ Wkr, const float* __restrict__ Wvr,
    unsigned short* __restrict__ q_o, unsigned short* __restrict__ k_o,
    unsigned short* __restrict__ v_o,
    unsigned short* __restrict__ WqT, unsigned short* __restrict__ WlkT,
    unsigned short* __restrict__ WlvT, unsigned short* __restrict__ WoT,
    unsigned short* __restrict__ WkrT, unsigned short* __restrict__ WvrT)
{
    __shared__ float tl[64][69];
    const int bid = blockIdx.x, tid = threadIdx.x;

    if (bid < 12288) {
        const int z = bid >> 12;
        const float* in = z == 0 ? q_in : (z == 1 ? k_in : v_in);
        unsigned short* out = z == 0 ? q_o : (z == 1 ? k_o : v_o);
        size_t i = ((size_t)(bid & 4095) * 256 + tid) * 8;
        float4 a = *(const float4*)&in[i];
        float4 b = *(const float4*)&in[i + 4];
        us8v o = { f2bf(a.x), f2bf(a.y), f2bf(a.z), f2bf(a.w),
                   f2bf(b.x), f2bf(b.y), f2bf(b.z), f2bf(b.w) };
        *(us8v*)&out[i] = o;
    } else if (bid < 16384) {
        const int t = bid - 12288;
        const int z = t >> 10;               // 0:Wq 1:Wlk 2:Wlv 3:Wo
        const int y = (t & 1023) >> 5, x = t & 31;
        const int Nz = (z == 1 || z == 2) ? 1024 : 2048;
        if (x * 64 >= Nz) return;
        const float* W = z == 0 ? Wq : (z == 1 ? Wlk : (z == 2 ? Wlv : Wo));
        unsigned short* WT = z == 0 ? WqT : (z == 1 ? WlkT : (z == 2 ? WlvT : WoT));
        const int k0 = y * 64, n0 = x * 64;
        #pragma unroll
        for (int c = 0; c < 4; ++c) {
            int idx = c * 256 + tid;
            int r = idx >> 4, c4 = (idx & 15) * 4;
            float4 v = *(const float4*)&W[(size_t)(k0 + r) * Nz + n0 + c4];
            tl[r][c4] = v.x; tl[r][c4 + 1] = v.y; tl[r][c4 + 2] = v.z; tl[r][c4 + 3] = v.w;
        }
        __syncthreads();
        #pragma unroll
        for (int c = 0; c < 2; ++c) {
            int idx = c * 256 + tid;
            int nr = idx >> 3, s = idx & 7;
            us8v o;
            #pragma unroll
            for (int j = 0; j < 8; ++j) o[j] = f2bf(tl[s * 8 + j][nr]);
            *(us8v*)&WT[(size_t)(n0 + nr) * KD + k0 + s * 8] = o;
        }
    } else {
        #pragma unroll 1
        for (int t2 = 0; t2 < 2; ++t2) {
            const float* W = t2 ? Wvr : Wkr;
            unsigned short* WT = t2 ? WvrT : WkrT;
            for (int i = 0; i < 32; ++i) {
                int e = i * 256 + tid;
                int d = e >> 6, l = e & 63;
                WT[d * 64 + l] = f2bf(W[l * 128 + d]);
            }
        }
    }
}

// ---------------------------------------------------------------------------
// Stage-1 batched GEMM, 256x256 tile, BK=64, 8 waves (2Mx4N), 8-phase-style
// schedule: asm ds_read_b128 (compiler-invisible), counted s_waitcnt vmcnt(4),
// raw s_barrier; 2 gates per K-tile, never a mid-loop drain.
// z=0: q = Xq@WqT^T (+bq)*SCALE_Q (N=2048); z=1/2: lat = X@WlT^T + bl (N=1024).
// grid 256 = one perfect round; XCD-bijective swizzle.
// ---------------------------------------------------------------------------
__global__ __launch_bounds__(512) void stage1_8p_kernel(
    const unsigned short* __restrict__ Aq, const unsigned short* __restrict__ Ak,
    const unsigned short* __restrict__ Av,
    const unsigned short* __restrict__ WqT, const unsigned short* __restrict__ WlkT,
    const unsigned short* __restrict__ WlvT,
    const float* __restrict__ bq, const float* __restrict__ blk,
    const float* __restrict__ blv,
    unsigned short* __restrict__ q_bf, unsigned short* __restrict__ lat_k,
    unsigned short* __restrict__ lat_v)
{
    // [buf][khalf][256 rows * 32 cols] bf16 = 16 KB per half; 64 KB per tensor
    __shared__ unsigned short Al[2][2][256 * 32];
    __shared__ unsigned short Bl[2][2][256 * 32];

    const int bid = blockIdx.x;
    const int swz = (bid & 7) * 32 + (bid >> 3);   // 256 blocks, bijective
    int z, rem, row0, col0, Nz;
    if (swz < 128)      { z = 0; rem = swz;       row0 = (rem >> 3) * 256; col0 = (rem & 7) * 256; Nz = 2048; }
    else if (swz < 192) { z = 1; rem = swz - 128; row0 = (rem >> 2) * 256; col0 = (rem & 3) * 256; Nz = 1024; }
    else                { z = 2; rem = swz - 192; row0 = (rem >> 2) * 256; col0 = (rem & 3) * 256; Nz = 1024; }

    const unsigned short* A    = z == 0 ? Aq  : (z == 1 ? Ak   : Av);
    const unsigned short* Bt   = z == 0 ? WqT : (z == 1 ? WlkT : WlvT);
    const float*          bias = z == 0 ? bq  : (z == 1 ? blk  : blv);
    unsigned short*       C    = z == 0 ? q_bf : (z == 1 ? lat_k : lat_v);

    const int tid = threadIdx.x;
    const int lane = tid & 63, wid = tid >> 6;
    const int lr = lane & 15, lg = lane >> 4;
    const int wm = wid >> 2, wn = wid & 3;

    // --- staging geometry: per k-half, thread covers lin {tid, 512+tid};
    // r = lin>>2, slot s = lin&3 holds source chunk s ^ ((r>>1)&3)
    const int lin0 = tid, lin1 = 512 + tid;
    const int rS0 = lin0 >> 2, rS1 = lin1 >> 2;
    const int cS0 = (lin0 & 3) ^ ((rS0 >> 1) & 3);
    const int cS1 = (lin1 & 3) ^ ((rS1 >> 1) & 3);
    const unsigned short* aS0 = A  + (size_t)(row0 + rS0) * KD + cS0 * 8;
    const unsigned short* aS1 = A  + (size_t)(row0 + rS1) * KD + cS1 * 8;
    const unsigned short* bS0 = Bt + (size_t)(col0 + rS0) * KD + cS0 * 8;
    const unsigned short* bS1 = Bt + (size_t)(col0 + rS1) * KD + cS1 * 8;
    const int d0 = lin0 * 8, d1 = lin1 * 8;

    // --- fragment LDS offsets (within one [256*32] half)
    int aoff[8], boff[4];
    #pragma unroll
    for (int m = 0; m < 8; ++m) {
        int row = wm * 128 + m * 16 + lr;
        aoff[m] = row * 32 + ((lg ^ ((row >> 1) & 3)) * 8);
    }
    #pragma unroll
    for (int n = 0; n < 4; ++n) {
        int row = wn * 64 + n * 16 + lr;
        boff[n] = row * 32 + ((lg ^ ((row >> 1) & 3)) * 8);
    }

    f32x4 acc[8][4];
    #pragma unroll
    for (int m = 0; m < 8; ++m)
        #pragma unroll
        for (int n = 0; n < 4; ++n) acc[m][n] = (f32x4){0.f, 0.f, 0.f, 0.f};

#define STAGE_A(buf, kh, kt) do { \
        gload16(aS0 + (size_t)(kt) * 64 + (kh) * 32, &Al[buf][kh][d0]); \
        gload16(aS1 + (size_t)(kt) * 64 + (kh) * 32, &Al[buf][kh][d1]); } while (0)
#define STAGE_B(buf, kh, kt) do { \
        gload16(bS0 + (size_t)(kt) * 64 + (kh) * 32, &Bl[buf][kh][d0]); \
        gload16(bS1 + (size_t)(kt) * 64 + (kh) * 32, &Bl[buf][kh][d1]); } while (0)

    // prologue: tile 0, per-wave issue order Ak0,Bk0,Ak1,Bk1 (8 loads)
    STAGE_A(0, 0, 0); STAGE_B(0, 0, 0); STAGE_A(0, 1, 0); STAGE_B(0, 1, 0);

    #pragma unroll 1
    for (int t = 0; t < NTK; ++t) {
        const int cur = t & 1, nxt = cur ^ 1;
        const bool more = (t + 1 < NTK);

        // ======== gate 1: Ak0/Bk0 of tile t landed ========
        asm volatile("s_waitcnt vmcnt(4)" ::: "memory");
        __builtin_amdgcn_s_barrier();
        asm volatile("" ::: "memory");

        bf16x8 af[8], bf0, bf1;
        // ---- P1: kh=0, n-frags {0,1} ----
        if (more) STAGE_A(nxt, 0, t + 1);
        #pragma unroll
        for (int m = 0; m < 8; ++m) af[m] = ds_read128(&Al[cur][0][aoff[m]]);
        bf0 = ds_read128(&Bl[cur][0][boff[0]]);
        bf1 = ds_read128(&Bl[cur][0][boff[1]]);
        asm volatile("s_waitcnt lgkmcnt(0)" ::: "memory");
        __builtin_amdgcn_sched_barrier(0);
        __builtin_amdgcn_s_setprio(1);
        #pragma unroll
        for (int m = 0; m < 8; ++m) {
            acc[m][0] = __builtin_amdgcn_mfma_f32_16x16x32_bf16(af[m], bf0, acc[m][0], 0, 0, 0);
            acc[m][1] = __builtin_amdgcn_mfma_f32_16x16x32_bf16(af[m], bf1, acc[m][1], 0, 0, 0);
        }
        __builtin_amdgcn_s_setprio(0);

        // ---- P2: kh=0, n-frags {2,3} ----
        if (more) STAGE_B(nxt, 0, t + 1);
        bf0 = ds_read128(&Bl[cur][0][boff[2]]);
        bf1 = ds_read128(&Bl[cur][0][boff[3]]);
        asm volatile("s_waitcnt lgkmcnt(0)" ::: "memory");
        __builtin_amdgcn_sched_barrier(0);
        __builtin_amdgcn_s_setprio(1);
        #pragma unroll
        for (int m = 0; m < 8; ++m) {
            acc[m][2] = __builtin_amdgcn_mfma_f32_16x16x32_bf16(af[m], bf0, acc[m][2], 0, 0, 0);
            acc[m][3] = __builtin_amdgcn_mfma_f32_16x16x32_bf16(af[m], bf1, acc[m][3], 0, 0, 0);
        }
        __builtin_amdgcn_s_setprio(0);

        // ======== gate 2: Ak1/Bk1 of tile t landed ========
        if (more) asm volatile("s_waitcnt vmcnt(4)" ::: "memory");
        else      asm volatile("s_waitcnt vmcnt(0)" ::: "memory");
        __builtin_amdgcn_s_barrier();
        asm volatile("" ::: "memory");

        // ---- P3: kh=1, n-frags {0,1} ----
        if (more) STAGE_A(nxt, 1, t + 1);
        #pragma unroll
        for (int m = 0; m < 8; ++m) af[m] = ds_read128(&Al[cur][1][aoff[m]]);
        bf0 = ds_read128(&Bl[cur][1][boff[0]]);
        bf1 = ds_read128(&Bl[cur][1][boff[1]]);
        asm volatile("s_waitcnt lgkmcnt(0)" ::: "memory");
        __builtin_amdgcn_sched_barrier(0);
        __builtin_amdgcn_s_setprio(1);
        #pragma unroll
        for (int m = 0; m < 8; ++m) {
            acc[m][0] = __builtin_amdgcn_mfma_f32_16x16x32_bf16(af[m], bf0, acc[m][0], 0, 0, 0);
            acc[m][1] = __builtin_amdgcn_mfma_f32_16x16x32_bf16(af[m], bf1, acc[m][1], 0, 0, 0);
        }
        __builtin_amdgcn_s_setprio(0);

        // ---- P4: kh=1, n-frags {2,3} ----
        if (more) STAGE_B(nxt, 1, t + 1);
        bf0 = ds_read128(&Bl[cur][1][boff[2]]);
        bf1 = ds_read128(&Bl[cur][1][boff[3]]);
        asm volatile("s_waitcnt lgkmcnt(0)" ::: "memory");
        __builtin_amdgcn_sched_barrier(0);
        __builtin_amdgcn_s_setprio(1);
        #pragma unroll
        for (int m = 0; m < 8; ++m) {
            acc[m][2] = __builtin_amdgcn_mfma_f32_16x16x32_bf16(af[m], bf0, acc[m][2], 0, 0, 0);
            acc[m][3] = __builtin_amdgcn_mfma_f32_16x16x32_bf16(af[m], bf1, acc[m][3], 0, 0, 0);
        }
        __builtin_amdgcn_s_setprio(0);
    }
#undef STAGE_A
#undef STAGE_B

    // ---- epilogue ----
    float bv[4];
    #pragma unroll
    for (int n = 0; n < 4; ++n) bv[n] = bias[col0 + wn * 64 + n * 16 + lr];
    const float omul = (z == 0) ? SCALE_Q : 1.0f;

    #pragma unroll
    for (int m = 0; m < 8; ++m) {
        #pragma unroll
        for (int n = 0; n < 4; ++n) {
            const int col = col0 + wn * 64 + n * 16 + lr;
            const int rowb = row0 + wm * 128 + m * 16 + lg * 4;
            #pragma unroll
            for (int j = 0; j < 4; ++j)
                C[(size_t)(rowb + j) * Nz + col] = f2bf((acc[m][n][j] + bv[n]) * omul);
        }
    }
}

// ---------------------------------------------------------------------------
// Stage-2 recon (unchanged from R8)
// ---------------------------------------------------------------------------
__global__ __launch_bounds__(256) void recon_kernel(
    const unsigned short* __restrict__ lat_k, const unsigned short* __restrict__ lat_v,
    const unsigned short* __restrict__ WkrT, const unsigned short* __restrict__ WvrT,
    const float* __restrict__ bkr, const float* __restrict__ bvr,
    unsigned short* __restrict__ k_bf, unsigned short* __restrict__ v_t)
{
    __shared__ unsigned short Alds[128 * 64];
    __shared__ unsigned short Blds[128 * 64];

    const int flat = blockIdx.x;
    const int swz = (flat & 7) * 128 + (flat >> 3);   // 1024 = 8*128
    const int z = swz >> 9;
    const int rem = swz & 511;
    const int h = rem >> 5;
    const int r0 = (rem & 31) * 128;

    const unsigned short* lat = z ? lat_v : lat_k;
    const unsigned short* WT  = z ? WvrT : WkrT;
    const float* bias = z ? bvr : bkr;

    const int tid = threadIdx.x;
    const int lane = tid & 63, wid = tid >> 6;
    const int lr = lane & 15, lg = lane >> 4;
    const int wm = wid >> 1, wn = wid & 1;

    #pragma unroll
    for (int c = 0; c < 4; ++c) {
        int e = c * 256 + tid;
        int row = e >> 3, pc = e & 7;
        gload16(lat + (size_t)(r0 + row) * 1024 + h * 64 + ((pc ^ (row & 7)) * 8),
                Alds + e * 8);
    }
    #pragma unroll
    for (int c = 0; c < 4; ++c) {
        int e = c * 256 + tid;
        int d = e >> 3, pc = e & 7;
        gload16(WT + (size_t)d * 64 + ((pc ^ (d & 7)) * 8), Blds + e * 8);
    }
    __syncthreads();

    f32x4 acc[4][4];
    #pragma unroll
    for (int m = 0; m < 4; ++m)
        #pragma unroll
        for (int n = 0; n < 4; ++n) acc[m][n] = (f32x4){0.f, 0.f, 0.f, 0.f};

    #pragma unroll
    for (int ks = 0; ks < 2; ++ks) {
        bf16x8 af[4], bfv[4];
        #pragma unroll
        for (int m = 0; m < 4; ++m) {
            int row = wm * 64 + m * 16 + lr;
            af[m] = *(const bf16x8*)&Alds[row * 64 + (((ks * 4 + lg) ^ (row & 7)) * 8)];
        }
        #pragma unroll
        for (int n = 0; n < 4; ++n) {
            int row = wn * 64 + n * 16 + lr;
            bfv[n] = *(const bf16x8*)&Blds[row * 64 + (((ks * 4 + lg) ^ (row & 7)) * 8)];
        }
        #pragma unroll
        for (int m = 0; m < 4; ++m)
            #pragma unroll
            for (int n = 0; n < 4; ++n)
                acc[m][n] = __builtin_amdgcn_mfma_f32_16x16x32_bf16(af[m], bfv[n], acc[m][n], 0, 0, 0);
    }

    const int b = r0 >> 11;
    float bv[4];
    #pragma unroll
    for (int n = 0; n < 4; ++n) bv[n] = bias[wn * 64 + n * 16 + lr];

    #pragma unroll
    for (int m = 0; m < 4; ++m) {
        #pragma unroll
        for (int n = 0; n < 4; ++n) {
            const int d = wn * 64 + n * 16 + lr;
            const int rowb = r0 + wm * 64 + m * 16 + lg * 4;
            if (z == 0) {
                #pragma unroll
                for (int j = 0; j < 4; ++j)
                    k_bf[(size_t)(rowb + j) * D_MODEL + h * D_HEAD + d] =
                        f2bf(acc[m][n][j] + bv[n]);
            } else {
                us4v o = { f2bf(acc[m][n][0] + bv[n]), f2bf(acc[m][n][1] + bv[n]),
                           f2bf(acc[m][n][2] + bv[n]), f2bf(acc[m][n][3] + bv[n]) };
                *(us4v*)&v_t[((size_t)(b * 16 + h) * 128 + d) * 2048 + (rowb & 2047)] = o;
            }
        }
    }
}

// ---------------------------------------------------------------------------
// Output GEMM (proven 128^2 2-barrier): out fp32 = ao @ WoT^T + bo. Grid 512.
// ---------------------------------------------------------------------------
__global__ __launch_bounds__(256) void out_gemm_kernel(
    const unsigned short* __restrict__ A,
    const unsigned short* __restrict__ Bt,
    const float* __restrict__ bias,
    float* __restrict__ C)
{
    __shared__ unsigned short Al[2][128 * 32];
    __shared__ unsigned short Bl[2][128 * 32];

    const int flat = blockIdx.x;
    const int swz = (flat & 7) * 64 + (flat >> 3);   // 512 = 8 * 64
    const int row0 = (swz >> 4) * 128, col0 = (swz & 15) * 128;

    const int tid = threadIdx.x;
    const int lane = tid & 63, wid = tid >> 6;
    const int lr = lane & 15, lg = lane >> 4;
    const int wr = wid >> 1, wc = wid & 1;

    const unsigned short* ag[2];
    const unsigned short* bg[2];
    unsigned short* alp[2][2];
    unsigned short* blp[2][2];
    #pragma unroll
    for (int c = 0; c < 2; ++c) {
        int idx = wid * 128 + c * 64 + lane;
        int row = idx >> 2, p = idx & 3;
        int sp = p ^ ((row >> 1) & 3);
        ag[c] = A  + (size_t)(row0 + row) * KD + sp * 8;
        bg[c] = Bt + (size_t)(col0 + row) * KD + sp * 8;
        alp[0][c] = Al[0] + idx * 8;  alp[1][c] = Al[1] + idx * 8;
        blp[0][c] = Bl[0] + idx * 8;  blp[1][c] = Bl[1] + idx * 8;
    }
    const int sx = (lr >> 1) & 3;
    const int abase = (wr * 64 + lr) * 32 + ((lg ^ sx) * 8);
    const int bbase = (wc * 64 + lr) * 32 + ((lg ^ sx) * 8);

    f32x4 acc[4][4];
    #pragma unroll
    for (int m = 0; m < 4; ++m)
        #pragma unroll
        for (int n = 0; n < 4; ++n) acc[m][n] = (f32x4){0.f, 0.f, 0.f, 0.f};

    #pragma unroll
    for (int c = 0; c < 2; ++c) { gload16(ag[c], alp[0][c]); gload16(bg[c], blp[0][c]); }
    __syncthreads();

    #pragma unroll 1
    for (int t = 0; t < NT; ++t) {
        const int cur = t & 1, nxt = cur ^ 1;
        if (t + 1 < NT) {
            #pragma unroll
            for (int c = 0; c < 2; ++c) {
                gload16(ag[c] + (size_t)(t + 1) * 32, alp[nxt][c]);
                gload16(bg[c] + (size_t)(t + 1) * 32, blp[nxt][c]);
            }
        }
        bf16x8 af[4], bfv[4];
        #pragma unroll
        for (int m = 0; m < 4; ++m) af[m]  = *(const bf16x8*)&Al[cur][abase + m * 512];
        #pragma unroll
        for (int n = 0; n < 4; ++n) bfv[n] = *(const bf16x8*)&Bl[cur][bbase + n * 512];
        __builtin_amdgcn_s_setprio(1);
        #pragma unroll
        for (int m = 0; m < 4; ++m)
            #pragma unroll
            for (int n = 0; n < 4; ++n)
                acc[m][n] = __builtin_amdgcn_mfma_f32_16x16x32_bf16(af[m], bfv[n], acc[m][n], 0, 0, 0);
        __builtin_amdgcn_s_setprio(0);
        __syncthreads();
    }

    float bv[4];
    #pragma unroll
    for (int n = 0; n < 4; ++n) bv[n] = bias[col0 + wc * 64 + n * 16 + lr];
    #pragma unroll
    for (int m = 0; m < 4; ++m)
        #pragma unroll
        for (int n = 0; n < 4; ++n) {
            const int col = col0 + wc * 64 + n * 16 + lr;
            const int rowb = row0 + wr * 64 + m * 16 + lg * 4;
            #pragma unroll
            for (int j = 0; j < 4; ++j)
                C[(size_t)(rowb + j) * D_MODEL + col] = acc[m][n][j] + bv[n];
        }
}

// ---------------------------------------------------------------------------
// Causal flash attention (unchanged from R8)
// ---------------------------------------------------------------------------
static __device__ __forceinline__ void flash_stage(
    const unsigned short* __restrict__ kgh,
    const unsigned short* __restrict__ vtb,
    unsigned short* Kl, unsigned short* Vl, int kv0, int tid)
{
    #pragma unroll
    for (int c = 0; c < 4; ++c) {
        int idx = c * 256 + tid;
        int r = idx >> 4, ch = idx & 15;
        gload16(kgh + (size_t)(kv0 + r) * D_MODEL + ((ch ^ (r & 7)) * 8), Kl + idx * 8);
    }
    #pragma unroll
    for (int c = 0; c < 4; ++c) {
        int idx = c * 256 + tid;
        int d = idx >> 3, ch = idx & 7;
        gload16(vtb + (size_t)d * S_LEN + kv0 + ((ch ^ (d & 7)) * 8), Vl + idx * 8);
    }
}

__global__ __launch_bounds__(256, 2) void flash_kernel(
    const unsigned short* __restrict__ Q,
    const unsigned short* __restrict__ Kg,
    const unsigned short* __restrict__ Vt,
    unsigned short* __restrict__ Og)
{
    __shared__ unsigned short Klds[2][64 * 128];
    __shared__ unsigned short Vlds[2][128 * 64];

    const int tid = threadIdx.x;
    const int lane = tid & 63, wid = tid >> 6;
    const int lc = lane & 31, hi = lane >> 5;

    const int blk = blockIdx.x;
    const int jj = blk >> 5;
    const int qt = (jj < 8) ? (15 - jj) : (jj - 8);   // heavy first
    const int bh = blk & 31;
    const int b = bh >> 4, h = bh & 15;
    const size_t base = (size_t)b * S_LEN * D_MODEL;
    const unsigned short* kgh = Kg + base + h * D_HEAD;
    const unsigned short* vtb = Vt + (size_t)bh * D_HEAD * S_LEN;

    const int q0w = qt * 128 + wid * 32;
    const int qcol = q0w + lc;

    bf16x8 qf[8];
    #pragma unroll
    for (int dc = 0; dc < 8; ++dc)
        qf[dc] = *(const bf16x8*)&Q[base + (size_t)qcol * D_MODEL + h * D_HEAD + dc * 16 + hi * 8];

    f32x16 o_acc[4];
    #pragma unroll
    for (int dt = 0; dt < 4; ++dt)
        #pragma unroll
        for (int r = 0; r < 16; ++r) o_acc[dt][r] = 0.f;
    float m_r = -3e38f, l_r = 0.f;

    const int kxor = lc & 7;
    const int nt = 2 * qt + 2;

    flash_stage(kgh, vtb, Klds[0], Vlds[0], 0, tid);

    #pragma unroll 1
    for (int t = 0; t < nt; ++t) {
        const int bb = t & 1;
        const int kv0 = t * 64;
        __syncthreads();
        if (t + 1 < nt)
            flash_stage(kgh, vtb, Klds[bb ^ 1], Vlds[bb ^ 1], (t + 1) * 64, tid);

        f32x16 s0a, s0b, s1a, s1b;
        #pragma unroll
        for (int r = 0; r < 16; ++r) { s0a[r] = 0.f; s0b[r] = 0.f; s1a[r] = 0.f; s1b[r] = 0.f; }
        __builtin_amdgcn_s_setprio(1);
        #pragma unroll
        for (int dc = 0; dc < 4; ++dc) {
            bf16x8 kf0 = *(const bf16x8*)&Klds[bb][lc * 128 + (((dc * 2 + hi) ^ kxor) * 8)];
            bf16x8 kf1 = *(const bf16x8*)&Klds[bb][(32 + lc) * 128 + (((dc * 2 + hi) ^ kxor) * 8)];
            s0a = __builtin_amdgcn_mfma_f32_32x32x16_bf16(kf0, qf[dc], s0a, 0, 0, 0);
            s1a = __builtin_amdgcn_mfma_f32_32x32x16_bf16(kf1, qf[dc], s1a, 0, 0, 0);
        }
        #pragma unroll
        for (int dc = 4; dc < 8; ++dc) {
            bf16x8 kf0 = *(const bf16x8*)&Klds[bb][lc * 128 + (((dc * 2 + hi) ^ kxor) * 8)];
            bf16x8 kf1 = *(const bf16x8*)&Klds[bb][(32 + lc) * 128 + (((dc * 2 + hi) ^ kxor) * 8)];
            s0b = __builtin_amdgcn_mfma_f32_32x32x16_bf16(kf0, qf[dc], s0b, 0, 0, 0);
            s1b = __builtin_amdgcn_mfma_f32_32x32x16_bf16(kf1, qf[dc], s1b, 0, 0, 0);
        }
        __builtin_amdgcn_s_setprio(0);
        f32x16 s0 = s0a + s0b;
        f32x16 s1 = s1a + s1b;

        if (t >= nt - 2) {
            #pragma unroll
            for (int r = 0; r < 16; ++r) {
                int krow = (r & 3) + 8 * (r >> 2) + 4 * hi;
                if (kv0 + krow > qcol)      s0[r] = -3e38f;
                if (kv0 + 32 + krow > qcol) s1[r] = -3e38f;
            }
        }

        float mt[8];
        #pragma unroll
        for (int i = 0; i < 8; ++i)
            mt[i] = fmaxf(fmaxf(s0[2 * i], s0[2 * i + 1]), fmaxf(s1[2 * i], s1[2 * i + 1]));
        float mA = fmaxf(fmaxf(mt[0], mt[1]), fmaxf(mt[2], mt[3]));
        float mB = fmaxf(fmaxf(mt[4], mt[5]), fmaxf(mt[6], mt[7]));
        float sm = fmaxf(mA, mB);
        sm = fmaxf(sm, __shfl_xor(sm, 32));

        if (__any(sm > m_r + 11.5f)) {
            float mnew = fmaxf(m_r, sm);
            float alpha = exp2_hw(m_r - mnew);
            l_r *= alpha;
            m_r = mnew;
            #pragma unroll
            for (int r = 0; r < 16; ++r) {
                float av = __shfl(alpha, (r & 3) + 8 * (r >> 2) + 4 * hi);
                #pragma unroll
                for (int dt = 0; dt < 4; ++dt) o_acc[dt][r] *= av;
            }
        }

        #pragma unroll
        for (int r = 0; r < 16; ++r) {
            s0[r] = exp2_hw(s0[r] - m_r);
            s1[r] = exp2_hw(s1[r] - m_r);
        }
        float st[8];
        #pragma unroll
        for (int i = 0; i < 8; ++i)
            st[i] = (s0[2 * i] + s0[2 * i + 1]) + (s1[2 * i] + s1[2 * i + 1]);
        l_r += ((st[0] + st[1]) + (st[2] + st[3])) + ((st[4] + st[5]) + (st[6] + st[7]));

        #pragma unroll
        for (int t32 = 0; t32 < 2; ++t32) {
            const f32x16& s = t32 ? s1 : s0;
            unsigned int c0[4], c1[4];
            #pragma unroll
            for (int g = 0; g < 4; ++g) {
                c0[g] = cvtpk_bf16(s[4 * g],     s[4 * g + 1]);
                c1[g] = cvtpk_bf16(s[4 * g + 2], s[4 * g + 3]);
            }
            #pragma unroll
            for (int kt = 0; kt < 2; ++kt) {
                unsigned int sel0 = hi ? c0[2 * kt] : c0[2 * kt + 1];
                unsigned int sel1 = hi ? c1[2 * kt] : c1[2 * kt + 1];
                unsigned int o0 = (unsigned int)__shfl_xor((int)sel0, 32);
                unsigned int o1 = (unsigned int)__shfl_xor((int)sel1, 32);
                u32x4 uu;
                uu.x = hi ? o0 : c0[2 * kt];
                uu.y = hi ? o1 : c1[2 * kt];
                uu.z = hi ? c0[2 * kt + 1] : o0;
                uu.w = hi ? c1[2 * kt + 1] : o1;
                bf16x8 pf = __builtin_bit_cast(bf16x8, uu);
                __builtin_amdgcn_s_setprio(1);
                #pragma unroll
                for (int dt = 0; dt < 4; ++dt) {
                    bf16x8 vf = *(const bf16x8*)
                        &Vlds[bb][(dt * 32 + lc) * 64 + (((t32 * 4 + kt * 2 + hi) ^ kxor) * 8)];
                    o_acc[dt] = __builtin_amdgcn_mfma_f32_32x32x16_bf16(pf, vf, o_acc[dt], 0, 0, 0);
                }
                __builtin_amdgcn_s_setprio(0);
            }
        }
    }

    float lt = l_r + __shfl_xor(l_r, 32);
    float inv = 1.0f / lt;
    #pragma unroll
    for (int r = 0; r < 16; ++r) {
        int qrow = (r & 3) + 8 * (r >> 2) + 4 * hi;
        float iv = __shfl(inv, qrow);
        #pragma unroll
        for (int dt = 0; dt < 4; ++dt)
            Og[base + (size_t)(q0w + qrow) * D_MODEL + h * D_HEAD + dt * 32 + lc] =
                f2bf(o_acc[dt][r] * iv);
    }
}

// ---------------------------------------------------------------------------
extern "C" void kernel_launch(void* const* d_in, const int* in_sizes, int n_in,
                              void* d_out, int out_size, void* d_ws, size_t ws_size,
                              hipStream_t stream)
{
    const float* queries = (const float*)d_in[0];
    const float* keys    = (const float*)d_in[1];
    const float* values  = (const float*)d_in[2];
    const float* Wq  = (const float*)d_in[3];
    const float* bq  = (const float*)d_in[4];
    const float* Wlk = (const float*)d_in[5];
    const float* blk = (const float*)d_in[6];
    const float* Wlv = (const float*)d_in[7];
    const float* blv = (const float*)d_in[8];
    const float* Wkr = (const float*)d_in[9];
    const float* bkr = (const float*)d_in[10];
    const float* Wvr = (const float*)d_in[11];
    const float* bvr = (const float*)d_in[12];
    const float* Wo  = (const float*)d_in[13];
    const float* bo  = (const float*)d_in[14];
    float* out = (float*)d_out;

    char* ws = (char*)d_ws;
    const size_t MB = 1024 * 1024;
    unsigned short* abf_q = (unsigned short*)(ws);            // 16MB; ao aliases
    unsigned short* abf_k = (unsigned short*)(ws + 16 * MB);  // 16MB
    unsigned short* abf_v = (unsigned short*)(ws + 32 * MB);
    unsigned short* q_bf  = (unsigned short*)(ws + 48 * MB);
    unsigned short* k_bf  = (unsigned short*)(ws + 64 * MB);
    unsigned short* v_t   = (unsigned short*)(ws + 80 * MB);
    unsigned short* lat_k = (unsigned short*)(ws + 96 * MB);   // 8MB
    unsigned short* lat_v = (unsigned short*)(ws + 104 * MB);  // 8MB
    unsigned short* WqT   = (unsigned short*)(ws + 112 * MB);  // 8MB
    unsigned short* WlkT  = (unsigned short*)(ws + 120 * MB);  // 4MB
    unsigned short* WlvT  = (unsigned short*)(ws + 124 * MB);  // 4MB
    unsigned short* WkrT  = (unsigned short*)(ws + 128 * MB);  // 16KB
    unsigned short* WvrT  = WkrT + 128 * 64;
    unsigned short* WoT   = (unsigned short*)(ws + 129 * MB);  // 8MB
    unsigned short* ao    = abf_q;   // dead after stage1

    prep_kernel<<<16385, 256, 0, stream>>>(
        queries, keys, values, Wq, Wlk, Wlv, Wo, Wkr, Wvr,
        abf_q, abf_k, abf_v, WqT, WlkT, WlvT, WoT, WkrT, WvrT);

    stage1_8p_kernel<<<256, 512, 0, stream>>>(
        abf_q, abf_k, abf_v, WqT, WlkT, WlvT, bq, blk, blv,
        q_bf, lat_k, lat_v);

    recon_kernel<<<1024, 256, 0, stream>>>(
        lat_k, lat_v, WkrT, WvrT, bkr, bvr, k_bf, v_t);

    flash_kernel<<<512, 256, 0, stream>>>(q_bf, k_bf, v_t, ao);

    out_gemm_kernel<<<512, 256, 0, stream>>>(ao, WoT, bo, out);
}

// Round 10
// 233.991 us; speedup vs baseline: 1.5617x; 1.0352x over previous
//
#include <hip/hip_runtime.h>
#include <hip/hip_bf16.h>

#define B_SZ    2
#define S_LEN   2048
#define D_MODEL 2048
#define N_HEADS 16
#define D_HEAD  128
#define L_RANK  64
#define M_ROWS  (B_SZ * S_LEN)   // 4096
#define KD      2048             // GEMM K
#define NT      (KD / 32)        // 64 K-steps (128^2 kernels)
#define NTK     (KD / 64)        // 32 K-tiles (8-phase kernels)

typedef short          bf16x8 __attribute__((ext_vector_type(8)));
typedef float          f32x4  __attribute__((ext_vector_type(4)));
typedef float          f32x16 __attribute__((ext_vector_type(16)));
typedef unsigned short us4v   __attribute__((ext_vector_type(4)));
typedef unsigned short us8v   __attribute__((ext_vector_type(8)));
typedef unsigned int   u32x4  __attribute__((ext_vector_type(4)));

// log2(e) / sqrt(128), folded into the Q projection epilogue
#define SCALE_Q 0.127517432f

static __device__ __forceinline__ unsigned short f2bf(float f) {
    unsigned int u = __float_as_uint(f);
    u += 0x7FFFu + ((u >> 16) & 1u);      // RNE; inputs finite
    return (unsigned short)(u >> 16);
}

static __device__ __forceinline__ void gload16(const void* g, void* l) {
    __builtin_amdgcn_global_load_lds(
        (const __attribute__((address_space(1))) unsigned int*)g,
        (__attribute__((address_space(3))) unsigned int*)l, 16, 0, 0);
}

// compiler-invisible LDS read (defeats alias-driven auto vmcnt waits);
// MUST be followed by explicit lgkmcnt(0) + sched_barrier(0) before use.
static __device__ __forceinline__ bf16x8 ds_read128(const unsigned short* p) {
    bf16x8 r;
    unsigned int a = (unsigned int)(size_t)
        (const __attribute__((address_space(3))) unsigned short*)p;
    asm volatile("ds_read_b128 %0, %1" : "=&v"(r) : "v"(a));
    return r;
}

static __device__ __forceinline__ float exp2_hw(float x) {
    float r; asm("v_exp_f32 %0, %1" : "=v"(r) : "v"(x)); return r;
}
static __device__ __forceinline__ unsigned int cvtpk_bf16(float a, float b) {
    unsigned int r; asm("v_cvt_pk_bf16_f32 %0, %1, %2" : "=v"(r) : "v"(a), "v"(b)); return r;
}

// ---------------------------------------------------------------------------
// Fused prep (unchanged)
// ---------------------------------------------------------------------------
__global__ __launch_bounds__(256) void prep_kernel(
    const float* __restrict__ q_in, const float* __restrict__ k_in,
    const float* __restrict__ v_in,
    const float* __restrict__ Wq, const float* __restrict__ Wlk,
    const float* __restrict__ Wlv, const float* __restrict__ Wo,
    const float* __restrict__ Wkr, const float* __restrict__ Wvr,
    unsigned short* __restrict__ q_o, unsigned short* __restrict__ k_o,
    unsigned short* __restrict__ v_o,
    unsigned short* __restrict__ WqT, unsigned short* __restrict__ WlkT,
    unsigned short* __restrict__ WlvT, unsigned short* __restrict__ WoT,
    unsigned short* __restrict__ WkrT, unsigned short* __restrict__ WvrT)
{
    __shared__ float tl[64][69];
    const int bid = blockIdx.x, tid = threadIdx.x;

    if (bid < 12288) {
        const int z = bid >> 12;
        const float* in = z == 0 ? q_in : (z == 1 ? k_in : v_in);
        unsigned short* out = z == 0 ? q_o : (z == 1 ? k_o : v_o);
        size_t i = ((size_t)(bid & 4095) * 256 + tid) * 8;
        float4 a = *(const float4*)&in[i];
        float4 b = *(const float4*)&in[i + 4];
        us8v o = { f2bf(a.x), f2bf(a.y), f2bf(a.z), f2bf(a.w),
                   f2bf(b.x), f2bf(b.y), f2bf(b.z), f2bf(b.w) };
        *(us8v*)&out[i] = o;
    } else if (bid < 16384) {
        const int t = bid - 12288;
        const int z = t >> 10;               // 0:Wq 1:Wlk 2:Wlv 3:Wo
        const int y = (t & 1023) >> 5, x = t & 31;
        const int Nz = (z == 1 || z == 2) ? 1024 : 2048;
        if (x * 64 >= Nz) return;
        const float* W = z == 0 ? Wq : (z == 1 ? Wlk : (z == 2 ? Wlv : Wo));
        unsigned short* WT = z == 0 ? WqT : (z == 1 ? WlkT : (z == 2 ? WlvT : WoT));
        const int k0 = y * 64, n0 = x * 64;
        #pragma unroll
        for (int c = 0; c < 4; ++c) {
            int idx = c * 256 + tid;
            int r = idx >> 4, c4 = (idx & 15) * 4;
            float4 v = *(const float4*)&W[(size_t)(k0 + r) * Nz + n0 + c4];
            tl[r][c4] = v.x; tl[r][c4 + 1] = v.y; tl[r][c4 + 2] = v.z; tl[r][c4 + 3] = v.w;
        }
        __syncthreads();
        #pragma unroll
        for (int c = 0; c < 2; ++c) {
            int idx = c * 256 + tid;
            int nr = idx >> 3, s = idx & 7;
            us8v o;
            #pragma unroll
            for (int j = 0; j < 8; ++j) o[j] = f2bf(tl[s * 8 + j][nr]);
            *(us8v*)&WT[(size_t)(n0 + nr) * KD + k0 + s * 8] = o;
        }
    } else {
        #pragma unroll 1
        for (int t2 = 0; t2 < 2; ++t2) {
            const float* W = t2 ? Wvr : Wkr;
            unsigned short* WT = t2 ? WvrT : WkrT;
            for (int i = 0; i < 32; ++i) {
                int e = i * 256 + tid;
                int d = e >> 6, l = e & 63;
                WT[d * 64 + l] = f2bf(W[l * 128 + d]);
            }
        }
    }
}

// ---------------------------------------------------------------------------
// Stage-1 batched GEMM, 256x256, 8-phase gated (unchanged from R9 — proven).
// ---------------------------------------------------------------------------
__global__ __launch_bounds__(512) void stage1_8p_kernel(
    const unsigned short* __restrict__ Aq, const unsigned short* __restrict__ Ak,
    const unsigned short* __restrict__ Av,
    const unsigned short* __restrict__ WqT, const unsigned short* __restrict__ WlkT,
    const unsigned short* __restrict__ WlvT,
    const float* __restrict__ bq, const float* __restrict__ blk,
    const float* __restrict__ blv,
    unsigned short* __restrict__ q_bf, unsigned short* __restrict__ lat_k,
    unsigned short* __restrict__ lat_v)
{
    __shared__ unsigned short Al[2][2][256 * 32];
    __shared__ unsigned short Bl[2][2][256 * 32];

    const int bid = blockIdx.x;
    const int swz = (bid & 7) * 32 + (bid >> 3);   // 256 blocks, bijective
    int z, rem, row0, col0, Nz;
    if (swz < 128)      { z = 0; rem = swz;       row0 = (rem >> 3) * 256; col0 = (rem & 7) * 256; Nz = 2048; }
    else if (swz < 192) { z = 1; rem = swz - 128; row0 = (rem >> 2) * 256; col0 = (rem & 3) * 256; Nz = 1024; }
    else                { z = 2; rem = swz - 192; row0 = (rem >> 2) * 256; col0 = (rem & 3) * 256; Nz = 1024; }

    const unsigned short* A    = z == 0 ? Aq  : (z == 1 ? Ak   : Av);
    const unsigned short* Bt   = z == 0 ? WqT : (z == 1 ? WlkT : WlvT);
    const float*          bias = z == 0 ? bq  : (z == 1 ? blk  : blv);
    unsigned short*       C    = z == 0 ? q_bf : (z == 1 ? lat_k : lat_v);

    const int tid = threadIdx.x;
    const int lane = tid & 63, wid = tid >> 6;
    const int lr = lane & 15, lg = lane >> 4;
    const int wm = wid >> 2, wn = wid & 3;

    const int lin0 = tid, lin1 = 512 + tid;
    const int rS0 = lin0 >> 2, rS1 = lin1 >> 2;
    const int cS0 = (lin0 & 3) ^ ((rS0 >> 1) & 3);
    const int cS1 = (lin1 & 3) ^ ((rS1 >> 1) & 3);
    const unsigned short* aS0 = A  + (size_t)(row0 + rS0) * KD + cS0 * 8;
    const unsigned short* aS1 = A  + (size_t)(row0 + rS1) * KD + cS1 * 8;
    const unsigned short* bS0 = Bt + (size_t)(col0 + rS0) * KD + cS0 * 8;
    const unsigned short* bS1 = Bt + (size_t)(col0 + rS1) * KD + cS1 * 8;
    const int d0 = lin0 * 8, d1 = lin1 * 8;

    int aoff[8], boff[4];
    #pragma unroll
    for (int m = 0; m < 8; ++m) {
        int row = wm * 128 + m * 16 + lr;
        aoff[m] = row * 32 + ((lg ^ ((row >> 1) & 3)) * 8);
    }
    #pragma unroll
    for (int n = 0; n < 4; ++n) {
        int row = wn * 64 + n * 16 + lr;
        boff[n] = row * 32 + ((lg ^ ((row >> 1) & 3)) * 8);
    }

    f32x4 acc[8][4];
    #pragma unroll
    for (int m = 0; m < 8; ++m)
        #pragma unroll
        for (int n = 0; n < 4; ++n) acc[m][n] = (f32x4){0.f, 0.f, 0.f, 0.f};

#define STAGE_A(buf, kh, kt) do { \
        gload16(aS0 + (size_t)(kt) * 64 + (kh) * 32, &Al[buf][kh][d0]); \
        gload16(aS1 + (size_t)(kt) * 64 + (kh) * 32, &Al[buf][kh][d1]); } while (0)
#define STAGE_B(buf, kh, kt) do { \
        gload16(bS0 + (size_t)(kt) * 64 + (kh) * 32, &Bl[buf][kh][d0]); \
        gload16(bS1 + (size_t)(kt) * 64 + (kh) * 32, &Bl[buf][kh][d1]); } while (0)

    STAGE_A(0, 0, 0); STAGE_B(0, 0, 0); STAGE_A(0, 1, 0); STAGE_B(0, 1, 0);

    #pragma unroll 1
    for (int t = 0; t < NTK; ++t) {
        const int cur = t & 1, nxt = cur ^ 1;
        const bool more = (t + 1 < NTK);

        asm volatile("s_waitcnt vmcnt(4)" ::: "memory");
        __builtin_amdgcn_s_barrier();
        asm volatile("" ::: "memory");

        bf16x8 af[8], bf0, bf1;
        if (more) STAGE_A(nxt, 0, t + 1);
        #pragma unroll
        for (int m = 0; m < 8; ++m) af[m] = ds_read128(&Al[cur][0][aoff[m]]);
        bf0 = ds_read128(&Bl[cur][0][boff[0]]);
        bf1 = ds_read128(&Bl[cur][0][boff[1]]);
        asm volatile("s_waitcnt lgkmcnt(0)" ::: "memory");
        __builtin_amdgcn_sched_barrier(0);
        __builtin_amdgcn_s_setprio(1);
        #pragma unroll
        for (int m = 0; m < 8; ++m) {
            acc[m][0] = __builtin_amdgcn_mfma_f32_16x16x32_bf16(af[m], bf0, acc[m][0], 0, 0, 0);
            acc[m][1] = __builtin_amdgcn_mfma_f32_16x16x32_bf16(af[m], bf1, acc[m][1], 0, 0, 0);
        }
        __builtin_amdgcn_s_setprio(0);

        if (more) STAGE_B(nxt, 0, t + 1);
        bf0 = ds_read128(&Bl[cur][0][boff[2]]);
        bf1 = ds_read128(&Bl[cur][0][boff[3]]);
        asm volatile("s_waitcnt lgkmcnt(0)" ::: "memory");
        __builtin_amdgcn_sched_barrier(0);
        __builtin_amdgcn_s_setprio(1);
        #pragma unroll
        for (int m = 0; m < 8; ++m) {
            acc[m][2] = __builtin_amdgcn_mfma_f32_16x16x32_bf16(af[m], bf0, acc[m][2], 0, 0, 0);
            acc[m][3] = __builtin_amdgcn_mfma_f32_16x16x32_bf16(af[m], bf1, acc[m][3], 0, 0, 0);
        }
        __builtin_amdgcn_s_setprio(0);

        if (more) asm volatile("s_waitcnt vmcnt(4)" ::: "memory");
        else      asm volatile("s_waitcnt vmcnt(0)" ::: "memory");
        __builtin_amdgcn_s_barrier();
        asm volatile("" ::: "memory");

        if (more) STAGE_A(nxt, 1, t + 1);
        #pragma unroll
        for (int m = 0; m < 8; ++m) af[m] = ds_read128(&Al[cur][1][aoff[m]]);
        bf0 = ds_read128(&Bl[cur][1][boff[0]]);
        bf1 = ds_read128(&Bl[cur][1][boff[1]]);
        asm volatile("s_waitcnt lgkmcnt(0)" ::: "memory");
        __builtin_amdgcn_sched_barrier(0);
        __builtin_amdgcn_s_setprio(1);
        #pragma unroll
        for (int m = 0; m < 8; ++m) {
            acc[m][0] = __builtin_amdgcn_mfma_f32_16x16x32_bf16(af[m], bf0, acc[m][0], 0, 0, 0);
            acc[m][1] = __builtin_amdgcn_mfma_f32_16x16x32_bf16(af[m], bf1, acc[m][1], 0, 0, 0);
        }
        __builtin_amdgcn_s_setprio(0);

        if (more) STAGE_B(nxt, 1, t + 1);
        bf0 = ds_read128(&Bl[cur][1][boff[2]]);
        bf1 = ds_read128(&Bl[cur][1][boff[3]]);
        asm volatile("s_waitcnt lgkmcnt(0)" ::: "memory");
        __builtin_amdgcn_sched_barrier(0);
        __builtin_amdgcn_s_setprio(1);
        #pragma unroll
        for (int m = 0; m < 8; ++m) {
            acc[m][2] = __builtin_amdgcn_mfma_f32_16x16x32_bf16(af[m], bf0, acc[m][2], 0, 0, 0);
            acc[m][3] = __builtin_amdgcn_mfma_f32_16x16x32_bf16(af[m], bf1, acc[m][3], 0, 0, 0);
        }
        __builtin_amdgcn_s_setprio(0);
    }
#undef STAGE_A
#undef STAGE_B

    float bv[4];
    #pragma unroll
    for (int n = 0; n < 4; ++n) bv[n] = bias[col0 + wn * 64 + n * 16 + lr];
    const float omul = (z == 0) ? SCALE_Q : 1.0f;

    #pragma unroll
    for (int m = 0; m < 8; ++m) {
        #pragma unroll
        for (int n = 0; n < 4; ++n) {
            const int col = col0 + wn * 64 + n * 16 + lr;
            const int rowb = row0 + wm * 128 + m * 16 + lg * 4;
            #pragma unroll
            for (int j = 0; j < 4; ++j)
                C[(size_t)(rowb + j) * Nz + col] = f2bf((acc[m][n][j] + bv[n]) * omul);
        }
    }
}

// ---------------------------------------------------------------------------
// Output GEMM, 8-phase gated port: BM=128, BN=256, BK=64, 8 waves (2Mx4N),
// grid 256 = one perfect round. Per-thread per-tile loads {Ak0:1,Bk0:2,
// Ak1:1,Bk1:2} = 6; both gates s_waitcnt vmcnt(3); never a mid-loop drain.
// ---------------------------------------------------------------------------
__global__ __launch_bounds__(512) void out_gemm8p_kernel(
    const unsigned short* __restrict__ A,
    const unsigned short* __restrict__ Bt,
    const float* __restrict__ bias,
    float* __restrict__ C)
{
    __shared__ unsigned short Al[2][2][128 * 32];   // 32 KB
    __shared__ unsigned short Bl[2][2][256 * 32];   // 64 KB

    const int bid = blockIdx.x;
    const int swz = (bid & 7) * 32 + (bid >> 3);    // 256 blocks, bijective
    const int row0 = (swz >> 3) * 128, col0 = (swz & 7) * 256;

    const int tid = threadIdx.x;
    const int lane = tid & 63, wid = tid >> 6;
    const int lr = lane & 15, lg = lane >> 4;
    const int wm = wid >> 2, wn = wid & 3;

    // A staging: one k-half = 128x32 -> 1 load/thread
    const int rA = tid >> 2;
    const int cA = (tid & 3) ^ ((rA >> 1) & 3);
    const unsigned short* aS = A + (size_t)(row0 + rA) * KD + cA * 8;
    const int dA = tid * 8;
    // B staging: one k-half = 256x32 -> 2 loads/thread
    const int lin0 = tid, lin1 = 512 + tid;
    const int rB0 = lin0 >> 2, rB1 = lin1 >> 2;
    const int cB0 = (lin0 & 3) ^ ((rB0 >> 1) & 3);
    const int cB1 = (lin1 & 3) ^ ((rB1 >> 1) & 3);
    const unsigned short* bS0 = Bt + (size_t)(col0 + rB0) * KD + cB0 * 8;
    const unsigned short* bS1 = Bt + (size_t)(col0 + rB1) * KD + cB1 * 8;
    const int dB0 = lin0 * 8, dB1 = lin1 * 8;

    int aoff[4], boff[4];
    #pragma unroll
    for (int m = 0; m < 4; ++m) {
        int row = wm * 64 + m * 16 + lr;
        aoff[m] = row * 32 + ((lg ^ ((row >> 1) & 3)) * 8);
    }
    #pragma unroll
    for (int n = 0; n < 4; ++n) {
        int row = wn * 64 + n * 16 + lr;
        boff[n] = row * 32 + ((lg ^ ((row >> 1) & 3)) * 8);
    }

    f32x4 acc[4][4];
    #pragma unroll
    for (int m = 0; m < 4; ++m)
        #pragma unroll
        for (int n = 0; n < 4; ++n) acc[m][n] = (f32x4){0.f, 0.f, 0.f, 0.f};

#define STAGE_A(buf, kh, kt) \
        gload16(aS + (size_t)(kt) * 64 + (kh) * 32, &Al[buf][kh][dA])
#define STAGE_B(buf, kh, kt) do { \
        gload16(bS0 + (size_t)(kt) * 64 + (kh) * 32, &Bl[buf][kh][dB0]); \
        gload16(bS1 + (size_t)(kt) * 64 + (kh) * 32, &Bl[buf][kh][dB1]); } while (0)

    // prologue: tile 0, issue order Ak0, Bk0, Ak1, Bk1 (6 loads/thread)
    STAGE_A(0, 0, 0); STAGE_B(0, 0, 0); STAGE_A(0, 1, 0); STAGE_B(0, 1, 0);

    #pragma unroll 1
    for (int t = 0; t < NTK; ++t) {
        const int cur = t & 1, nxt = cur ^ 1;
        const bool more = (t + 1 < NTK);

        // gate 1: Ak0+Bk0 of tile t landed (leave t's Ak1,Bk1 = 3 in flight)
        asm volatile("s_waitcnt vmcnt(3)" ::: "memory");
        __builtin_amdgcn_s_barrier();
        asm volatile("" ::: "memory");

        bf16x8 af[4], bf0, bf1;
        // P1
        if (more) STAGE_A(nxt, 0, t + 1);
        #pragma unroll
        for (int m = 0; m < 4; ++m) af[m] = ds_read128(&Al[cur][0][aoff[m]]);
        bf0 = ds_read128(&Bl[cur][0][boff[0]]);
        bf1 = ds_read128(&Bl[cur][0][boff[1]]);
        asm volatile("s_waitcnt lgkmcnt(0)" ::: "memory");
        __builtin_amdgcn_sched_barrier(0);
        __builtin_amdgcn_s_setprio(1);
        #pragma unroll
        for (int m = 0; m < 4; ++m) {
            acc[m][0] = __builtin_amdgcn_mfma_f32_16x16x32_bf16(af[m], bf0, acc[m][0], 0, 0, 0);
            acc[m][1] = __builtin_amdgcn_mfma_f32_16x16x32_bf16(af[m], bf1, acc[m][1], 0, 0, 0);
        }
        __builtin_amdgcn_s_setprio(0);

        // P2
        if (more) STAGE_B(nxt, 0, t + 1);
        bf0 = ds_read128(&Bl[cur][0][boff[2]]);
        bf1 = ds_read128(&Bl[cur][0][boff[3]]);
        asm volatile("s_waitcnt lgkmcnt(0)" ::: "memory");
        __builtin_amdgcn_sched_barrier(0);
        __builtin_amdgcn_s_setprio(1);
        #pragma unroll
        for (int m = 0; m < 4; ++m) {
            acc[m][2] = __builtin_amdgcn_mfma_f32_16x16x32_bf16(af[m], bf0, acc[m][2], 0, 0, 0);
            acc[m][3] = __builtin_amdgcn_mfma_f32_16x16x32_bf16(af[m], bf1, acc[m][3], 0, 0, 0);
        }
        __builtin_amdgcn_s_setprio(0);

        // gate 2: Ak1+Bk1 of tile t landed (leave t+1's Ak0,Bk0 = 3 in flight)
        if (more) asm volatile("s_waitcnt vmcnt(3)" ::: "memory");
        else      asm volatile("s_waitcnt vmcnt(0)" ::: "memory");
        __builtin_amdgcn_s_barrier();
        asm volatile("" ::: "memory");

        // P3
        if (more) STAGE_A(nxt, 1, t + 1);
        #pragma unroll
        for (int m = 0; m < 4; ++m) af[m] = ds_read128(&Al[cur][1][aoff[m]]);
        bf0 = ds_read128(&Bl[cur][1][boff[0]]);
        bf1 = ds_read128(&Bl[cur][1][boff[1]]);
        asm volatile("s_waitcnt lgkmcnt(0)" ::: "memory");
        __builtin_amdgcn_sched_barrier(0);
        __builtin_amdgcn_s_setprio(1);
        #pragma unroll
        for (int m = 0; m < 4; ++m) {
            acc[m][0] = __builtin_amdgcn_mfma_f32_16x16x32_bf16(af[m], bf0, acc[m][0], 0, 0, 0);
            acc[m][1] = __builtin_amdgcn_mfma_f32_16x16x32_bf16(af[m], bf1, acc[m][1], 0, 0, 0);
        }
        __builtin_amdgcn_s_setprio(0);

        // P4
        if (more) STAGE_B(nxt, 1, t + 1);
        bf0 = ds_read128(&Bl[cur][1][boff[2]]);
        bf1 = ds_read128(&Bl[cur][1][boff[3]]);
        asm volatile("s_waitcnt lgkmcnt(0)" ::: "memory");
        __builtin_amdgcn_sched_barrier(0);
        __builtin_amdgcn_s_setprio(1);
        #pragma unroll
        for (int m = 0; m < 4; ++m) {
            acc[m][2] = __builtin_amdgcn_mfma_f32_16x16x32_bf16(af[m], bf0, acc[m][2], 0, 0, 0);
            acc[m][3] = __builtin_amdgcn_mfma_f32_16x16x32_bf16(af[m], bf1, acc[m][3], 0, 0, 0);
        }
        __builtin_amdgcn_s_setprio(0);
    }
#undef STAGE_A
#undef STAGE_B

    float bv[4];
    #pragma unroll
    for (int n = 0; n < 4; ++n) bv[n] = bias[col0 + wn * 64 + n * 16 + lr];
    #pragma unroll
    for (int m = 0; m < 4; ++m)
        #pragma unroll
        for (int n = 0; n < 4; ++n) {
            const int col = col0 + wn * 64 + n * 16 + lr;
            const int rowb = row0 + wm * 64 + m * 16 + lg * 4;
            #pragma unroll
            for (int j = 0; j < 4; ++j)
                C[(size_t)(rowb + j) * D_MODEL + col] = acc[m][n][j] + bv[n];
        }
}

// ---------------------------------------------------------------------------
// Stage-2 recon (unchanged)
// ---------------------------------------------------------------------------
__global__ __launch_bounds__(256) void recon_kernel(
    const unsigned short* __restrict__ lat_k, const unsigned short* __restrict__ lat_v,
    const unsigned short* __restrict__ WkrT, const unsigned short* __restrict__ WvrT,
    const float* __restrict__ bkr, const float* __restrict__ bvr,
    unsigned short* __restrict__ k_bf, unsigned short* __restrict__ v_t)
{
    __shared__ unsigned short Alds[128 * 64];
    __shared__ unsigned short Blds[128 * 64];

    const int flat = blockIdx.x;
    const int swz = (flat & 7) * 128 + (flat >> 3);   // 1024 = 8*128
    const int z = swz >> 9;
    const int rem = swz & 511;
    const int h = rem >> 5;
    const int r0 = (rem & 31) * 128;

    const unsigned short* lat = z ? lat_v : lat_k;
    const unsigned short* WT  = z ? WvrT : WkrT;
    const float* bias = z ? bvr : bkr;

    const int tid = threadIdx.x;
    const int lane = tid & 63, wid = tid >> 6;
    const int lr = lane & 15, lg = lane >> 4;
    const int wm = wid >> 1, wn = wid & 1;

    #pragma unroll
    for (int c = 0; c < 4; ++c) {
        int e = c * 256 + tid;
        int row = e >> 3, pc = e & 7;
        gload16(lat + (size_t)(r0 + row) * 1024 + h * 64 + ((pc ^ (row & 7)) * 8),
                Alds + e * 8);
    }
    #pragma unroll
    for (int c = 0; c < 4; ++c) {
        int e = c * 256 + tid;
        int d = e >> 3, pc = e & 7;
        gload16(WT + (size_t)d * 64 + ((pc ^ (d & 7)) * 8), Blds + e * 8);
    }
    __syncthreads();

    f32x4 acc[4][4];
    #pragma unroll
    for (int m = 0; m < 4; ++m)
        #pragma unroll
        for (int n = 0; n < 4; ++n) acc[m][n] = (f32x4){0.f, 0.f, 0.f, 0.f};

    #pragma unroll
    for (int ks = 0; ks < 2; ++ks) {
        bf16x8 af[4], bfv[4];
        #pragma unroll
        for (int m = 0; m < 4; ++m) {
            int row = wm * 64 + m * 16 + lr;
            af[m] = *(const bf16x8*)&Alds[row * 64 + (((ks * 4 + lg) ^ (row & 7)) * 8)];
        }
        #pragma unroll
        for (int n = 0; n < 4; ++n) {
            int row = wn * 64 + n * 16 + lr;
            bfv[n] = *(const bf16x8*)&Blds[row * 64 + (((ks * 4 + lg) ^ (row & 7)) * 8)];
        }
        #pragma unroll
        for (int m = 0; m < 4; ++m)
            #pragma unroll
            for (int n = 0; n < 4; ++n)
                acc[m][n] = __builtin_amdgcn_mfma_f32_16x16x32_bf16(af[m], bfv[n], acc[m][n], 0, 0, 0);
    }

    const int b = r0 >> 11;
    float bv[4];
    #pragma unroll
    for (int n = 0; n < 4; ++n) bv[n] = bias[wn * 64 + n * 16 + lr];

    #pragma unroll
    for (int m = 0; m < 4; ++m) {
        #pragma unroll
        for (int n = 0; n < 4; ++n) {
            const int d = wn * 64 + n * 16 + lr;
            const int rowb = r0 + wm * 64 + m * 16 + lg * 4;
            if (z == 0) {
                #pragma unroll
                for (int j = 0; j < 4; ++j)
                    k_bf[(size_t)(rowb + j) * D_MODEL + h * D_HEAD + d] =
                        f2bf(acc[m][n][j] + bv[n]);
            } else {
                us4v o = { f2bf(acc[m][n][0] + bv[n]), f2bf(acc[m][n][1] + bv[n]),
                           f2bf(acc[m][n][2] + bv[n]), f2bf(acc[m][n][3] + bv[n]) };
                *(us4v*)&v_t[((size_t)(b * 16 + h) * 128 + d) * 2048 + (rowb & 2047)] = o;
            }
        }
    }
}

// ---------------------------------------------------------------------------
// Causal flash attention (unchanged)
// ---------------------------------------------------------------------------
static __device__ __forceinline__ void flash_stage(
    const unsigned short* __restrict__ kgh,
    const unsigned short* __restrict__ vtb,
    unsigned short* Kl, unsigned short* Vl, int kv0, int tid)
{
    #pragma unroll
    for (int c = 0; c < 4; ++c) {
        int idx = c * 256 + tid;
        int r = idx >> 4, ch = idx & 15;
        gload16(kgh + (size_t)(kv0 + r) * D_MODEL + ((ch ^ (r & 7)) * 8), Kl + idx * 8);
    }
    #pragma unroll
    for (int c = 0; c < 4; ++c) {
        int idx = c * 256 + tid;
        int d = idx >> 3, ch = idx & 7;
        gload16(vtb + (size_t)d * S_LEN + kv0 + ((ch ^ (d & 7)) * 8), Vl + idx * 8);
    }
}

__global__ __launch_bounds__(256, 2) void flash_kernel(
    const unsigned short* __restrict__ Q,
    const unsigned short* __restrict__ Kg,
    const unsigned short* __restrict__ Vt,
    unsigned short* __restrict__ Og)
{
    __shared__ unsigned short Klds[2][64 * 128];
    __shared__ unsigned short Vlds[2][128 * 64];

    const int tid = threadIdx.x;
    const int lane = tid & 63, wid = tid >> 6;
    const int lc = lane & 31, hi = lane >> 5;

    const int blk = blockIdx.x;
    const int jj = blk >> 5;
    const int qt = (jj < 8) ? (15 - jj) : (jj - 8);   // heavy first
    const int bh = blk & 31;
    const int b = bh >> 4, h = bh & 15;
    const size_t base = (size_t)b * S_LEN * D_MODEL;
    const unsigned short* kgh = Kg + base + h * D_HEAD;
    const unsigned short* vtb = Vt + (size_t)bh * D_HEAD * S_LEN;

    const int q0w = qt * 128 + wid * 32;
    const int qcol = q0w + lc;

    bf16x8 qf[8];
    #pragma unroll
    for (int dc = 0; dc < 8; ++dc)
        qf[dc] = *(const bf16x8*)&Q[base + (size_t)qcol * D_MODEL + h * D_HEAD + dc * 16 + hi * 8];

    f32x16 o_acc[4];
    #pragma unroll
    for (int dt = 0; dt < 4; ++dt)
        #pragma unroll
        for (int r = 0; r < 16; ++r) o_acc[dt][r] = 0.f;
    float m_r = -3e38f, l_r = 0.f;

    const int kxor = lc & 7;
    const int nt = 2 * qt + 2;

    flash_stage(kgh, vtb, Klds[0], Vlds[0], 0, tid);

    #pragma unroll 1
    for (int t = 0; t < nt; ++t) {
        const int bb = t & 1;
        const int kv0 = t * 64;
        __syncthreads();
        if (t + 1 < nt)
            flash_stage(kgh, vtb, Klds[bb ^ 1], Vlds[bb ^ 1], (t + 1) * 64, tid);

        f32x16 s0a, s0b, s1a, s1b;
        #pragma unroll
        for (int r = 0; r < 16; ++r) { s0a[r] = 0.f; s0b[r] = 0.f; s1a[r] = 0.f; s1b[r] = 0.f; }
        __builtin_amdgcn_s_setprio(1);
        #pragma unroll
        for (int dc = 0; dc < 4; ++dc) {
            bf16x8 kf0 = *(const bf16x8*)&Klds[bb][lc * 128 + (((dc * 2 + hi) ^ kxor) * 8)];
            bf16x8 kf1 = *(const bf16x8*)&Klds[bb][(32 + lc) * 128 + (((dc * 2 + hi) ^ kxor) * 8)];
            s0a = __builtin_amdgcn_mfma_f32_32x32x16_bf16(kf0, qf[dc], s0a, 0, 0, 0);
            s1a = __builtin_amdgcn_mfma_f32_32x32x16_bf16(kf1, qf[dc], s1a, 0, 0, 0);
        }
        #pragma unroll
        for (int dc = 4; dc < 8; ++dc) {
            bf16x8 kf0 = *(const bf16x8*)&Klds[bb][lc * 128 + (((dc * 2 + hi) ^ kxor) * 8)];
            bf16x8 kf1 = *(const bf16x8*)&Klds[bb][(32 + lc) * 128 + (((dc * 2 + hi) ^ kxor) * 8)];
            s0b = __builtin_amdgcn_mfma_f32_32x32x16_bf16(kf0, qf[dc], s0b, 0, 0, 0);
            s1b = __builtin_amdgcn_mfma_f32_32x32x16_bf16(kf1, qf[dc], s1b, 0, 0, 0);
        }
        __builtin_amdgcn_s_setprio(0);
        f32x16 s0 = s0a + s0b;
        f32x16 s1 = s1a + s1b;

        if (t >= nt - 2) {
            #pragma unroll
            for (int r = 0; r < 16; ++r) {
                int krow = (r & 3) + 8 * (r >> 2) + 4 * hi;
                if (kv0 + krow > qcol)      s0[r] = -3e38f;
                if (kv0 + 32 + krow > qcol) s1[r] = -3e38f;
            }
        }

        float mt[8];
        #pragma unroll
        for (int i = 0; i < 8; ++i)
            mt[i] = fmaxf(fmaxf(s0[2 * i], s0[2 * i + 1]), fmaxf(s1[2 * i], s1[2 * i + 1]));
        float mA = fmaxf(fmaxf(mt[0], mt[1]), fmaxf(mt[2], mt[3]));
        float mB = fmaxf(fmaxf(mt[4], mt[5]), fmaxf(mt[6], mt[7]));
        float sm = fmaxf(mA, mB);
        sm = fmaxf(sm, __shfl_xor(sm, 32));

        if (__any(sm > m_r + 11.5f)) {
            float mnew = fmaxf(m_r, sm);
            float alpha = exp2_hw(m_r - mnew);
            l_r *= alpha;
            m_r = mnew;
            #pragma unroll
            for (int r = 0; r < 16; ++r) {
                float av = __shfl(alpha, (r & 3) + 8 * (r >> 2) + 4 * hi);
                #pragma unroll
                for (int dt = 0; dt < 4; ++dt) o_acc[dt][r] *= av;
            }
        }

        #pragma unroll
        for (int r = 0; r < 16; ++r) {
            s0[r] = exp2_hw(s0[r] - m_r);
            s1[r] = exp2_hw(s1[r] - m_r);
        }
        float st[8];
        #pragma unroll
        for (int i = 0; i < 8; ++i)
            st[i] = (s0[2 * i] + s0[2 * i + 1]) + (s1[2 * i] + s1[2 * i + 1]);
        l_r += ((st[0] + st[1]) + (st[2] + st[3])) + ((st[4] + st[5]) + (st[6] + st[7]));

        #pragma unroll
        for (int t32 = 0; t32 < 2; ++t32) {
            const f32x16& s = t32 ? s1 : s0;
            unsigned int c0[4], c1[4];
            #pragma unroll
            for (int g = 0; g < 4; ++g) {
                c0[g] = cvtpk_bf16(s[4 * g],     s[4 * g + 1]);
                c1[g] = cvtpk_bf16(s[4 * g + 2], s[4 * g + 3]);
            }
            #pragma unroll
            for (int kt = 0; kt < 2; ++kt) {
                unsigned int sel0 = hi ? c0[2 * kt] : c0[2 * kt + 1];
                unsigned int sel1 = hi ? c1[2 * kt] : c1[2 * kt + 1];
                unsigned int o0 = (unsigned int)__shfl_xor((int)sel0, 32);
                unsigned int o1 = (unsigned int)__shfl_xor((int)sel1, 32);
                u32x4 uu;
                uu.x = hi ? o0 : c0[2 * kt];
                uu.y = hi ? o1 : c1[2 * kt];
                uu.z = hi ? c0[2 * kt + 1] : o0;
                uu.w = hi ? c1[2 * kt + 1] : o1;
                bf16x8 pf = __builtin_bit_cast(bf16x8, uu);
                __builtin_amdgcn_s_setprio(1);
                #pragma unroll
                for (int dt = 0; dt < 4; ++dt) {
                    bf16x8 vf = *(const bf16x8*)
                        &Vlds[bb][(dt * 32 + lc) * 64 + (((t32 * 4 + kt * 2 + hi) ^ kxor) * 8)];
                    o_acc[dt] = __builtin_amdgcn_mfma_f32_32x32x16_bf16(pf, vf, o_acc[dt], 0, 0, 0);
                }
                __builtin_amdgcn_s_setprio(0);
            }
        }
    }

    float lt = l_r + __shfl_xor(l_r, 32);
    float inv = 1.0f / lt;
    #pragma unroll
    for (int r = 0; r < 16; ++r) {
        int qrow = (r & 3) + 8 * (r >> 2) + 4 * hi;
        float iv = __shfl(inv, qrow);
        #pragma unroll
        for (int dt = 0; dt < 4; ++dt)
            Og[base + (size_t)(q0w + qrow) * D_MODEL + h * D_HEAD + dt * 32 + lc] =
                f2bf(o_acc[dt][r] * iv);
    }
}

// ---------------------------------------------------------------------------
extern "C" void kernel_launch(void* const* d_in, const int* in_sizes, int n_in,
                              void* d_out, int out_size, void* d_ws, size_t ws_size,
                              hipStream_t stream)
{
    const float* queries = (const float*)d_in[0];
    const float* keys    = (const float*)d_in[1];
    const float* values  = (const float*)d_in[2];
    const float* Wq  = (const float*)d_in[3];
    const float* bq  = (const float*)d_in[4];
    const float* Wlk = (const float*)d_in[5];
    const float* blk = (const float*)d_in[6];
    const float* Wlv = (const float*)d_in[7];
    const float* blv = (const float*)d_in[8];
    const float* Wkr = (const float*)d_in[9];
    const float* bkr = (const float*)d_in[10];
    const float* Wvr = (const float*)d_in[11];
    const float* bvr = (const float*)d_in[12];
    const float* Wo  = (const float*)d_in[13];
    const float* bo  = (const float*)d_in[14];
    float* out = (float*)d_out;

    char* ws = (char*)d_ws;
    const size_t MB = 1024 * 1024;
    unsigned short* abf_q = (unsigned short*)(ws);            // 16MB; ao aliases
    unsigned short* abf_k = (unsigned short*)(ws + 16 * MB);  // 16MB
    unsigned short* abf_v = (unsigned short*)(ws + 32 * MB);
    unsigned short* q_bf  = (unsigned short*)(ws + 48 * MB);
    unsigned short* k_bf  = (unsigned short*)(ws + 64 * MB);
    unsigned short* v_t   = (unsigned short*)(ws + 80 * MB);
    unsigned short* lat_k = (unsigned short*)(ws + 96 * MB);   // 8MB
    unsigned short* lat_v = (unsigned short*)(ws + 104 * MB);  // 8MB
    unsigned short* WqT   = (unsigned short*)(ws + 112 * MB);  // 8MB
    unsigned short* WlkT  = (unsigned short*)(ws + 120 * MB);  // 4MB
    unsigned short* WlvT  = (unsigned short*)(ws + 124 * MB);  // 4MB
    unsigned short* WkrT  = (unsigned short*)(ws + 128 * MB);  // 16KB
    unsigned short* WvrT  = WkrT + 128 * 64;
    unsigned short* WoT   = (unsigned short*)(ws + 129 * MB);  // 8MB
    unsigned short* ao    = abf_q;   // dead after stage1

    prep_kernel<<<16385, 256, 0, stream>>>(
        queries, keys, values, Wq, Wlk, Wlv, Wo, Wkr, Wvr,
        abf_q, abf_k, abf_v, WqT, WlkT, WlvT, WoT, WkrT, WvrT);

    stage1_8p_kernel<<<256, 512, 0, stream>>>(
        abf_q, abf_k, abf_v, WqT, WlkT, WlvT, bq, blk, blv,
        q_bf, lat_k, lat_v);

    recon_kernel<<<1024, 256, 0, stream>>>(
        lat_k, lat_v, WkrT, WvrT, bkr, bvr, k_bf, v_t);

    flash_kernel<<<512, 256, 0, stream>>>(q_bf, k_bf, v_t, ao);

    out_gemm8p_kernel<<<256, 512, 0, stream>>>(ao, WoT, bo, out);
}

// Round 11
// 231.334 us; speedup vs baseline: 1.5796x; 1.0115x over previous
//
#include <hip/hip_runtime.h>
#include <hip/hip_bf16.h>

#define B_SZ    2
#define S_LEN   2048
#define D_MODEL 2048
#define N_HEADS 16
#define D_HEAD  128
#define L_RANK  64
#define M_ROWS  (B_SZ * S_LEN)   // 4096
#define KD      2048             // GEMM K
#define NT      (KD / 32)        // 64 K-steps (128^2 kernels)
#define NTK     (KD / 64)        // 32 K-tiles (8-phase kernels)

typedef short          bf16x8 __attribute__((ext_vector_type(8)));
typedef float          f32x4  __attribute__((ext_vector_type(4)));
typedef float          f32x16 __attribute__((ext_vector_type(16)));
typedef unsigned short us4v   __attribute__((ext_vector_type(4)));
typedef unsigned short us8v   __attribute__((ext_vector_type(8)));
typedef unsigned int   u32x4  __attribute__((ext_vector_type(4)));

// log2(e) / sqrt(128), folded into the Q projection epilogue
#define SCALE_Q 0.127517432f

static __device__ __forceinline__ unsigned short f2bf(float f) {
    unsigned int u = __float_as_uint(f);
    u += 0x7FFFu + ((u >> 16) & 1u);      // RNE; inputs finite
    return (unsigned short)(u >> 16);
}

static __device__ __forceinline__ void gload16(const void* g, void* l) {
    __builtin_amdgcn_global_load_lds(
        (const __attribute__((address_space(1))) unsigned int*)g,
        (__attribute__((address_space(3))) unsigned int*)l, 16, 0, 0);
}

// compiler-invisible LDS read (defeats alias-driven auto vmcnt waits);
// MUST be followed by explicit lgkmcnt(0) + sched_barrier(0) before use.
static __device__ __forceinline__ bf16x8 ds_read128(const unsigned short* p) {
    bf16x8 r;
    unsigned int a = (unsigned int)(size_t)
        (const __attribute__((address_space(3))) unsigned short*)p;
    asm volatile("ds_read_b128 %0, %1" : "=&v"(r) : "v"(a));
    return r;
}

static __device__ __forceinline__ float exp2_hw(float x) {
    float r; asm("v_exp_f32 %0, %1" : "=v"(r) : "v"(x)); return r;
}
static __device__ __forceinline__ unsigned int cvtpk_bf16(float a, float b) {
    unsigned int r; asm("v_cvt_pk_bf16_f32 %0, %1, %2" : "=v"(r) : "v"(a), "v"(b)); return r;
}

// ---------------------------------------------------------------------------
// Fused prep (unchanged)
// ---------------------------------------------------------------------------
__global__ __launch_bounds__(256) void prep_kernel(
    const float* __restrict__ q_in, const float* __restrict__ k_in,
    const float* __restrict__ v_in,
    const float* __restrict__ Wq, const float* __restrict__ Wlk,
    const float* __restrict__ Wlv, const float* __restrict__ Wo,
    const float* __restrict__ Wkr, const float* __restrict__ Wvr,
    unsigned short* __restrict__ q_o, unsigned short* __restrict__ k_o,
    unsigned short* __restrict__ v_o,
    unsigned short* __restrict__ WqT, unsigned short* __restrict__ WlkT,
    unsigned short* __restrict__ WlvT, unsigned short* __restrict__ WoT,
    unsigned short* __restrict__ WkrT, unsigned short* __restrict__ WvrT)
{
    __shared__ float tl[64][69];
    const int bid = blockIdx.x, tid = threadIdx.x;

    if (bid < 12288) {
        const int z = bid >> 12;
        const float* in = z == 0 ? q_in : (z == 1 ? k_in : v_in);
        unsigned short* out = z == 0 ? q_o : (z == 1 ? k_o : v_o);
        size_t i = ((size_t)(bid & 4095) * 256 + tid) * 8;
        float4 a = *(const float4*)&in[i];
        float4 b = *(const float4*)&in[i + 4];
        us8v o = { f2bf(a.x), f2bf(a.y), f2bf(a.z), f2bf(a.w),
                   f2bf(b.x), f2bf(b.y), f2bf(b.z), f2bf(b.w) };
        *(us8v*)&out[i] = o;
    } else if (bid < 16384) {
        const int t = bid - 12288;
        const int z = t >> 10;               // 0:Wq 1:Wlk 2:Wlv 3:Wo
        const int y = (t & 1023) >> 5, x = t & 31;
        const int Nz = (z == 1 || z == 2) ? 1024 : 2048;
        if (x * 64 >= Nz) return;
        const float* W = z == 0 ? Wq : (z == 1 ? Wlk : (z == 2 ? Wlv : Wo));
        unsigned short* WT = z == 0 ? WqT : (z == 1 ? WlkT : (z == 2 ? WlvT : WoT));
        const int k0 = y * 64, n0 = x * 64;
        #pragma unroll
        for (int c = 0; c < 4; ++c) {
            int idx = c * 256 + tid;
            int r = idx >> 4, c4 = (idx & 15) * 4;
            float4 v = *(const float4*)&W[(size_t)(k0 + r) * Nz + n0 + c4];
            tl[r][c4] = v.x; tl[r][c4 + 1] = v.y; tl[r][c4 + 2] = v.z; tl[r][c4 + 3] = v.w;
        }
        __syncthreads();
        #pragma unroll
        for (int c = 0; c < 2; ++c) {
            int idx = c * 256 + tid;
            int nr = idx >> 3, s = idx & 7;
            us8v o;
            #pragma unroll
            for (int j = 0; j < 8; ++j) o[j] = f2bf(tl[s * 8 + j][nr]);
            *(us8v*)&WT[(size_t)(n0 + nr) * KD + k0 + s * 8] = o;
        }
    } else {
        #pragma unroll 1
        for (int t2 = 0; t2 < 2; ++t2) {
            const float* W = t2 ? Wvr : Wkr;
            unsigned short* WT = t2 ? WvrT : WkrT;
            for (int i = 0; i < 32; ++i) {
                int e = i * 256 + tid;
                int d = e >> 6, l = e & 63;
                WT[d * 64 + l] = f2bf(W[l * 128 + d]);
            }
        }
    }
}

// ---------------------------------------------------------------------------
// Stage-1 batched GEMM, 256x256, 8-phase gated (unchanged — proven).
// ---------------------------------------------------------------------------
__global__ __launch_bounds__(512) void stage1_8p_kernel(
    const unsigned short* __restrict__ Aq, const unsigned short* __restrict__ Ak,
    const unsigned short* __restrict__ Av,
    const unsigned short* __restrict__ WqT, const unsigned short* __restrict__ WlkT,
    const unsigned short* __restrict__ WlvT,
    const float* __restrict__ bq, const float* __restrict__ blk,
    const float* __restrict__ blv,
    unsigned short* __restrict__ q_bf, unsigned short* __restrict__ lat_k,
    unsigned short* __restrict__ lat_v)
{
    __shared__ unsigned short Al[2][2][256 * 32];
    __shared__ unsigned short Bl[2][2][256 * 32];

    const int bid = blockIdx.x;
    const int swz = (bid & 7) * 32 + (bid >> 3);   // 256 blocks, bijective
    int z, rem, row0, col0, Nz;
    if (swz < 128)      { z = 0; rem = swz;       row0 = (rem >> 3) * 256; col0 = (rem & 7) * 256; Nz = 2048; }
    else if (swz < 192) { z = 1; rem = swz - 128; row0 = (rem >> 2) * 256; col0 = (rem & 3) * 256; Nz = 1024; }
    else                { z = 2; rem = swz - 192; row0 = (rem >> 2) * 256; col0 = (rem & 3) * 256; Nz = 1024; }

    const unsigned short* A    = z == 0 ? Aq  : (z == 1 ? Ak   : Av);
    const unsigned short* Bt   = z == 0 ? WqT : (z == 1 ? WlkT : WlvT);
    const float*          bias = z == 0 ? bq  : (z == 1 ? blk  : blv);
    unsigned short*       C    = z == 0 ? q_bf : (z == 1 ? lat_k : lat_v);

    const int tid = threadIdx.x;
    const int lane = tid & 63, wid = tid >> 6;
    const int lr = lane & 15, lg = lane >> 4;
    const int wm = wid >> 2, wn = wid & 3;

    const int lin0 = tid, lin1 = 512 + tid;
    const int rS0 = lin0 >> 2, rS1 = lin1 >> 2;
    const int cS0 = (lin0 & 3) ^ ((rS0 >> 1) & 3);
    const int cS1 = (lin1 & 3) ^ ((rS1 >> 1) & 3);
    const unsigned short* aS0 = A  + (size_t)(row0 + rS0) * KD + cS0 * 8;
    const unsigned short* aS1 = A  + (size_t)(row0 + rS1) * KD + cS1 * 8;
    const unsigned short* bS0 = Bt + (size_t)(col0 + rS0) * KD + cS0 * 8;
    const unsigned short* bS1 = Bt + (size_t)(col0 + rS1) * KD + cS1 * 8;
    const int d0 = lin0 * 8, d1 = lin1 * 8;

    int aoff[8], boff[4];
    #pragma unroll
    for (int m = 0; m < 8; ++m) {
        int row = wm * 128 + m * 16 + lr;
        aoff[m] = row * 32 + ((lg ^ ((row >> 1) & 3)) * 8);
    }
    #pragma unroll
    for (int n = 0; n < 4; ++n) {
        int row = wn * 64 + n * 16 + lr;
        boff[n] = row * 32 + ((lg ^ ((row >> 1) & 3)) * 8);
    }

    f32x4 acc[8][4];
    #pragma unroll
    for (int m = 0; m < 8; ++m)
        #pragma unroll
        for (int n = 0; n < 4; ++n) acc[m][n] = (f32x4){0.f, 0.f, 0.f, 0.f};

#define STAGE_A(buf, kh, kt) do { \
        gload16(aS0 + (size_t)(kt) * 64 + (kh) * 32, &Al[buf][kh][d0]); \
        gload16(aS1 + (size_t)(kt) * 64 + (kh) * 32, &Al[buf][kh][d1]); } while (0)
#define STAGE_B(buf, kh, kt) do { \
        gload16(bS0 + (size_t)(kt) * 64 + (kh) * 32, &Bl[buf][kh][d0]); \
        gload16(bS1 + (size_t)(kt) * 64 + (kh) * 32, &Bl[buf][kh][d1]); } while (0)

    STAGE_A(0, 0, 0); STAGE_B(0, 0, 0); STAGE_A(0, 1, 0); STAGE_B(0, 1, 0);

    #pragma unroll 1
    for (int t = 0; t < NTK; ++t) {
        const int cur = t & 1, nxt = cur ^ 1;
        const bool more = (t + 1 < NTK);

        asm volatile("s_waitcnt vmcnt(4)" ::: "memory");
        __builtin_amdgcn_s_barrier();
        asm volatile("" ::: "memory");

        bf16x8 af[8], bf0, bf1;
        if (more) STAGE_A(nxt, 0, t + 1);
        #pragma unroll
        for (int m = 0; m < 8; ++m) af[m] = ds_read128(&Al[cur][0][aoff[m]]);
        bf0 = ds_read128(&Bl[cur][0][boff[0]]);
        bf1 = ds_read128(&Bl[cur][0][boff[1]]);
        asm volatile("s_waitcnt lgkmcnt(0)" ::: "memory");
        __builtin_amdgcn_sched_barrier(0);
        __builtin_amdgcn_s_setprio(1);
        #pragma unroll
        for (int m = 0; m < 8; ++m) {
            acc[m][0] = __builtin_amdgcn_mfma_f32_16x16x32_bf16(af[m], bf0, acc[m][0], 0, 0, 0);
            acc[m][1] = __builtin_amdgcn_mfma_f32_16x16x32_bf16(af[m], bf1, acc[m][1], 0, 0, 0);
        }
        __builtin_amdgcn_s_setprio(0);

        if (more) STAGE_B(nxt, 0, t + 1);
        bf0 = ds_read128(&Bl[cur][0][boff[2]]);
        bf1 = ds_read128(&Bl[cur][0][boff[3]]);
        asm volatile("s_waitcnt lgkmcnt(0)" ::: "memory");
        __builtin_amdgcn_sched_barrier(0);
        __builtin_amdgcn_s_setprio(1);
        #pragma unroll
        for (int m = 0; m < 8; ++m) {
            acc[m][2] = __builtin_amdgcn_mfma_f32_16x16x32_bf16(af[m], bf0, acc[m][2], 0, 0, 0);
            acc[m][3] = __builtin_amdgcn_mfma_f32_16x16x32_bf16(af[m], bf1, acc[m][3], 0, 0, 0);
        }
        __builtin_amdgcn_s_setprio(0);

        if (more) asm volatile("s_waitcnt vmcnt(4)" ::: "memory");
        else      asm volatile("s_waitcnt vmcnt(0)" ::: "memory");
        __builtin_amdgcn_s_barrier();
        asm volatile("" ::: "memory");

        if (more) STAGE_A(nxt, 1, t + 1);
        #pragma unroll
        for (int m = 0; m < 8; ++m) af[m] = ds_read128(&Al[cur][1][aoff[m]]);
        bf0 = ds_read128(&Bl[cur][1][boff[0]]);
        bf1 = ds_read128(&Bl[cur][1][boff[1]]);
        asm volatile("s_waitcnt lgkmcnt(0)" ::: "memory");
        __builtin_amdgcn_sched_barrier(0);
        __builtin_amdgcn_s_setprio(1);
        #pragma unroll
        for (int m = 0; m < 8; ++m) {
            acc[m][0] = __builtin_amdgcn_mfma_f32_16x16x32_bf16(af[m], bf0, acc[m][0], 0, 0, 0);
            acc[m][1] = __builtin_amdgcn_mfma_f32_16x16x32_bf16(af[m], bf1, acc[m][1], 0, 0, 0);
        }
        __builtin_amdgcn_s_setprio(0);

        if (more) STAGE_B(nxt, 1, t + 1);
        bf0 = ds_read128(&Bl[cur][1][boff[2]]);
        bf1 = ds_read128(&Bl[cur][1][boff[3]]);
        asm volatile("s_waitcnt lgkmcnt(0)" ::: "memory");
        __builtin_amdgcn_sched_barrier(0);
        __builtin_amdgcn_s_setprio(1);
        #pragma unroll
        for (int m = 0; m < 8; ++m) {
            acc[m][2] = __builtin_amdgcn_mfma_f32_16x16x32_bf16(af[m], bf0, acc[m][2], 0, 0, 0);
            acc[m][3] = __builtin_amdgcn_mfma_f32_16x16x32_bf16(af[m], bf1, acc[m][3], 0, 0, 0);
        }
        __builtin_amdgcn_s_setprio(0);
    }
#undef STAGE_A
#undef STAGE_B

    float bv[4];
    #pragma unroll
    for (int n = 0; n < 4; ++n) bv[n] = bias[col0 + wn * 64 + n * 16 + lr];
    const float omul = (z == 0) ? SCALE_Q : 1.0f;

    #pragma unroll
    for (int m = 0; m < 8; ++m) {
        #pragma unroll
        for (int n = 0; n < 4; ++n) {
            const int col = col0 + wn * 64 + n * 16 + lr;
            const int rowb = row0 + wm * 128 + m * 16 + lg * 4;
            #pragma unroll
            for (int j = 0; j < 4; ++j)
                C[(size_t)(rowb + j) * Nz + col] = f2bf((acc[m][n][j] + bv[n]) * omul);
        }
    }
}

// ---------------------------------------------------------------------------
// Output GEMM, 8-phase gated (unchanged — proven).
// ---------------------------------------------------------------------------
__global__ __launch_bounds__(512) void out_gemm8p_kernel(
    const unsigned short* __restrict__ A,
    const unsigned short* __restrict__ Bt,
    const float* __restrict__ bias,
    float* __restrict__ C)
{
    __shared__ unsigned short Al[2][2][128 * 32];   // 32 KB
    __shared__ unsigned short Bl[2][2][256 * 32];   // 64 KB

    const int bid = blockIdx.x;
    const int swz = (bid & 7) * 32 + (bid >> 3);    // 256 blocks, bijective
    const int row0 = (swz >> 3) * 128, col0 = (swz & 7) * 256;

    const int tid = threadIdx.x;
    const int lane = tid & 63, wid = tid >> 6;
    const int lr = lane & 15, lg = lane >> 4;
    const int wm = wid >> 2, wn = wid & 3;

    const int rA = tid >> 2;
    const int cA = (tid & 3) ^ ((rA >> 1) & 3);
    const unsigned short* aS = A + (size_t)(row0 + rA) * KD + cA * 8;
    const int dA = tid * 8;
    const int lin0 = tid, lin1 = 512 + tid;
    const int rB0 = lin0 >> 2, rB1 = lin1 >> 2;
    const int cB0 = (lin0 & 3) ^ ((rB0 >> 1) & 3);
    const int cB1 = (lin1 & 3) ^ ((rB1 >> 1) & 3);
    const unsigned short* bS0 = Bt + (size_t)(col0 + rB0) * KD + cB0 * 8;
    const unsigned short* bS1 = Bt + (size_t)(col0 + rB1) * KD + cB1 * 8;
    const int dB0 = lin0 * 8, dB1 = lin1 * 8;

    int aoff[4], boff[4];
    #pragma unroll
    for (int m = 0; m < 4; ++m) {
        int row = wm * 64 + m * 16 + lr;
        aoff[m] = row * 32 + ((lg ^ ((row >> 1) & 3)) * 8);
    }
    #pragma unroll
    for (int n = 0; n < 4; ++n) {
        int row = wn * 64 + n * 16 + lr;
        boff[n] = row * 32 + ((lg ^ ((row >> 1) & 3)) * 8);
    }

    f32x4 acc[4][4];
    #pragma unroll
    for (int m = 0; m < 4; ++m)
        #pragma unroll
        for (int n = 0; n < 4; ++n) acc[m][n] = (f32x4){0.f, 0.f, 0.f, 0.f};

#define STAGE_A(buf, kh, kt) \
        gload16(aS + (size_t)(kt) * 64 + (kh) * 32, &Al[buf][kh][dA])
#define STAGE_B(buf, kh, kt) do { \
        gload16(bS0 + (size_t)(kt) * 64 + (kh) * 32, &Bl[buf][kh][dB0]); \
        gload16(bS1 + (size_t)(kt) * 64 + (kh) * 32, &Bl[buf][kh][dB1]); } while (0)

    STAGE_A(0, 0, 0); STAGE_B(0, 0, 0); STAGE_A(0, 1, 0); STAGE_B(0, 1, 0);

    #pragma unroll 1
    for (int t = 0; t < NTK; ++t) {
        const int cur = t & 1, nxt = cur ^ 1;
        const bool more = (t + 1 < NTK);

        asm volatile("s_waitcnt vmcnt(3)" ::: "memory");
        __builtin_amdgcn_s_barrier();
        asm volatile("" ::: "memory");

        bf16x8 af[4], bf0, bf1;
        if (more) STAGE_A(nxt, 0, t + 1);
        #pragma unroll
        for (int m = 0; m < 4; ++m) af[m] = ds_read128(&Al[cur][0][aoff[m]]);
        bf0 = ds_read128(&Bl[cur][0][boff[0]]);
        bf1 = ds_read128(&Bl[cur][0][boff[1]]);
        asm volatile("s_waitcnt lgkmcnt(0)" ::: "memory");
        __builtin_amdgcn_sched_barrier(0);
        __builtin_amdgcn_s_setprio(1);
        #pragma unroll
        for (int m = 0; m < 4; ++m) {
            acc[m][0] = __builtin_amdgcn_mfma_f32_16x16x32_bf16(af[m], bf0, acc[m][0], 0, 0, 0);
            acc[m][1] = __builtin_amdgcn_mfma_f32_16x16x32_bf16(af[m], bf1, acc[m][1], 0, 0, 0);
        }
        __builtin_amdgcn_s_setprio(0);

        if (more) STAGE_B(nxt, 0, t + 1);
        bf0 = ds_read128(&Bl[cur][0][boff[2]]);
        bf1 = ds_read128(&Bl[cur][0][boff[3]]);
        asm volatile("s_waitcnt lgkmcnt(0)" ::: "memory");
        __builtin_amdgcn_sched_barrier(0);
        __builtin_amdgcn_s_setprio(1);
        #pragma unroll
        for (int m = 0; m < 4; ++m) {
            acc[m][2] = __builtin_amdgcn_mfma_f32_16x16x32_bf16(af[m], bf0, acc[m][2], 0, 0, 0);
            acc[m][3] = __builtin_amdgcn_mfma_f32_16x16x32_bf16(af[m], bf1, acc[m][3], 0, 0, 0);
        }
        __builtin_amdgcn_s_setprio(0);

        if (more) asm volatile("s_waitcnt vmcnt(3)" ::: "memory");
        else      asm volatile("s_waitcnt vmcnt(0)" ::: "memory");
        __builtin_amdgcn_s_barrier();
        asm volatile("" ::: "memory");

        if (more) STAGE_A(nxt, 1, t + 1);
        #pragma unroll
        for (int m = 0; m < 4; ++m) af[m] = ds_read128(&Al[cur][1][aoff[m]]);
        bf0 = ds_read128(&Bl[cur][1][boff[0]]);
        bf1 = ds_read128(&Bl[cur][1][boff[1]]);
        asm volatile("s_waitcnt lgkmcnt(0)" ::: "memory");
        __builtin_amdgcn_sched_barrier(0);
        __builtin_amdgcn_s_setprio(1);
        #pragma unroll
        for (int m = 0; m < 4; ++m) {
            acc[m][0] = __builtin_amdgcn_mfma_f32_16x16x32_bf16(af[m], bf0, acc[m][0], 0, 0, 0);
            acc[m][1] = __builtin_amdgcn_mfma_f32_16x16x32_bf16(af[m], bf1, acc[m][1], 0, 0, 0);
        }
        __builtin_amdgcn_s_setprio(0);

        if (more) STAGE_B(nxt, 1, t + 1);
        bf0 = ds_read128(&Bl[cur][1][boff[2]]);
        bf1 = ds_read128(&Bl[cur][1][boff[3]]);
        asm volatile("s_waitcnt lgkmcnt(0)" ::: "memory");
        __builtin_amdgcn_sched_barrier(0);
        __builtin_amdgcn_s_setprio(1);
        #pragma unroll
        for (int m = 0; m < 4; ++m) {
            acc[m][2] = __builtin_amdgcn_mfma_f32_16x16x32_bf16(af[m], bf0, acc[m][2], 0, 0, 0);
            acc[m][3] = __builtin_amdgcn_mfma_f32_16x16x32_bf16(af[m], bf1, acc[m][3], 0, 0, 0);
        }
        __builtin_amdgcn_s_setprio(0);
    }
#undef STAGE_A
#undef STAGE_B

    float bv[4];
    #pragma unroll
    for (int n = 0; n < 4; ++n) bv[n] = bias[col0 + wn * 64 + n * 16 + lr];
    #pragma unroll
    for (int m = 0; m < 4; ++m)
        #pragma unroll
        for (int n = 0; n < 4; ++n) {
            const int col = col0 + wn * 64 + n * 16 + lr;
            const int rowb = row0 + wm * 64 + m * 16 + lg * 4;
            #pragma unroll
            for (int j = 0; j < 4; ++j)
                C[(size_t)(rowb + j) * D_MODEL + col] = acc[m][n][j] + bv[n];
        }
}

// ---------------------------------------------------------------------------
// Stage-2 recon (unchanged)
// ---------------------------------------------------------------------------
__global__ __launch_bounds__(256) void recon_kernel(
    const unsigned short* __restrict__ lat_k, const unsigned short* __restrict__ lat_v,
    const unsigned short* __restrict__ WkrT, const unsigned short* __restrict__ WvrT,
    const float* __restrict__ bkr, const float* __restrict__ bvr,
    unsigned short* __restrict__ k_bf, unsigned short* __restrict__ v_t)
{
    __shared__ unsigned short Alds[128 * 64];
    __shared__ unsigned short Blds[128 * 64];

    const int flat = blockIdx.x;
    const int swz = (flat & 7) * 128 + (flat >> 3);   // 1024 = 8*128
    const int z = swz >> 9;
    const int rem = swz & 511;
    const int h = rem >> 5;
    const int r0 = (rem & 31) * 128;

    const unsigned short* lat = z ? lat_v : lat_k;
    const unsigned short* WT  = z ? WvrT : WkrT;
    const float* bias = z ? bvr : bkr;

    const int tid = threadIdx.x;
    const int lane = tid & 63, wid = tid >> 6;
    const int lr = lane & 15, lg = lane >> 4;
    const int wm = wid >> 1, wn = wid & 1;

    #pragma unroll
    for (int c = 0; c < 4; ++c) {
        int e = c * 256 + tid;
        int row = e >> 3, pc = e & 7;
        gload16(lat + (size_t)(r0 + row) * 1024 + h * 64 + ((pc ^ (row & 7)) * 8),
                Alds + e * 8);
    }
    #pragma unroll
    for (int c = 0; c < 4; ++c) {
        int e = c * 256 + tid;
        int d = e >> 3, pc = e & 7;
        gload16(WT + (size_t)d * 64 + ((pc ^ (d & 7)) * 8), Blds + e * 8);
    }
    __syncthreads();

    f32x4 acc[4][4];
    #pragma unroll
    for (int m = 0; m < 4; ++m)
        #pragma unroll
        for (int n = 0; n < 4; ++n) acc[m][n] = (f32x4){0.f, 0.f, 0.f, 0.f};

    #pragma unroll
    for (int ks = 0; ks < 2; ++ks) {
        bf16x8 af[4], bfv[4];
        #pragma unroll
        for (int m = 0; m < 4; ++m) {
            int row = wm * 64 + m * 16 + lr;
            af[m] = *(const bf16x8*)&Alds[row * 64 + (((ks * 4 + lg) ^ (row & 7)) * 8)];
        }
        #pragma unroll
        for (int n = 0; n < 4; ++n) {
            int row = wn * 64 + n * 16 + lr;
            bfv[n] = *(const bf16x8*)&Blds[row * 64 + (((ks * 4 + lg) ^ (row & 7)) * 8)];
        }
        #pragma unroll
        for (int m = 0; m < 4; ++m)
            #pragma unroll
            for (int n = 0; n < 4; ++n)
                acc[m][n] = __builtin_amdgcn_mfma_f32_16x16x32_bf16(af[m], bfv[n], acc[m][n], 0, 0, 0);
    }

    const int b = r0 >> 11;
    float bv[4];
    #pragma unroll
    for (int n = 0; n < 4; ++n) bv[n] = bias[wn * 64 + n * 16 + lr];

    #pragma unroll
    for (int m = 0; m < 4; ++m) {
        #pragma unroll
        for (int n = 0; n < 4; ++n) {
            const int d = wn * 64 + n * 16 + lr;
            const int rowb = r0 + wm * 64 + m * 16 + lg * 4;
            if (z == 0) {
                #pragma unroll
                for (int j = 0; j < 4; ++j)
                    k_bf[(size_t)(rowb + j) * D_MODEL + h * D_HEAD + d] =
                        f2bf(acc[m][n][j] + bv[n]);
            } else {
                us4v o = { f2bf(acc[m][n][0] + bv[n]), f2bf(acc[m][n][1] + bv[n]),
                           f2bf(acc[m][n][2] + bv[n]), f2bf(acc[m][n][3] + bv[n]) };
                *(us4v*)&v_t[((size_t)(b * 16 + h) * 128 + d) * 2048 + (rowb & 2047)] = o;
            }
        }
    }
}

// ---------------------------------------------------------------------------
// Causal flash attention — gated port: raw s_barrier + explicit vmcnt(0)
// gate, asm ds_read_b128 for all K/V fragment reads (compiler-invisible, so
// stage(t+1)'s global_load_lds stays in flight under compute of tile t),
// explicit lgkmcnt(0) + sched_barrier(0) before each MFMA cluster.
// ---------------------------------------------------------------------------
static __device__ __forceinline__ void flash_stage(
    const unsigned short* __restrict__ kgh,
    const unsigned short* __restrict__ vtb,
    unsigned short* Kl, unsigned short* Vl, int kv0, int tid)
{
    #pragma unroll
    for (int c = 0; c < 4; ++c) {
        int idx = c * 256 + tid;
        int r = idx >> 4, ch = idx & 15;
        gload16(kgh + (size_t)(kv0 + r) * D_MODEL + ((ch ^ (r & 7)) * 8), Kl + idx * 8);
    }
    #pragma unroll
    for (int c = 0; c < 4; ++c) {
        int idx = c * 256 + tid;
        int d = idx >> 3, ch = idx & 7;
        gload16(vtb + (size_t)d * S_LEN + kv0 + ((ch ^ (d & 7)) * 8), Vl + idx * 8);
    }
}

__global__ __launch_bounds__(256, 2) void flash_kernel(
    const unsigned short* __restrict__ Q,
    const unsigned short* __restrict__ Kg,
    const unsigned short* __restrict__ Vt,
    unsigned short* __restrict__ Og)
{
    __shared__ unsigned short Klds[2][64 * 128];
    __shared__ unsigned short Vlds[2][128 * 64];

    const int tid = threadIdx.x;
    const int lane = tid & 63, wid = tid >> 6;
    const int lc = lane & 31, hi = lane >> 5;

    const int blk = blockIdx.x;
    const int jj = blk >> 5;
    const int qt = (jj < 8) ? (15 - jj) : (jj - 8);   // heavy first
    const int bh = blk & 31;
    const int b = bh >> 4, h = bh & 15;
    const size_t base = (size_t)b * S_LEN * D_MODEL;
    const unsigned short* kgh = Kg + base + h * D_HEAD;
    const unsigned short* vtb = Vt + (size_t)bh * D_HEAD * S_LEN;

    const int q0w = qt * 128 + wid * 32;
    const int qcol = q0w + lc;

    bf16x8 qf[8];
    #pragma unroll
    for (int dc = 0; dc < 8; ++dc)
        qf[dc] = *(const bf16x8*)&Q[base + (size_t)qcol * D_MODEL + h * D_HEAD + dc * 16 + hi * 8];

    f32x16 o_acc[4];
    #pragma unroll
    for (int dt = 0; dt < 4; ++dt)
        #pragma unroll
        for (int r = 0; r < 16; ++r) o_acc[dt][r] = 0.f;
    float m_r = -3e38f, l_r = 0.f;

    const int kxor = lc & 7;
    const int nt = 2 * qt + 2;

    // K-fragment byte offsets within a K buffer; V offsets within V buffer
    int koff[16];
    #pragma unroll
    for (int dc = 0; dc < 8; ++dc) {
        koff[2 * dc]     = lc * 128 + (((dc * 2 + hi) ^ kxor) * 8);
        koff[2 * dc + 1] = (32 + lc) * 128 + (((dc * 2 + hi) ^ kxor) * 8);
    }

    flash_stage(kgh, vtb, Klds[0], Vlds[0], 0, tid);

    #pragma unroll 1
    for (int t = 0; t < nt; ++t) {
        const int bb = t & 1;
        const int kv0 = t * 64;

        // gate: own stage(t) loads landed; all waves past their tile-(t-1) reads
        asm volatile("s_waitcnt vmcnt(0)" ::: "memory");
        __builtin_amdgcn_s_barrier();
        asm volatile("" ::: "memory");

        if (t + 1 < nt)
            flash_stage(kgh, vtb, Klds[bb ^ 1], Vlds[bb ^ 1], (t + 1) * 64, tid);

        const unsigned short* Kb = Klds[bb];
        const unsigned short* Vb = Vlds[bb];

        // ---- S^T = K Q^T: two groups of {8 asm reads -> wait -> 8 MFMA} ----
        f32x16 s0a, s0b, s1a, s1b;
        #pragma unroll
        for (int r = 0; r < 16; ++r) { s0a[r] = 0.f; s0b[r] = 0.f; s1a[r] = 0.f; s1b[r] = 0.f; }

        bf16x8 kf[8];
        #pragma unroll
        for (int i = 0; i < 8; ++i) kf[i] = ds_read128(&Kb[koff[i]]);
        asm volatile("s_waitcnt lgkmcnt(0)" ::: "memory");
        __builtin_amdgcn_sched_barrier(0);
        __builtin_amdgcn_s_setprio(1);
        #pragma unroll
        for (int dc = 0; dc < 4; ++dc) {
            s0a = __builtin_amdgcn_mfma_f32_32x32x16_bf16(kf[2 * dc],     qf[dc], s0a, 0, 0, 0);
            s1a = __builtin_amdgcn_mfma_f32_32x32x16_bf16(kf[2 * dc + 1], qf[dc], s1a, 0, 0, 0);
        }
        __builtin_amdgcn_s_setprio(0);

        #pragma unroll
        for (int i = 0; i < 8; ++i) kf[i] = ds_read128(&Kb[koff[8 + i]]);
        asm volatile("s_waitcnt lgkmcnt(0)" ::: "memory");
        __builtin_amdgcn_sched_barrier(0);
        __builtin_amdgcn_s_setprio(1);
        #pragma unroll
        for (int dc = 0; dc < 4; ++dc) {
            s0b = __builtin_amdgcn_mfma_f32_32x32x16_bf16(kf[2 * dc],     qf[dc + 4], s0b, 0, 0, 0);
            s1b = __builtin_amdgcn_mfma_f32_32x32x16_bf16(kf[2 * dc + 1], qf[dc + 4], s1b, 0, 0, 0);
        }
        __builtin_amdgcn_s_setprio(0);

        f32x16 s0 = s0a + s0b;
        f32x16 s1 = s1a + s1b;

        if (t >= nt - 2) {
            #pragma unroll
            for (int r = 0; r < 16; ++r) {
                int krow = (r & 3) + 8 * (r >> 2) + 4 * hi;
                if (kv0 + krow > qcol)      s0[r] = -3e38f;
                if (kv0 + 32 + krow > qcol) s1[r] = -3e38f;
            }
        }

        float mt[8];
        #pragma unroll
        for (int i = 0; i < 8; ++i)
            mt[i] = fmaxf(fmaxf(s0[2 * i], s0[2 * i + 1]), fmaxf(s1[2 * i], s1[2 * i + 1]));
        float mA = fmaxf(fmaxf(mt[0], mt[1]), fmaxf(mt[2], mt[3]));
        float mB = fmaxf(fmaxf(mt[4], mt[5]), fmaxf(mt[6], mt[7]));
        float sm = fmaxf(mA, mB);
        sm = fmaxf(sm, __shfl_xor(sm, 32));

        if (__any(sm > m_r + 11.5f)) {
            float mnew = fmaxf(m_r, sm);
            float alpha = exp2_hw(m_r - mnew);
            l_r *= alpha;
            m_r = mnew;
            #pragma unroll
            for (int r = 0; r < 16; ++r) {
                float av = __shfl(alpha, (r & 3) + 8 * (r >> 2) + 4 * hi);
                #pragma unroll
                for (int dt = 0; dt < 4; ++dt) o_acc[dt][r] *= av;
            }
        }

        #pragma unroll
        for (int r = 0; r < 16; ++r) {
            s0[r] = exp2_hw(s0[r] - m_r);
            s1[r] = exp2_hw(s1[r] - m_r);
        }
        float st[8];
        #pragma unroll
        for (int i = 0; i < 8; ++i)
            st[i] = (s0[2 * i] + s0[2 * i + 1]) + (s1[2 * i] + s1[2 * i + 1]);
        l_r += ((st[0] + st[1]) + (st[2] + st[3])) + ((st[4] + st[5]) + (st[6] + st[7]));

        // ---- PV: per t32, build both pf, then {8 asm reads -> wait -> 8 MFMA}
        #pragma unroll
        for (int t32 = 0; t32 < 2; ++t32) {
            const f32x16& s = t32 ? s1 : s0;
            unsigned int c0[4], c1[4];
            #pragma unroll
            for (int g = 0; g < 4; ++g) {
                c0[g] = cvtpk_bf16(s[4 * g],     s[4 * g + 1]);
                c1[g] = cvtpk_bf16(s[4 * g + 2], s[4 * g + 3]);
            }
            bf16x8 pf[2];
            #pragma unroll
            for (int kt = 0; kt < 2; ++kt) {
                unsigned int sel0 = hi ? c0[2 * kt] : c0[2 * kt + 1];
                unsigned int sel1 = hi ? c1[2 * kt] : c1[2 * kt + 1];
                unsigned int o0 = (unsigned int)__shfl_xor((int)sel0, 32);
                unsigned int o1 = (unsigned int)__shfl_xor((int)sel1, 32);
                u32x4 uu;
                uu.x = hi ? o0 : c0[2 * kt];
                uu.y = hi ? o1 : c1[2 * kt];
                uu.z = hi ? c0[2 * kt + 1] : o0;
                uu.w = hi ? c1[2 * kt + 1] : o1;
                pf[kt] = __builtin_bit_cast(bf16x8, uu);
            }
            bf16x8 vf[8];
            #pragma unroll
            for (int kt = 0; kt < 2; ++kt)
                #pragma unroll
                for (int dt = 0; dt < 4; ++dt)
                    vf[kt * 4 + dt] = ds_read128(
                        &Vb[(dt * 32 + lc) * 64 + (((t32 * 4 + kt * 2 + hi) ^ kxor) * 8)]);
            asm volatile("s_waitcnt lgkmcnt(0)" ::: "memory");
            __builtin_amdgcn_sched_barrier(0);
            __builtin_amdgcn_s_setprio(1);
            #pragma unroll
            for (int kt = 0; kt < 2; ++kt)
                #pragma unroll
                for (int dt = 0; dt < 4; ++dt)
                    o_acc[dt] = __builtin_amdgcn_mfma_f32_32x32x16_bf16(
                        pf[kt], vf[kt * 4 + dt], o_acc[dt], 0, 0, 0);
            __builtin_amdgcn_s_setprio(0);
        }
    }

    float lt = l_r + __shfl_xor(l_r, 32);
    float inv = 1.0f / lt;
    #pragma unroll
    for (int r = 0; r < 16; ++r) {
        int qrow = (r & 3) + 8 * (r >> 2) + 4 * hi;
        float iv = __shfl(inv, qrow);
        #pragma unroll
        for (int dt = 0; dt < 4; ++dt)
            Og[base + (size_t)(q0w + qrow) * D_MODEL + h * D_HEAD + dt * 32 + lc] =
                f2bf(o_acc[dt][r] * iv);
    }
}

// ---------------------------------------------------------------------------
extern "C" void kernel_launch(void* const* d_in, const int* in_sizes, int n_in,
                              void* d_out, int out_size, void* d_ws, size_t ws_size,
                              hipStream_t stream)
{
    const float* queries = (const float*)d_in[0];
    const float* keys    = (const float*)d_in[1];
    const float* values  = (const float*)d_in[2];
    const float* Wq  = (const float*)d_in[3];
    const float* bq  = (const float*)d_in[4];
    const float* Wlk = (const float*)d_in[5];
    const float* blk = (const float*)d_in[6];
    const float* Wlv = (const float*)d_in[7];
    const float* blv = (const float*)d_in[8];
    const float* Wkr = (const float*)d_in[9];
    const float* bkr = (const float*)d_in[10];
    const float* Wvr = (const float*)d_in[11];
    const float* bvr = (const float*)d_in[12];
    const float* Wo  = (const float*)d_in[13];
    const float* bo  = (const float*)d_in[14];
    float* out = (float*)d_out;

    char* ws = (char*)d_ws;
    const size_t MB = 1024 * 1024;
    unsigned short* abf_q = (unsigned short*)(ws);            // 16MB; ao aliases
    unsigned short* abf_k = (unsigned short*)(ws + 16 * MB);  // 16MB
    unsigned short* abf_v = (unsigned short*)(ws + 32 * MB);
    unsigned short* q_bf  = (unsigned short*)(ws + 48 * MB);
    unsigned short* k_bf  = (unsigned short*)(ws + 64 * MB);
    unsigned short* v_t   = (unsigned short*)(ws + 80 * MB);
    unsigned short* lat_k = (unsigned short*)(ws + 96 * MB);   // 8MB
    unsigned short* lat_v = (unsigned short*)(ws + 104 * MB);  // 8MB
    unsigned short* WqT   = (unsigned short*)(ws + 112 * MB);  // 8MB
    unsigned short* WlkT  = (unsigned short*)(ws + 120 * MB);  // 4MB
    unsigned short* WlvT  = (unsigned short*)(ws + 124 * MB);  // 4MB
    unsigned short* WkrT  = (unsigned short*)(ws + 128 * MB);  // 16KB
    unsigned short* WvrT  = WkrT + 128 * 64;
    unsigned short* WoT   = (unsigned short*)(ws + 129 * MB);  // 8MB
    unsigned short* ao    = abf_q;   // dead after stage1

    prep_kernel<<<16385, 256, 0, stream>>>(
        queries, keys, values, Wq, Wlk, Wlv, Wo, Wkr, Wvr,
        abf_q, abf_k, abf_v, WqT, WlkT, WlvT, WoT, WkrT, WvrT);

    stage1_8p_kernel<<<256, 512, 0, stream>>>(
        abf_q, abf_k, abf_v, WqT, WlkT, WlvT, bq, blk, blv,
        q_bf, lat_k, lat_v);

    recon_kernel<<<1024, 256, 0, stream>>>(
        lat_k, lat_v, WkrT, WvrT, bkr, bvr, k_bf, v_t);

    flash_kernel<<<512, 256, 0, stream>>>(q_bf, k_bf, v_t, ao);

    out_gemm8p_kernel<<<256, 512, 0, stream>>>(ao, WoT, bo, out);
}